// Round 9
// baseline (294.349 us; speedup 1.0000x reference)
//
#include <hip/hip_runtime.h>
#include <math.h>

#define NWTOK 343
#define NTOK 117649
#define QSH 0.2550348672f    // 0.5 * (1/sqrt(8)) * log2(e); dup-trick doubles the dot
#define LOG2E 1.4426950408889634f
#define NPAD 352             // 343 padded to 22*16

typedef unsigned int u32;
typedef __fp16 h2 __attribute__((ext_vector_type(2)));
typedef __fp16 h4 __attribute__((ext_vector_type(4)));
typedef float f32x4 __attribute__((ext_vector_type(4)));

__device__ __forceinline__ u32 packh2(float a, float b) {
    h2 h = __builtin_amdgcn_cvt_pkrtz(a, b);
    return __builtin_bit_cast(u32, h);
}
__device__ __forceinline__ float fast_exp2(float x) {
#if __has_builtin(__builtin_amdgcn_exp2f)
    return __builtin_amdgcn_exp2f(x);
#else
    return exp2f(x);
#endif
}

// Inline exact-GELU via Abramowitz-Stegun 7.1.26 erf (max abs err 1.5e-7).
__device__ __forceinline__ float gelu_exact(float x) {
    const float z = x * 0.70710678118654752f;
    const float az = fabsf(z);
    const float t = __builtin_amdgcn_rcpf(fmaf(0.3275911f, az, 1.0f));
    float y = fmaf(t, 1.061405429f, -1.453152027f);
    y = fmaf(t, y, 1.421413741f);
    y = fmaf(t, y, -0.284496736f);
    y = fmaf(t, y, 0.254829592f);
    y *= t;
    const float one_m_erf = y * __expf(-az * az);
    const float erf_az = 1.0f - one_m_erf;
    const float erf_z = (z < 0.f) ? -erf_az : erf_az;
    return 0.5f * x * (1.0f + erf_z);
}

// ------- bias expand: bexp[blk*2+h][i(352)][j(352)] = rpb[rpi(i,j)][h]*log2e -------
__global__ __launch_bounds__(384) void k_bias_expand(
    const float* __restrict__ rpb,   // (3, 2197, 2)
    float* __restrict__ bexp)
{
    const int b = blockIdx.x;        // bh*352 + i
    const int bh = b / NPAD;
    const int i = b - bh * NPAD;
    const int blk = bh >> 1, h = bh & 1;
    const int j = threadIdx.x;
    if (j >= NPAD) return;
    float val;
    if (j >= NWTOK) {
        val = -60.f;                 // key padding -> exp2 ~ 0
    } else if (i >= NWTOK) {
        val = 0.f;                   // query padding, never stored
    } else {
        const int iz = i / 49, ir = i - iz * 49, iy = ir / 7, ix = ir - iy * 7;
        const int jz = j / 49, jr = j - jz * 49, jy = jr / 7, jx = jr - jy * 7;
        const int idx = (iz - jz + 6) * 169 + (iy - jy + 6) * 13 + (ix - jx + 6);
        val = rpb[((size_t)blk * 2197 + idx) * 2 + h] * LOG2E;
    }
    bexp[((size_t)bh * NPAD + i) * NPAD + j] = val;
}

// ---------------- K0: patch embed + LN -> xe (window-major) ----------------
__global__ __launch_bounds__(256, 2) void k0_patch(
    const float* __restrict__ x,
    const float* __restrict__ pe_w,
    const float* __restrict__ pe_bias,
    const float* __restrict__ pe_g,
    const float* __restrict__ pe_b,
    float* __restrict__ xe)
{
    __shared__ float w_s[128];
    __shared__ float pb_s[16], g_s[16], b_s[16];
    const int tid = threadIdx.x;
    if (tid < 128) w_s[tid] = pe_w[tid];
    if (tid < 16) { pb_s[tid] = pe_bias[tid]; g_s[tid] = pe_g[tid]; b_s[tid] = pe_b[tid]; }
    __syncthreads();
    const int g = blockIdx.x * 256 + tid;
    if (g >= NTOK) return;
    const int z = g / 2401;
    const int r = g - z * 2401;
    const int y = r / 49;
    const int xx = r - y * 49;
    const float* bp = x + ((2 * z) * 98 + (2 * y)) * 98 + 2 * xx;
    float in[8];
    in[0] = bp[0];    in[1] = bp[1];
    in[2] = bp[98];   in[3] = bp[99];
    in[4] = bp[9604]; in[5] = bp[9605];
    in[6] = bp[9702]; in[7] = bp[9703];
    float v[16];
    float mu = 0.f;
    #pragma unroll
    for (int c = 0; c < 16; ++c) {
        float a = pb_s[c];
        #pragma unroll
        for (int k = 0; k < 8; ++k) a = fmaf(in[k], w_s[c * 8 + k], a);
        v[c] = a; mu += a;
    }
    mu *= 0.0625f;
    float var = 0.f;
    #pragma unroll
    for (int c = 0; c < 16; ++c) { float d = v[c] - mu; var = fmaf(d, d, var); }
    var *= 0.0625f;
    const float rs = rsqrtf(var + 1e-5f);
    float o[16];
    #pragma unroll
    for (int c = 0; c < 16; ++c) o[c] = (v[c] - mu) * rs * g_s[c] + b_s[c];

    const int zw = z / 7, zi = z - zw * 7;
    const int yw = y / 7, yi = y - yw * 7;
    const int xw = xx / 7, xi = xx - xw * 7;
    const int w = (zw * 7 + yw) * 7 + xw;
    const int t = (zi * 7 + yi) * 7 + xi;
    float4* dst = (float4*)(xe + (size_t)(w * NWTOK + t) * 16);
    dst[0] = ((float4*)o)[0]; dst[1] = ((float4*)o)[1];
    dst[2] = ((float4*)o)[2]; dst[3] = ((float4*)o)[3];
}

// ---- K_swin: one WG per window, all 3 blocks fused (shift=0 -> windows independent) ----
__global__ __launch_bounds__(512, 4) void k_swin(
    const float* __restrict__ xe,      // [343 win][343 tok][16]
    const float* __restrict__ bexp,    // [3][2][352][352]
    const float* __restrict__ qkv_w,   // (3,48,16)
    const float* __restrict__ proj_w,  // (3,16,16)
    const float* __restrict__ proj_b,  // (3,16)
    const float* __restrict__ n1_g, const float* __restrict__ n1_b,
    const float* __restrict__ n2_g, const float* __restrict__ n2_b,
    const float* __restrict__ fc1_w,   // (3,64,16)
    const float* __restrict__ fc1_b,   // (3,64)
    const float* __restrict__ fc2_w,   // (3,16,64)
    const float* __restrict__ fc2_b,   // (3,16)
    float* __restrict__ outp)
{
    __shared__ __fp16 Kl[NPAD][16];    // keys x 16 dims (h0: 0-7, h1: 8-15)
    __shared__ __fp16 Ql[NPAD][16];
    __shared__ __fp16 Vt[16][360];     // dims x keys (padded stride)
    __shared__ float Ol[NWTOK][16];    // attention output per token
    __shared__ float qkvw_s[768];
    __shared__ float projw_s[256];
    __shared__ float fc1w_s[1024];
    __shared__ float fc2w_s[1024];
    __shared__ float n1g_s[16], n1b_s[16], projb_s[16], n2g_s[16], n2b_s[16], fc2b_s[16];
    __shared__ float fc1b_s[64];

    const int tid = threadIdx.x;
    const int w = blockIdx.x;
    const int t = tid;                 // token id when < NWTOK

    // zero-init K/Q/V (covers row/col padding once; real rows rewritten each block)
    for (int i = tid; i < 2816; i += 512) { ((u32*)Kl)[i] = 0u; ((u32*)Ql)[i] = 0u; }
    for (int i = tid; i < 2880; i += 512) ((u32*)Vt)[i] = 0u;

    // persistent token state
    float xr[16];
    if (t < NWTOK) {
        const float4* xs = (const float4*)(xe + (size_t)(w * NWTOK + t) * 16);
        ((float4*)xr)[0] = xs[0]; ((float4*)xr)[1] = xs[1];
        ((float4*)xr)[2] = xs[2]; ((float4*)xr)[3] = xs[3];
    }

    const int lane = tid & 63;
    const int wave = tid >> 6;
    const int n = lane & 15;
    const int g4 = (lane >> 4) << 2;

    for (int blk = 0; blk < 3; ++blk) {
        // ---- stage this block's weights ----
        for (int i = tid; i < 768; i += 512) qkvw_s[i] = qkv_w[blk * 768 + i];
        if (tid < 256) projw_s[tid] = proj_w[blk * 256 + tid];
        for (int i = tid; i < 1024; i += 512) {
            fc1w_s[i] = fc1_w[blk * 1024 + i];
            fc2w_s[i] = fc2_w[blk * 1024 + i];
        }
        if (tid < 16) {
            n1g_s[tid] = n1_g[blk * 16 + tid]; n1b_s[tid] = n1_b[blk * 16 + tid];
            projb_s[tid] = proj_b[blk * 16 + tid];
            n2g_s[tid] = n2_g[blk * 16 + tid]; n2b_s[tid] = n2_b[blk * 16 + tid];
            fc2b_s[tid] = fc2_b[blk * 16 + tid];
        }
        if (tid < 64) fc1b_s[tid] = fc1_b[blk * 64 + tid];
        __syncthreads();

        // ---- phase A: LN1 + QKV -> LDS (f16) ----
        if (t < NWTOK) {
            float mu = 0.f;
            #pragma unroll
            for (int c = 0; c < 16; ++c) mu += xr[c];
            mu *= 0.0625f;
            float var = 0.f;
            #pragma unroll
            for (int c = 0; c < 16; ++c) { float d = xr[c] - mu; var = fmaf(d, d, var); }
            var *= 0.0625f;
            const float rs = rsqrtf(var + 1e-5f);
            float yv[16];
            #pragma unroll
            for (int c = 0; c < 16; ++c) yv[c] = (xr[c] - mu) * rs * n1g_s[c] + n1b_s[c];

            float tmp[16];
            #pragma unroll
            for (int rr = 0; rr < 16; ++rr) {
                float a = 0.f;
                #pragma unroll
                for (int c = 0; c < 16; ++c) a = fmaf(yv[c], qkvw_s[rr * 16 + c], a);
                tmp[rr] = a * QSH;
            }
            uint4 ua, ub;
            ua.x = packh2(tmp[0], tmp[1]);  ua.y = packh2(tmp[2], tmp[3]);
            ua.z = packh2(tmp[4], tmp[5]);  ua.w = packh2(tmp[6], tmp[7]);
            ub.x = packh2(tmp[8], tmp[9]);  ub.y = packh2(tmp[10], tmp[11]);
            ub.z = packh2(tmp[12], tmp[13]); ub.w = packh2(tmp[14], tmp[15]);
            *(uint4*)&Ql[t][0] = ua; *(uint4*)&Ql[t][8] = ub;

            #pragma unroll
            for (int rr = 0; rr < 16; ++rr) {
                float a = 0.f;
                #pragma unroll
                for (int c = 0; c < 16; ++c) a = fmaf(yv[c], qkvw_s[(16 + rr) * 16 + c], a);
                tmp[rr] = a;
            }
            ua.x = packh2(tmp[0], tmp[1]);  ua.y = packh2(tmp[2], tmp[3]);
            ua.z = packh2(tmp[4], tmp[5]);  ua.w = packh2(tmp[6], tmp[7]);
            ub.x = packh2(tmp[8], tmp[9]);  ub.y = packh2(tmp[10], tmp[11]);
            ub.z = packh2(tmp[12], tmp[13]); ub.w = packh2(tmp[14], tmp[15]);
            *(uint4*)&Kl[t][0] = ua; *(uint4*)&Kl[t][8] = ub;

            #pragma unroll
            for (int rr = 0; rr < 16; ++rr) {
                float a = 0.f;
                #pragma unroll
                for (int c = 0; c < 16; ++c) a = fmaf(yv[c], qkvw_s[(32 + rr) * 16 + c], a);
                Vt[rr][t] = (__fp16)a;
            }
        }
        __syncthreads();

        // ---- phase B: MFMA attention, both heads (44 qt-tiles over 8 waves) ----
        // Dup trick: head-h dims (8) fill all 16 k-slots twice via hd = h*8+(g4&4);
        // q pre-scaled x0.5 makes the doubled dot come out right. Bias is C.
        for (int tile = wave; tile < 44; tile += 8) {
            const int h = (tile >= 22) ? 1 : 0;
            const int qt = tile - h * 22;
            const int qi = qt * 16 + n;
            const int hd = h * 8 + (g4 & 4);
            const h4 bq = *(const h4*)&Ql[qi][hd];
            const float* brow = bexp + (((size_t)blk * 2 + h) * NPAD + qi) * NPAD;
            f32x4 acc = {0.f, 0.f, 0.f, 0.f};
            float l = 0.f;
            for (int kt = 0; kt < 22; ++kt) {
                const f32x4 cb = *(const f32x4*)(brow + kt * 16 + g4);
                const h4 ak = *(const h4*)&Kl[kt * 16 + n][hd];
                f32x4 s = __builtin_amdgcn_mfma_f32_16x16x16f16(ak, bq, cb, 0, 0, 0);
                const float p0 = fast_exp2(s[0]);
                const float p1 = fast_exp2(s[1]);
                const float p2 = fast_exp2(s[2]);
                const float p3 = fast_exp2(s[3]);
                l += (p0 + p1) + (p2 + p3);
                const h4 bp = __builtin_bit_cast(h4,
                    make_uint2(packh2(p0, p1), packh2(p2, p3)));
                const h4 av = *(const h4*)&Vt[n][kt * 16 + g4];
                acc = __builtin_amdgcn_mfma_f32_16x16x16f16(av, bp, acc, 0, 0, 0);
            }
            l += __shfl_xor(l, 16);
            l += __shfl_xor(l, 32);
            if (((g4 >> 3) == h) && qi < NWTOK) {   // lanes holding head-h o dims
                const float inv = 1.f / l;
                f32x4 o = acc * inv;
                *(f32x4*)&Ol[qi][g4] = o;
            }
        }
        __syncthreads();

        // ---- phase C: proj + residual + LN2 + MLP + residual ----
        if (t < NWTOK) {
            float o[16];
            ((float4*)o)[0] = *(const float4*)&Ol[t][0];
            ((float4*)o)[1] = *(const float4*)&Ol[t][4];
            ((float4*)o)[2] = *(const float4*)&Ol[t][8];
            ((float4*)o)[3] = *(const float4*)&Ol[t][12];

            #pragma unroll
            for (int c = 0; c < 16; ++c) {
                float a = projb_s[c];
                #pragma unroll
                for (int cc = 0; cc < 16; ++cc) a = fmaf(o[cc], projw_s[c * 16 + cc], a);
                xr[c] += a;
            }

            float mu = 0.f;
            #pragma unroll
            for (int c = 0; c < 16; ++c) mu += xr[c];
            mu *= 0.0625f;
            float var = 0.f;
            #pragma unroll
            for (int c = 0; c < 16; ++c) { float d = xr[c] - mu; var = fmaf(d, d, var); }
            var *= 0.0625f;
            const float rs = rsqrtf(var + 1e-5f);
            float zv[16];
            #pragma unroll
            for (int c = 0; c < 16; ++c) zv[c] = (xr[c] - mu) * rs * n2g_s[c] + n2b_s[c];

            float accm[16];
            #pragma unroll
            for (int c = 0; c < 16; ++c) accm[c] = fc2b_s[c];
            #pragma unroll
            for (int ch = 0; ch < 4; ++ch) {
                float hv[16];
                #pragma unroll
                for (int mm = 0; mm < 16; ++mm) {
                    const int mi = ch * 16 + mm;
                    float a = fc1b_s[mi];
                    #pragma unroll
                    for (int c = 0; c < 16; ++c) a = fmaf(zv[c], fc1w_s[mi * 16 + c], a);
                    hv[mm] = gelu_exact(a);
                }
                #pragma unroll
                for (int c = 0; c < 16; ++c) {
                    float a = accm[c];
                    #pragma unroll
                    for (int mm = 0; mm < 16; ++mm)
                        a = fmaf(hv[mm], fc2w_s[c * 64 + ch * 16 + mm], a);
                    accm[c] = a;
                }
            }
            #pragma unroll
            for (int c = 0; c < 16; ++c) xr[c] += accm[c];

            if (blk == 2) {
                const int wd = w / 49;
                const int wr2 = w - wd * 49;
                const int whh = wr2 / 7;
                const int www = wr2 - whh * 7;
                const int tz = t / 49;
                const int tr2 = t - tz * 49;
                const int ty = tr2 / 7;
                const int tx = tr2 - ty * 7;
                const int g = ((wd * 7 + tz) * 49 + (whh * 7 + ty)) * 49 + (www * 7 + tx);
                #pragma unroll
                for (int c = 0; c < 16; ++c) outp[(size_t)c * NTOK + g] = xr[c];
            }
        }
        __syncthreads();   // protect weights/LDS for next block's restage
    }
}

extern "C" void kernel_launch(void* const* d_in, const int* in_sizes, int n_in,
                              void* d_out, int out_size, void* d_ws, size_t ws_size,
                              hipStream_t stream) {
    const float* x       = (const float*)d_in[0];
    const float* pe_w    = (const float*)d_in[1];
    const float* pe_bias = (const float*)d_in[2];
    const float* pe_g    = (const float*)d_in[3];
    const float* pe_b    = (const float*)d_in[4];
    const float* n1_g    = (const float*)d_in[5];
    const float* n1_b    = (const float*)d_in[6];
    const float* qkv_w   = (const float*)d_in[7];
    const float* rpb     = (const float*)d_in[8];
    const float* proj_w  = (const float*)d_in[9];
    const float* proj_b  = (const float*)d_in[10];
    const float* n2_g    = (const float*)d_in[11];
    const float* n2_b    = (const float*)d_in[12];
    const float* fc1_w   = (const float*)d_in[13];
    const float* fc1_b   = (const float*)d_in[14];
    const float* fc2_w   = (const float*)d_in[15];
    const float* fc2_b   = (const float*)d_in[16];

    float* ws = (float*)d_ws;
    const size_t SEG = (size_t)NTOK * 16;          // xe: 1,882,384 floats
    float* xe = ws;
    float* bexp = ws + SEG;                        // 6*352*352 floats
    float* out = (float*)d_out;

    k_bias_expand<<<6 * NPAD, 384, 0, stream>>>(rpb, bexp);

    k0_patch<<<(NTOK + 255) / 256, 256, 0, stream>>>(
        x, pe_w, pe_bias, pe_g, pe_b, xe);

    k_swin<<<NWTOK, 512, 0, stream>>>(
        xe, bexp, qkv_w, proj_w, proj_b,
        n1_g, n1_b, n2_g, n2_b,
        fc1_w, fc1_b, fc2_w, fc2_b, out);
}

// Round 10
// 260.126 us; speedup vs baseline: 1.1316x; 1.1316x over previous
//
#include <hip/hip_runtime.h>
#include <math.h>

#define NWTOK 343
#define NTOK 117649
#define QSCALE 0.510069734f   // (1/sqrt(8)) * log2(e)
#define LOG2E 1.4426950408889634f
#define QPLANE 1372   // u32 per (window,head) plane of f16 rows
#define OPLANE 2744   // f32 per (window,head) plane of o
#define NPAD 352

typedef unsigned int u32;
typedef __fp16 h2 __attribute__((ext_vector_type(2)));
typedef __fp16 h4 __attribute__((ext_vector_type(4)));
typedef float f32x4 __attribute__((ext_vector_type(4)));

__device__ __forceinline__ u32 packh2(float a, float b) {
    h2 h = __builtin_amdgcn_cvt_pkrtz(a, b);
    return __builtin_bit_cast(u32, h);
}
__device__ __forceinline__ float fast_exp2(float x) {
#if __has_builtin(__builtin_amdgcn_exp2f)
    return __builtin_amdgcn_exp2f(x);
#else
    return exp2f(x);
#endif
}

// dot of v[16] with 16 consecutive LDS floats via 4x ds_read_b128
__device__ __forceinline__ float dot16_lds(const float* __restrict__ wrow,
                                           const float* __restrict__ v) {
    const float4 w0 = *(const float4*)(wrow);
    const float4 w1 = *(const float4*)(wrow + 4);
    const float4 w2 = *(const float4*)(wrow + 8);
    const float4 w3 = *(const float4*)(wrow + 12);
    float a = v[0] * w0.x;
    a = fmaf(v[1], w0.y, a); a = fmaf(v[2], w0.z, a); a = fmaf(v[3], w0.w, a);
    a = fmaf(v[4], w1.x, a); a = fmaf(v[5], w1.y, a); a = fmaf(v[6], w1.z, a);
    a = fmaf(v[7], w1.w, a);
    a = fmaf(v[8], w2.x, a); a = fmaf(v[9], w2.y, a); a = fmaf(v[10], w2.z, a);
    a = fmaf(v[11], w2.w, a);
    a = fmaf(v[12], w3.x, a); a = fmaf(v[13], w3.y, a); a = fmaf(v[14], w3.z, a);
    a = fmaf(v[15], w3.w, a);
    return a;
}

// Inline exact-GELU via Abramowitz-Stegun 7.1.26 erf (max abs err 1.5e-7).
__device__ __forceinline__ float gelu_exact(float x) {
    const float z = x * 0.70710678118654752f;
    const float az = fabsf(z);
    const float t = __builtin_amdgcn_rcpf(fmaf(0.3275911f, az, 1.0f));
    float y = fmaf(t, 1.061405429f, -1.453152027f);
    y = fmaf(t, y, 1.421413741f);
    y = fmaf(t, y, -0.284496736f);
    y = fmaf(t, y, 0.254829592f);
    y *= t;
    const float one_m_erf = y * __expf(-az * az);
    const float erf_az = 1.0f - one_m_erf;
    const float erf_z = (z < 0.f) ? -erf_az : erf_az;
    return 0.5f * x * (1.0f + erf_z);
}

__device__ __forceinline__ void store_f16_row(u32* base, int t, const float* v8) {
    uint4 u;
    u.x = packh2(v8[0], v8[1]); u.y = packh2(v8[2], v8[3]);
    u.z = packh2(v8[4], v8[5]); u.w = packh2(v8[6], v8[7]);
    *(uint4*)(base + t * 4) = u;
}

// ------- bias expand: bexp[blk*2+h][i(352)][j(352)] = rpb[rpi(i,j)][h]*log2e -------
__global__ __launch_bounds__(384) void k_bias_expand(
    const float* __restrict__ rpb,   // (3, 2197, 2)
    float* __restrict__ bexp)
{
    const int b = blockIdx.x;        // bh*352 + i
    const int bh = b / NPAD;
    const int i = b - bh * NPAD;
    const int blk = bh >> 1, h = bh & 1;
    const int j = threadIdx.x;
    if (j >= NPAD) return;
    float val;
    if (j >= NWTOK) {
        val = -60.f;
    } else if (i >= NWTOK) {
        val = 0.f;
    } else {
        const int iz = i / 49, ir = i - iz * 49, iy = ir / 7, ix = ir - iy * 7;
        const int jz = j / 49, jr = j - jz * 49, jy = jr / 7, jx = jr - jy * 7;
        const int idx = (iz - jz + 6) * 169 + (iy - jy + 6) * 13 + (ix - jx + 6);
        val = rpb[((size_t)blk * 2197 + idx) * 2 + h] * LOG2E;
    }
    bexp[((size_t)bh * NPAD + i) * NPAD + j] = val;
}

// ---------------- K0: patch embed + LN + LN1 + QKV(block 0) ----------------
__global__ __launch_bounds__(256, 2) void k0_patch_qkv(
    const float* __restrict__ x,
    const float* __restrict__ pe_w,
    const float* __restrict__ pe_bias,
    const float* __restrict__ pe_g,
    const float* __restrict__ pe_b,
    const float* __restrict__ n1_g,
    const float* __restrict__ n1_b,
    const float* __restrict__ qkv_w,
    float* __restrict__ xe,
    u32* __restrict__ qg,
    u32* __restrict__ kg,
    u32* __restrict__ vg)
{
    __shared__ float w_s[128];
    __shared__ float pb_s[16], g_s[16], b_s[16], n1g_s[16], n1b_s[16];
    __shared__ float qkvw_s[768];
    const int tid = threadIdx.x;
    if (tid < 128) w_s[tid] = pe_w[tid];
    if (tid < 16) {
        pb_s[tid] = pe_bias[tid]; g_s[tid] = pe_g[tid]; b_s[tid] = pe_b[tid];
        n1g_s[tid] = n1_g[tid]; n1b_s[tid] = n1_b[tid];
    }
    for (int i = tid; i < 768; i += 256) qkvw_s[i] = qkv_w[i];
    __syncthreads();
    const int g = blockIdx.x * 256 + tid;
    if (g >= NTOK) return;
    const int z = g / 2401;
    const int r = g - z * 2401;
    const int y = r / 49;
    const int xx = r - y * 49;
    const float* bp = x + ((2 * z) * 98 + (2 * y)) * 98 + 2 * xx;
    float in[8];
    in[0] = bp[0];    in[1] = bp[1];
    in[2] = bp[98];   in[3] = bp[99];
    in[4] = bp[9604]; in[5] = bp[9605];
    in[6] = bp[9702]; in[7] = bp[9703];
    float v[16];
    float mu = 0.f;
    #pragma unroll
    for (int c = 0; c < 16; ++c) {
        float a = pb_s[c];
        #pragma unroll
        for (int k = 0; k < 8; ++k) a = fmaf(in[k], w_s[c * 8 + k], a);
        v[c] = a; mu += a;
    }
    mu *= 0.0625f;
    float var = 0.f;
    #pragma unroll
    for (int c = 0; c < 16; ++c) { float d = v[c] - mu; var = fmaf(d, d, var); }
    var *= 0.0625f;
    float rs = rsqrtf(var + 1e-5f);
    float o[16];
    #pragma unroll
    for (int c = 0; c < 16; ++c) o[c] = (v[c] - mu) * rs * g_s[c] + b_s[c];

    const int zw = z / 7, zi = z - zw * 7;
    const int yw = y / 7, yi = y - yw * 7;
    const int xw = xx / 7, xi = xx - xw * 7;
    const int w = (zw * 7 + yw) * 7 + xw;
    const int t = (zi * 7 + yi) * 7 + xi;
    const int widx = w * NWTOK + t;

    float4* dst = (float4*)(xe + (size_t)widx * 16);
    dst[0] = ((float4*)o)[0]; dst[1] = ((float4*)o)[1];
    dst[2] = ((float4*)o)[2]; dst[3] = ((float4*)o)[3];

    mu = 0.f;
    #pragma unroll
    for (int c = 0; c < 16; ++c) mu += o[c];
    mu *= 0.0625f;
    var = 0.f;
    #pragma unroll
    for (int c = 0; c < 16; ++c) { float d = o[c] - mu; var = fmaf(d, d, var); }
    var *= 0.0625f;
    rs = rsqrtf(var + 1e-5f);
    float yv[16];
    #pragma unroll
    for (int c = 0; c < 16; ++c) yv[c] = (o[c] - mu) * rs * n1g_s[c] + n1b_s[c];

    float tmp[16];
    #pragma unroll
    for (int rr = 0; rr < 16; ++rr) tmp[rr] = dot16_lds(qkvw_s + rr * 16, yv) * QSCALE;
    store_f16_row(qg + (size_t)(w * 2) * QPLANE, t, tmp);
    store_f16_row(qg + (size_t)(w * 2 + 1) * QPLANE, t, tmp + 8);
    #pragma unroll
    for (int rr = 0; rr < 16; ++rr) tmp[rr] = dot16_lds(qkvw_s + (16 + rr) * 16, yv);
    store_f16_row(kg + (size_t)(w * 2) * QPLANE, t, tmp);
    store_f16_row(kg + (size_t)(w * 2 + 1) * QPLANE, t, tmp + 8);
    #pragma unroll
    for (int rr = 0; rr < 16; ++rr) tmp[rr] = dot16_lds(qkvw_s + (32 + rr) * 16, yv);
    store_f16_row(vg + (size_t)(w * 2) * QPLANE, t, tmp);
    store_f16_row(vg + (size_t)(w * 2 + 1) * QPLANE, t, tmp + 8);
}

// ---- K_attn (MFMA): WG per (window,head), 8 waves; 2 qt-tiles per wave ----
// S^T = mfma(A=K, B=Q^T, C=bias); p = exp2; O^T = mfma(A=V^T, B=p).
// ak/av ds_reads depend only on kt -> shared across the tile pair; kt loop
// fully unrolled so independent cb/ds loads are hoisted (latency hiding).
__global__ __launch_bounds__(512, 4) void k_attn(
    const u32* __restrict__ qg,
    const u32* __restrict__ kg,
    const u32* __restrict__ vg,
    float* __restrict__ og,
    const float* __restrict__ bexp)   // this block's [2][352][352]
{
    __shared__ __fp16 Kl[NPAD][16];
    __shared__ __fp16 Ql[NPAD][16];
    __shared__ __fp16 Vt[16][360];

    const int tid = threadIdx.x;
    const int wh = blockIdx.x;
    const int h = wh & 1;
    const size_t qpl = (size_t)wh * QPLANE;

    if (tid < NPAD) {
        const uint4 z4 = make_uint4(0, 0, 0, 0);
        if (tid < NWTOK) {
            const uint4 kw = ((const uint4*)(kg + qpl))[tid];
            const uint4 qw = ((const uint4*)(qg + qpl))[tid];
            const uint4 vw = ((const uint4*)(vg + qpl))[tid];
            *(uint4*)&Kl[tid][0] = kw; *(uint4*)&Kl[tid][8] = z4;
            *(uint4*)&Ql[tid][0] = qw; *(uint4*)&Ql[tid][8] = z4;
            const h2 v01 = __builtin_bit_cast(h2, vw.x);
            const h2 v23 = __builtin_bit_cast(h2, vw.y);
            const h2 v45 = __builtin_bit_cast(h2, vw.z);
            const h2 v67 = __builtin_bit_cast(h2, vw.w);
            Vt[0][tid] = v01.x; Vt[1][tid] = v01.y;
            Vt[2][tid] = v23.x; Vt[3][tid] = v23.y;
            Vt[4][tid] = v45.x; Vt[5][tid] = v45.y;
            Vt[6][tid] = v67.x; Vt[7][tid] = v67.y;
        } else {
            *(uint4*)&Kl[tid][0] = z4; *(uint4*)&Kl[tid][8] = z4;
            *(uint4*)&Ql[tid][0] = z4; *(uint4*)&Ql[tid][8] = z4;
            #pragma unroll
            for (int d = 0; d < 8; ++d) Vt[d][tid] = (__fp16)0.f;
        }
        #pragma unroll
        for (int d = 8; d < 16; ++d) Vt[d][tid] = (__fp16)0.f;
    }
    __syncthreads();

    const int wave = tid >> 6;
    const int lane = tid & 63;
    const int n = lane & 15;
    const int g4 = (lane >> 4) * 4;

    for (int p = wave; p < 11; p += 8) {
        const int qiA = (2 * p) * 16 + n;
        const int qiB = qiA + 16;
        const h4 bqA = *(const h4*)&Ql[qiA][g4];
        const h4 bqB = *(const h4*)&Ql[qiB][g4];
        const float* browA = bexp + ((size_t)h * NPAD + qiA) * NPAD;
        const float* browB = browA + (size_t)16 * NPAD;
        f32x4 accA = {0.f, 0.f, 0.f, 0.f};
        f32x4 accB = {0.f, 0.f, 0.f, 0.f};
        float lA = 0.f, lB = 0.f;
        #pragma unroll
        for (int kt = 0; kt < 22; ++kt) {
            const h4 ak = *(const h4*)&Kl[kt * 16 + n][g4];
            const h4 av = *(const h4*)&Vt[n][kt * 16 + g4];
            const f32x4 cbA = *(const f32x4*)(browA + kt * 16 + g4);
            const f32x4 cbB = *(const f32x4*)(browB + kt * 16 + g4);
            f32x4 sA = __builtin_amdgcn_mfma_f32_16x16x16f16(ak, bqA, cbA, 0, 0, 0);
            f32x4 sB = __builtin_amdgcn_mfma_f32_16x16x16f16(ak, bqB, cbB, 0, 0, 0);
            const float pA0 = fast_exp2(sA[0]);
            const float pA1 = fast_exp2(sA[1]);
            const float pA2 = fast_exp2(sA[2]);
            const float pA3 = fast_exp2(sA[3]);
            const float pB0 = fast_exp2(sB[0]);
            const float pB1 = fast_exp2(sB[1]);
            const float pB2 = fast_exp2(sB[2]);
            const float pB3 = fast_exp2(sB[3]);
            lA += (pA0 + pA1) + (pA2 + pA3);
            lB += (pB0 + pB1) + (pB2 + pB3);
            const h4 bpA = __builtin_bit_cast(h4,
                make_uint2(packh2(pA0, pA1), packh2(pA2, pA3)));
            const h4 bpB = __builtin_bit_cast(h4,
                make_uint2(packh2(pB0, pB1), packh2(pB2, pB3)));
            accA = __builtin_amdgcn_mfma_f32_16x16x16f16(av, bpA, accA, 0, 0, 0);
            accB = __builtin_amdgcn_mfma_f32_16x16x16f16(av, bpB, accB, 0, 0, 0);
        }
        lA += __shfl_xor(lA, 16);
        lA += __shfl_xor(lA, 32);
        lB += __shfl_xor(lB, 16);
        lB += __shfl_xor(lB, 32);
        if (g4 < 8) {
            if (qiA < NWTOK) {
                const f32x4 o = accA * (1.f / lA);
                *(f32x4*)(og + (size_t)wh * OPLANE + qiA * 8 + g4) = o;
            }
            if (qiB < NWTOK) {
                const f32x4 o = accB * (1.f / lB);
                *(f32x4*)(og + (size_t)wh * OPLANE + qiB * 8 + g4) = o;
            }
        }
    }
}

// ------- K_post: proj + residual + LN2 + MLP (+ next LN1+QKV or output) -------
__global__ __launch_bounds__(256, 2) void k_post(
    float* __restrict__ xe,
    const float* __restrict__ og,
    u32* __restrict__ qg,
    u32* __restrict__ kg,
    u32* __restrict__ vg,
    const float* __restrict__ proj_w,
    const float* __restrict__ proj_b,
    const float* __restrict__ n2_g,
    const float* __restrict__ n2_b,
    const float* __restrict__ fc1_w,
    const float* __restrict__ fc1_b,
    const float* __restrict__ fc2_w,
    const float* __restrict__ fc2_b,
    const float* __restrict__ n1_g_nx,
    const float* __restrict__ n1_b_nx,
    const float* __restrict__ qkv_w_nx,
    float* __restrict__ outp,
    const int last)
{
    __shared__ float projw_s[256];
    __shared__ float fc1w_s[1024];
    __shared__ float fc2w_s[1024];
    __shared__ float qkvw_s[768];
    __shared__ float projb_s[16], n2g_s[16], n2b_s[16], fc2b_s[16], n1g_s[16], n1b_s[16];
    __shared__ float fc1b_s[64];
    const int tid = threadIdx.x;
    if (tid < 256) projw_s[tid] = proj_w[tid];
    for (int i = tid; i < 1024; i += 256) { fc1w_s[i] = fc1_w[i]; fc2w_s[i] = fc2_w[i]; }
    for (int i = tid; i < 768; i += 256) qkvw_s[i] = qkv_w_nx[i];
    if (tid < 16) {
        projb_s[tid] = proj_b[tid];
        n2g_s[tid] = n2_g[tid]; n2b_s[tid] = n2_b[tid];
        fc2b_s[tid] = fc2_b[tid];
        n1g_s[tid] = n1_g_nx[tid]; n1b_s[tid] = n1_b_nx[tid];
    }
    if (tid < 64) fc1b_s[tid] = fc1_b[tid];
    __syncthreads();

    const int widx = blockIdx.x * 256 + tid;
    if (widx >= NTOK) return;
    const int w = widx / NWTOK;
    const int t = widx - w * NWTOK;

    float o[16];
    const float* o0 = og + (size_t)(w * 2) * OPLANE + t * 8;
    const float* o1 = og + (size_t)(w * 2 + 1) * OPLANE + t * 8;
    ((float4*)o)[0] = ((const float4*)o0)[0]; ((float4*)o)[1] = ((const float4*)o0)[1];
    ((float4*)o)[2] = ((const float4*)o1)[0]; ((float4*)o)[3] = ((const float4*)o1)[1];

    float xr[16];
    const float4* xs = (const float4*)(xe + (size_t)widx * 16);
    ((float4*)xr)[0] = xs[0]; ((float4*)xr)[1] = xs[1];
    ((float4*)xr)[2] = xs[2]; ((float4*)xr)[3] = xs[3];

    #pragma unroll
    for (int c = 0; c < 16; ++c) xr[c] += projb_s[c] + dot16_lds(projw_s + c * 16, o);

    float mu = 0.f;
    #pragma unroll
    for (int c = 0; c < 16; ++c) mu += xr[c];
    mu *= 0.0625f;
    float var = 0.f;
    #pragma unroll
    for (int c = 0; c < 16; ++c) { float d = xr[c] - mu; var = fmaf(d, d, var); }
    var *= 0.0625f;
    float rs = rsqrtf(var + 1e-5f);
    float zv[16];
    #pragma unroll
    for (int c = 0; c < 16; ++c) zv[c] = (xr[c] - mu) * rs * n2g_s[c] + n2b_s[c];

    float hv[64];
    #pragma unroll
    for (int mi = 0; mi < 64; ++mi)
        hv[mi] = gelu_exact(fc1b_s[mi] + dot16_lds(fc1w_s + mi * 16, zv));
    #pragma unroll
    for (int c = 0; c < 16; ++c) {
        float a = fc2b_s[c];
        #pragma unroll
        for (int q = 0; q < 4; ++q) {
            a += dot16_lds(fc2w_s + c * 64 + q * 16, hv + q * 16);
        }
        xr[c] += a;
    }

    if (last) {
        const int wd = w / 49;
        const int wr2 = w - wd * 49;
        const int whh = wr2 / 7;
        const int www = wr2 - whh * 7;
        const int tz = t / 49;
        const int tr2 = t - tz * 49;
        const int ty = tr2 / 7;
        const int tx = tr2 - ty * 7;
        const int g = ((wd * 7 + tz) * 49 + (whh * 7 + ty)) * 49 + (www * 7 + tx);
        #pragma unroll
        for (int c = 0; c < 16; ++c) outp[(size_t)c * NTOK + g] = xr[c];
        return;
    }

    float4* dst = (float4*)(xe + (size_t)widx * 16);
    dst[0] = ((float4*)xr)[0]; dst[1] = ((float4*)xr)[1];
    dst[2] = ((float4*)xr)[2]; dst[3] = ((float4*)xr)[3];

    // LN1 + QKV for next block (f16 packed)
    mu = 0.f;
    #pragma unroll
    for (int c = 0; c < 16; ++c) mu += xr[c];
    mu *= 0.0625f;
    var = 0.f;
    #pragma unroll
    for (int c = 0; c < 16; ++c) { float d = xr[c] - mu; var = fmaf(d, d, var); }
    var *= 0.0625f;
    rs = rsqrtf(var + 1e-5f);
    float yv[16];
    #pragma unroll
    for (int c = 0; c < 16; ++c) yv[c] = (xr[c] - mu) * rs * n1g_s[c] + n1b_s[c];

    float tmp[16];
    #pragma unroll
    for (int rr = 0; rr < 16; ++rr) tmp[rr] = dot16_lds(qkvw_s + rr * 16, yv) * QSCALE;
    store_f16_row(qg + (size_t)(w * 2) * QPLANE, t, tmp);
    store_f16_row(qg + (size_t)(w * 2 + 1) * QPLANE, t, tmp + 8);
    #pragma unroll
    for (int rr = 0; rr < 16; ++rr) tmp[rr] = dot16_lds(qkvw_s + (16 + rr) * 16, yv);
    store_f16_row(kg + (size_t)(w * 2) * QPLANE, t, tmp);
    store_f16_row(kg + (size_t)(w * 2 + 1) * QPLANE, t, tmp + 8);
    #pragma unroll
    for (int rr = 0; rr < 16; ++rr) tmp[rr] = dot16_lds(qkvw_s + (32 + rr) * 16, yv);
    store_f16_row(vg + (size_t)(w * 2) * QPLANE, t, tmp);
    store_f16_row(vg + (size_t)(w * 2 + 1) * QPLANE, t, tmp + 8);
}

extern "C" void kernel_launch(void* const* d_in, const int* in_sizes, int n_in,
                              void* d_out, int out_size, void* d_ws, size_t ws_size,
                              hipStream_t stream) {
    const float* x       = (const float*)d_in[0];
    const float* pe_w    = (const float*)d_in[1];
    const float* pe_bias = (const float*)d_in[2];
    const float* pe_g    = (const float*)d_in[3];
    const float* pe_b    = (const float*)d_in[4];
    const float* n1_g    = (const float*)d_in[5];
    const float* n1_b    = (const float*)d_in[6];
    const float* qkv_w   = (const float*)d_in[7];
    const float* rpb     = (const float*)d_in[8];
    const float* proj_w  = (const float*)d_in[9];
    const float* proj_b  = (const float*)d_in[10];
    const float* n2_g    = (const float*)d_in[11];
    const float* n2_b    = (const float*)d_in[12];
    const float* fc1_w   = (const float*)d_in[13];
    const float* fc1_b   = (const float*)d_in[14];
    const float* fc2_w   = (const float*)d_in[15];
    const float* fc2_b   = (const float*)d_in[16];

    float* ws = (float*)d_ws;
    const size_t SEG = (size_t)NTOK * 16;     // 1,882,384 floats
    const size_t QSEG = (size_t)686 * QPLANE; // 941,192 u32
    float* xe = ws;
    u32* qg = (u32*)(ws + SEG);
    u32* kg = qg + QSEG;
    u32* vg = kg + QSEG;
    float* og = (float*)(vg + QSEG);                  // 686*2744 f32
    float* bexp = og + (size_t)686 * OPLANE;          // 6*352*352 f32
    float* out = (float*)d_out;

    k_bias_expand<<<6 * NPAD, 384, 0, stream>>>(rpb, bexp);

    k0_patch_qkv<<<(NTOK + 255) / 256, 256, 0, stream>>>(
        x, pe_w, pe_bias, pe_g, pe_b, n1_g, n1_b, qkv_w, xe, qg, kg, vg);

    for (int i = 0; i < 3; ++i) {
        const int last = (i == 2) ? 1 : 0;
        const int nx = last ? i : i + 1;
        k_attn<<<686, 512, 0, stream>>>(
            qg, kg, vg, og, bexp + (size_t)i * 2 * NPAD * NPAD);
        k_post<<<(NTOK + 255) / 256, 256, 0, stream>>>(
            xe, og, qg, kg, vg,
            proj_w + (size_t)i * 256, proj_b + (size_t)i * 16,
            n2_g + (size_t)i * 16, n2_b + (size_t)i * 16,
            fc1_w + (size_t)i * 1024, fc1_b + (size_t)i * 64,
            fc2_w + (size_t)i * 1024, fc2_b + (size_t)i * 16,
            n1_g + (size_t)nx * 16, n1_b + (size_t)nx * 16,
            qkv_w + (size_t)nx * 768,
            out, last);
    }
}

// Round 11
// 255.341 us; speedup vs baseline: 1.1528x; 1.0187x over previous
//
#include <hip/hip_runtime.h>
#include <math.h>

#define NWTOK 343
#define NTOK 117649
#define QSCALE 0.510069734f   // (1/sqrt(8)) * log2(e)
#define LOG2E 1.4426950408889634f
#define QPLANE 1372   // u32 per (window,head) plane of f16 rows
#define OPLANE 2744   // f32 per (window,head) plane of o
#define NPAD 352

typedef unsigned int u32;
typedef __fp16 h2 __attribute__((ext_vector_type(2)));
typedef __fp16 h4 __attribute__((ext_vector_type(4)));
typedef float f32x4 __attribute__((ext_vector_type(4)));

__device__ __forceinline__ u32 packh2(float a, float b) {
    h2 h = __builtin_amdgcn_cvt_pkrtz(a, b);
    return __builtin_bit_cast(u32, h);
}
__device__ __forceinline__ float fast_exp2(float x) {
#if __has_builtin(__builtin_amdgcn_exp2f)
    return __builtin_amdgcn_exp2f(x);
#else
    return exp2f(x);
#endif
}

// dot of v[16] with 16 consecutive LDS floats via 4x ds_read_b128
__device__ __forceinline__ float dot16_lds(const float* __restrict__ wrow,
                                           const float* __restrict__ v) {
    const float4 w0 = *(const float4*)(wrow);
    const float4 w1 = *(const float4*)(wrow + 4);
    const float4 w2 = *(const float4*)(wrow + 8);
    const float4 w3 = *(const float4*)(wrow + 12);
    float a = v[0] * w0.x;
    a = fmaf(v[1], w0.y, a); a = fmaf(v[2], w0.z, a); a = fmaf(v[3], w0.w, a);
    a = fmaf(v[4], w1.x, a); a = fmaf(v[5], w1.y, a); a = fmaf(v[6], w1.z, a);
    a = fmaf(v[7], w1.w, a);
    a = fmaf(v[8], w2.x, a); a = fmaf(v[9], w2.y, a); a = fmaf(v[10], w2.z, a);
    a = fmaf(v[11], w2.w, a);
    a = fmaf(v[12], w3.x, a); a = fmaf(v[13], w3.y, a); a = fmaf(v[14], w3.z, a);
    a = fmaf(v[15], w3.w, a);
    return a;
}

// Inline exact-GELU via Abramowitz-Stegun 7.1.26 erf (max abs err 1.5e-7).
__device__ __forceinline__ float gelu_exact(float x) {
    const float z = x * 0.70710678118654752f;
    const float az = fabsf(z);
    const float t = __builtin_amdgcn_rcpf(fmaf(0.3275911f, az, 1.0f));
    float y = fmaf(t, 1.061405429f, -1.453152027f);
    y = fmaf(t, y, 1.421413741f);
    y = fmaf(t, y, -0.284496736f);
    y = fmaf(t, y, 0.254829592f);
    y *= t;
    const float one_m_erf = y * __expf(-az * az);
    const float erf_az = 1.0f - one_m_erf;
    const float erf_z = (z < 0.f) ? -erf_az : erf_az;
    return 0.5f * x * (1.0f + erf_z);
}

__device__ __forceinline__ void store_f16_row(u32* base, int t, const float* v8) {
    uint4 u;
    u.x = packh2(v8[0], v8[1]); u.y = packh2(v8[2], v8[3]);
    u.z = packh2(v8[4], v8[5]); u.w = packh2(v8[6], v8[7]);
    *(uint4*)(base + t * 4) = u;
}

// ------- bias expand: bexp[blk*2+h][i(352)][j(352)] = rpb[rpi(i,j)][h]*log2e -------
__global__ __launch_bounds__(384) void k_bias_expand(
    const float* __restrict__ rpb,   // (3, 2197, 2)
    float* __restrict__ bexp)
{
    const int b = blockIdx.x;        // bh*352 + i
    const int bh = b / NPAD;
    const int i = b - bh * NPAD;
    const int blk = bh >> 1, h = bh & 1;
    const int j = threadIdx.x;
    if (j >= NPAD) return;
    float val;
    if (j >= NWTOK) {
        val = -60.f;
    } else if (i >= NWTOK) {
        val = 0.f;
    } else {
        const int iz = i / 49, ir = i - iz * 49, iy = ir / 7, ix = ir - iy * 7;
        const int jz = j / 49, jr = j - jz * 49, jy = jr / 7, jx = jr - jy * 7;
        const int idx = (iz - jz + 6) * 169 + (iy - jy + 6) * 13 + (ix - jx + 6);
        val = rpb[((size_t)blk * 2197 + idx) * 2 + h] * LOG2E;
    }
    bexp[((size_t)bh * NPAD + i) * NPAD + j] = val;
}

// ---------------- K0: patch embed + LN + LN1 + QKV(block 0) ----------------
__global__ __launch_bounds__(256, 2) void k0_patch_qkv(
    const float* __restrict__ x,
    const float* __restrict__ pe_w,
    const float* __restrict__ pe_bias,
    const float* __restrict__ pe_g,
    const float* __restrict__ pe_b,
    const float* __restrict__ n1_g,
    const float* __restrict__ n1_b,
    const float* __restrict__ qkv_w,
    float* __restrict__ xe,
    u32* __restrict__ qg,
    u32* __restrict__ kg,
    u32* __restrict__ vg)
{
    __shared__ float w_s[128];
    __shared__ float pb_s[16], g_s[16], b_s[16], n1g_s[16], n1b_s[16];
    __shared__ float qkvw_s[768];
    const int tid = threadIdx.x;
    if (tid < 128) w_s[tid] = pe_w[tid];
    if (tid < 16) {
        pb_s[tid] = pe_bias[tid]; g_s[tid] = pe_g[tid]; b_s[tid] = pe_b[tid];
        n1g_s[tid] = n1_g[tid]; n1b_s[tid] = n1_b[tid];
    }
    for (int i = tid; i < 768; i += 256) qkvw_s[i] = qkv_w[i];
    __syncthreads();
    const int g = blockIdx.x * 256 + tid;
    if (g >= NTOK) return;
    const int z = g / 2401;
    const int r = g - z * 2401;
    const int y = r / 49;
    const int xx = r - y * 49;
    const float* bp = x + ((2 * z) * 98 + (2 * y)) * 98 + 2 * xx;
    float in[8];
    in[0] = bp[0];    in[1] = bp[1];
    in[2] = bp[98];   in[3] = bp[99];
    in[4] = bp[9604]; in[5] = bp[9605];
    in[6] = bp[9702]; in[7] = bp[9703];
    float v[16];
    float mu = 0.f;
    #pragma unroll
    for (int c = 0; c < 16; ++c) {
        float a = pb_s[c];
        #pragma unroll
        for (int k = 0; k < 8; ++k) a = fmaf(in[k], w_s[c * 8 + k], a);
        v[c] = a; mu += a;
    }
    mu *= 0.0625f;
    float var = 0.f;
    #pragma unroll
    for (int c = 0; c < 16; ++c) { float d = v[c] - mu; var = fmaf(d, d, var); }
    var *= 0.0625f;
    float rs = rsqrtf(var + 1e-5f);
    float o[16];
    #pragma unroll
    for (int c = 0; c < 16; ++c) o[c] = (v[c] - mu) * rs * g_s[c] + b_s[c];

    const int zw = z / 7, zi = z - zw * 7;
    const int yw = y / 7, yi = y - yw * 7;
    const int xw = xx / 7, xi = xx - xw * 7;
    const int w = (zw * 7 + yw) * 7 + xw;
    const int t = (zi * 7 + yi) * 7 + xi;
    const int widx = w * NWTOK + t;

    float4* dst = (float4*)(xe + (size_t)widx * 16);
    dst[0] = ((float4*)o)[0]; dst[1] = ((float4*)o)[1];
    dst[2] = ((float4*)o)[2]; dst[3] = ((float4*)o)[3];

    mu = 0.f;
    #pragma unroll
    for (int c = 0; c < 16; ++c) mu += o[c];
    mu *= 0.0625f;
    var = 0.f;
    #pragma unroll
    for (int c = 0; c < 16; ++c) { float d = o[c] - mu; var = fmaf(d, d, var); }
    var *= 0.0625f;
    rs = rsqrtf(var + 1e-5f);
    float yv[16];
    #pragma unroll
    for (int c = 0; c < 16; ++c) yv[c] = (o[c] - mu) * rs * n1g_s[c] + n1b_s[c];

    float tmp[16];
    #pragma unroll
    for (int rr = 0; rr < 16; ++rr) tmp[rr] = dot16_lds(qkvw_s + rr * 16, yv) * QSCALE;
    store_f16_row(qg + (size_t)(w * 2) * QPLANE, t, tmp);
    store_f16_row(qg + (size_t)(w * 2 + 1) * QPLANE, t, tmp + 8);
    #pragma unroll
    for (int rr = 0; rr < 16; ++rr) tmp[rr] = dot16_lds(qkvw_s + (16 + rr) * 16, yv);
    store_f16_row(kg + (size_t)(w * 2) * QPLANE, t, tmp);
    store_f16_row(kg + (size_t)(w * 2 + 1) * QPLANE, t, tmp + 8);
    #pragma unroll
    for (int rr = 0; rr < 16; ++rr) tmp[rr] = dot16_lds(qkvw_s + (32 + rr) * 16, yv);
    store_f16_row(vg + (size_t)(w * 2) * QPLANE, t, tmp);
    store_f16_row(vg + (size_t)(w * 2 + 1) * QPLANE, t, tmp + 8);
}

// ---- K_attn (MFMA): WG per (window,head); 11 waves; EXACTLY one qt-pair/wave ----
// Balance fix: R8/R10 gave 3 of 8 waves double work (critical path 2x). Here
// wave w owns pair p=w -> identical work per wave, no early-exit waves.
__global__ __launch_bounds__(704, 6) void k_attn(
    const u32* __restrict__ qg,
    const u32* __restrict__ kg,
    const u32* __restrict__ vg,
    float* __restrict__ og,
    const float* __restrict__ bexp)   // this block's [2][352][352]
{
    __shared__ __fp16 Kl[NPAD][16];
    __shared__ __fp16 Ql[NPAD][16];
    __shared__ __fp16 Vt[16][360];

    const int tid = threadIdx.x;
    const int wh = blockIdx.x;
    const int h = wh & 1;
    const size_t qpl = (size_t)wh * QPLANE;

    if (tid < NPAD) {
        const uint4 z4 = make_uint4(0, 0, 0, 0);
        if (tid < NWTOK) {
            const uint4 kw = ((const uint4*)(kg + qpl))[tid];
            const uint4 qw = ((const uint4*)(qg + qpl))[tid];
            const uint4 vw = ((const uint4*)(vg + qpl))[tid];
            *(uint4*)&Kl[tid][0] = kw; *(uint4*)&Kl[tid][8] = z4;
            *(uint4*)&Ql[tid][0] = qw; *(uint4*)&Ql[tid][8] = z4;
            const h2 v01 = __builtin_bit_cast(h2, vw.x);
            const h2 v23 = __builtin_bit_cast(h2, vw.y);
            const h2 v45 = __builtin_bit_cast(h2, vw.z);
            const h2 v67 = __builtin_bit_cast(h2, vw.w);
            Vt[0][tid] = v01.x; Vt[1][tid] = v01.y;
            Vt[2][tid] = v23.x; Vt[3][tid] = v23.y;
            Vt[4][tid] = v45.x; Vt[5][tid] = v45.y;
            Vt[6][tid] = v67.x; Vt[7][tid] = v67.y;
        } else {
            *(uint4*)&Kl[tid][0] = z4; *(uint4*)&Kl[tid][8] = z4;
            *(uint4*)&Ql[tid][0] = z4; *(uint4*)&Ql[tid][8] = z4;
            #pragma unroll
            for (int d = 0; d < 8; ++d) Vt[d][tid] = (__fp16)0.f;
        }
        #pragma unroll
        for (int d = 8; d < 16; ++d) Vt[d][tid] = (__fp16)0.f;
    }
    __syncthreads();

    const int wave = tid >> 6;        // 0..10 == pair index
    const int lane = tid & 63;
    const int n = lane & 15;
    const int g4 = (lane >> 4) * 4;

    const int qiA = (2 * wave) * 16 + n;
    const int qiB = qiA + 16;
    const h4 bqA = *(const h4*)&Ql[qiA][g4];
    const h4 bqB = *(const h4*)&Ql[qiB][g4];
    const float* browA = bexp + ((size_t)h * NPAD + qiA) * NPAD;
    const float* browB = browA + (size_t)16 * NPAD;
    f32x4 accA = {0.f, 0.f, 0.f, 0.f};
    f32x4 accB = {0.f, 0.f, 0.f, 0.f};
    float lA = 0.f, lB = 0.f;
    #pragma unroll
    for (int kt = 0; kt < 22; ++kt) {
        const h4 ak = *(const h4*)&Kl[kt * 16 + n][g4];
        const h4 av = *(const h4*)&Vt[n][kt * 16 + g4];
        const f32x4 cbA = *(const f32x4*)(browA + kt * 16 + g4);
        const f32x4 cbB = *(const f32x4*)(browB + kt * 16 + g4);
        f32x4 sA = __builtin_amdgcn_mfma_f32_16x16x16f16(ak, bqA, cbA, 0, 0, 0);
        f32x4 sB = __builtin_amdgcn_mfma_f32_16x16x16f16(ak, bqB, cbB, 0, 0, 0);
        const float pA0 = fast_exp2(sA[0]);
        const float pA1 = fast_exp2(sA[1]);
        const float pA2 = fast_exp2(sA[2]);
        const float pA3 = fast_exp2(sA[3]);
        const float pB0 = fast_exp2(sB[0]);
        const float pB1 = fast_exp2(sB[1]);
        const float pB2 = fast_exp2(sB[2]);
        const float pB3 = fast_exp2(sB[3]);
        lA += (pA0 + pA1) + (pA2 + pA3);
        lB += (pB0 + pB1) + (pB2 + pB3);
        const h4 bpA = __builtin_bit_cast(h4,
            make_uint2(packh2(pA0, pA1), packh2(pA2, pA3)));
        const h4 bpB = __builtin_bit_cast(h4,
            make_uint2(packh2(pB0, pB1), packh2(pB2, pB3)));
        accA = __builtin_amdgcn_mfma_f32_16x16x16f16(av, bpA, accA, 0, 0, 0);
        accB = __builtin_amdgcn_mfma_f32_16x16x16f16(av, bpB, accB, 0, 0, 0);
    }
    lA += __shfl_xor(lA, 16);
    lA += __shfl_xor(lA, 32);
    lB += __shfl_xor(lB, 16);
    lB += __shfl_xor(lB, 32);
    if (g4 < 8) {
        if (qiA < NWTOK) {
            const f32x4 o = accA * (1.f / lA);
            *(f32x4*)(og + (size_t)wh * OPLANE + qiA * 8 + g4) = o;
        }
        if (qiB < NWTOK) {
            const f32x4 o = accB * (1.f / lB);
            *(f32x4*)(og + (size_t)wh * OPLANE + qiB * 8 + g4) = o;
        }
    }
}

// ------- K_post: proj + residual + LN2 + MLP (+ next LN1+QKV or output) -------
__global__ __launch_bounds__(256, 4) void k_post(
    float* __restrict__ xe,
    const float* __restrict__ og,
    u32* __restrict__ qg,
    u32* __restrict__ kg,
    u32* __restrict__ vg,
    const float* __restrict__ proj_w,
    const float* __restrict__ proj_b,
    const float* __restrict__ n2_g,
    const float* __restrict__ n2_b,
    const float* __restrict__ fc1_w,
    const float* __restrict__ fc1_b,
    const float* __restrict__ fc2_w,
    const float* __restrict__ fc2_b,
    const float* __restrict__ n1_g_nx,
    const float* __restrict__ n1_b_nx,
    const float* __restrict__ qkv_w_nx,
    float* __restrict__ outp,
    const int last)
{
    __shared__ float projw_s[256];
    __shared__ float fc1w_s[1024];
    __shared__ float fc2w_s[1024];
    __shared__ float qkvw_s[768];
    __shared__ float projb_s[16], n2g_s[16], n2b_s[16], fc2b_s[16], n1g_s[16], n1b_s[16];
    __shared__ float fc1b_s[64];
    const int tid = threadIdx.x;
    if (tid < 256) projw_s[tid] = proj_w[tid];
    for (int i = tid; i < 1024; i += 256) { fc1w_s[i] = fc1_w[i]; fc2w_s[i] = fc2_w[i]; }
    for (int i = tid; i < 768; i += 256) qkvw_s[i] = qkv_w_nx[i];
    if (tid < 16) {
        projb_s[tid] = proj_b[tid];
        n2g_s[tid] = n2_g[tid]; n2b_s[tid] = n2_b[tid];
        fc2b_s[tid] = fc2_b[tid];
        n1g_s[tid] = n1_g_nx[tid]; n1b_s[tid] = n1_b_nx[tid];
    }
    if (tid < 64) fc1b_s[tid] = fc1_b[tid];
    __syncthreads();

    const int widx = blockIdx.x * 256 + tid;
    if (widx >= NTOK) return;
    const int w = widx / NWTOK;
    const int t = widx - w * NWTOK;

    float o[16];
    const float* o0 = og + (size_t)(w * 2) * OPLANE + t * 8;
    const float* o1 = og + (size_t)(w * 2 + 1) * OPLANE + t * 8;
    ((float4*)o)[0] = ((const float4*)o0)[0]; ((float4*)o)[1] = ((const float4*)o0)[1];
    ((float4*)o)[2] = ((const float4*)o1)[0]; ((float4*)o)[3] = ((const float4*)o1)[1];

    float xr[16];
    const float4* xs = (const float4*)(xe + (size_t)widx * 16);
    ((float4*)xr)[0] = xs[0]; ((float4*)xr)[1] = xs[1];
    ((float4*)xr)[2] = xs[2]; ((float4*)xr)[3] = xs[3];

    #pragma unroll
    for (int c = 0; c < 16; ++c) xr[c] += projb_s[c] + dot16_lds(projw_s + c * 16, o);

    float mu = 0.f;
    #pragma unroll
    for (int c = 0; c < 16; ++c) mu += xr[c];
    mu *= 0.0625f;
    float var = 0.f;
    #pragma unroll
    for (int c = 0; c < 16; ++c) { float d = xr[c] - mu; var = fmaf(d, d, var); }
    var *= 0.0625f;
    float rs = rsqrtf(var + 1e-5f);
    float zv[16];
    #pragma unroll
    for (int c = 0; c < 16; ++c) zv[c] = (xr[c] - mu) * rs * n2g_s[c] + n2b_s[c];

    float accm[16];
    #pragma unroll
    for (int c = 0; c < 16; ++c) accm[c] = fc2b_s[c];
    #pragma unroll
    for (int ch = 0; ch < 4; ++ch) {
        float hv[16];
        #pragma unroll
        for (int mm = 0; mm < 16; ++mm) {
            const int mi = ch * 16 + mm;
            hv[mm] = gelu_exact(fc1b_s[mi] + dot16_lds(fc1w_s + mi * 16, zv));
        }
        #pragma unroll
        for (int c = 0; c < 16; ++c)
            accm[c] += dot16_lds(fc2w_s + c * 64 + ch * 16, hv);
    }
    #pragma unroll
    for (int c = 0; c < 16; ++c) xr[c] += accm[c];

    if (last) {
        const int wd = w / 49;
        const int wr2 = w - wd * 49;
        const int whh = wr2 / 7;
        const int www = wr2 - whh * 7;
        const int tz = t / 49;
        const int tr2 = t - tz * 49;
        const int ty = tr2 / 7;
        const int tx = tr2 - ty * 7;
        const int g = ((wd * 7 + tz) * 49 + (whh * 7 + ty)) * 49 + (www * 7 + tx);
        #pragma unroll
        for (int c = 0; c < 16; ++c) outp[(size_t)c * NTOK + g] = xr[c];
        return;
    }

    float4* dst = (float4*)(xe + (size_t)widx * 16);
    dst[0] = ((float4*)xr)[0]; dst[1] = ((float4*)xr)[1];
    dst[2] = ((float4*)xr)[2]; dst[3] = ((float4*)xr)[3];

    // LN1 + QKV for next block (f16 packed)
    mu = 0.f;
    #pragma unroll
    for (int c = 0; c < 16; ++c) mu += xr[c];
    mu *= 0.0625f;
    var = 0.f;
    #pragma unroll
    for (int c = 0; c < 16; ++c) { float d = xr[c] - mu; var = fmaf(d, d, var); }
    var *= 0.0625f;
    rs = rsqrtf(var + 1e-5f);
    float yv[16];
    #pragma unroll
    for (int c = 0; c < 16; ++c) yv[c] = (xr[c] - mu) * rs * n1g_s[c] + n1b_s[c];

    float tmp[16];
    #pragma unroll
    for (int rr = 0; rr < 16; ++rr) tmp[rr] = dot16_lds(qkvw_s + rr * 16, yv) * QSCALE;
    store_f16_row(qg + (size_t)(w * 2) * QPLANE, t, tmp);
    store_f16_row(qg + (size_t)(w * 2 + 1) * QPLANE, t, tmp + 8);
    #pragma unroll
    for (int rr = 0; rr < 16; ++rr) tmp[rr] = dot16_lds(qkvw_s + (16 + rr) * 16, yv);
    store_f16_row(kg + (size_t)(w * 2) * QPLANE, t, tmp);
    store_f16_row(kg + (size_t)(w * 2 + 1) * QPLANE, t, tmp + 8);
    #pragma unroll
    for (int rr = 0; rr < 16; ++rr) tmp[rr] = dot16_lds(qkvw_s + (32 + rr) * 16, yv);
    store_f16_row(vg + (size_t)(w * 2) * QPLANE, t, tmp);
    store_f16_row(vg + (size_t)(w * 2 + 1) * QPLANE, t, tmp + 8);
}

extern "C" void kernel_launch(void* const* d_in, const int* in_sizes, int n_in,
                              void* d_out, int out_size, void* d_ws, size_t ws_size,
                              hipStream_t stream) {
    const float* x       = (const float*)d_in[0];
    const float* pe_w    = (const float*)d_in[1];
    const float* pe_bias = (const float*)d_in[2];
    const float* pe_g    = (const float*)d_in[3];
    const float* pe_b    = (const float*)d_in[4];
    const float* n1_g    = (const float*)d_in[5];
    const float* n1_b    = (const float*)d_in[6];
    const float* qkv_w   = (const float*)d_in[7];
    const float* rpb     = (const float*)d_in[8];
    const float* proj_w  = (const float*)d_in[9];
    const float* proj_b  = (const float*)d_in[10];
    const float* n2_g    = (const float*)d_in[11];
    const float* n2_b    = (const float*)d_in[12];
    const float* fc1_w   = (const float*)d_in[13];
    const float* fc1_b   = (const float*)d_in[14];
    const float* fc2_w   = (const float*)d_in[15];
    const float* fc2_b   = (const float*)d_in[16];

    float* ws = (float*)d_ws;
    const size_t SEG = (size_t)NTOK * 16;     // 1,882,384 floats
    const size_t QSEG = (size_t)686 * QPLANE; // 941,192 u32
    float* xe = ws;
    u32* qg = (u32*)(ws + SEG);
    u32* kg = qg + QSEG;
    u32* vg = kg + QSEG;
    float* og = (float*)(vg + QSEG);                  // 686*2744 f32
    float* bexp = og + (size_t)686 * OPLANE;          // 6*352*352 f32
    float* out = (float*)d_out;

    k_bias_expand<<<6 * NPAD, 384, 0, stream>>>(rpb, bexp);

    k0_patch_qkv<<<(NTOK + 255) / 256, 256, 0, stream>>>(
        x, pe_w, pe_bias, pe_g, pe_b, n1_g, n1_b, qkv_w, xe, qg, kg, vg);

    for (int i = 0; i < 3; ++i) {
        const int last = (i == 2) ? 1 : 0;
        const int nx = last ? i : i + 1;
        k_attn<<<686, 704, 0, stream>>>(
            qg, kg, vg, og, bexp + (size_t)i * 2 * NPAD * NPAD);
        k_post<<<(NTOK + 255) / 256, 256, 0, stream>>>(
            xe, og, qg, kg, vg,
            proj_w + (size_t)i * 256, proj_b + (size_t)i * 16,
            n2_g + (size_t)i * 16, n2_b + (size_t)i * 16,
            fc1_w + (size_t)i * 1024, fc1_b + (size_t)i * 64,
            fc2_w + (size_t)i * 1024, fc2_b + (size_t)i * 16,
            n1_g + (size_t)nx * 16, n1_b + (size_t)nx * 16,
            qkv_w + (size_t)nx * 768,
            out, last);
    }
}

// Round 12
// 215.868 us; speedup vs baseline: 1.3636x; 1.1829x over previous
//
#include <hip/hip_runtime.h>
#include <math.h>

#define NWTOK 343
#define NTOK 117649
#define QSCALE 0.510069734f   // (1/sqrt(8)) * log2(e)
#define LOG2E 1.4426950408889634f
#define QPLANE 1372   // u32 per (window,head) plane of f16 rows
#define OPLANE 2744   // f32 per (window,head) plane of o
#define NPAD 352
#define NTILE 22

typedef unsigned int u32;
typedef __fp16 h2 __attribute__((ext_vector_type(2)));
typedef __fp16 h4 __attribute__((ext_vector_type(4)));
typedef float f32x4 __attribute__((ext_vector_type(4)));

__device__ __forceinline__ u32 packh2(float a, float b) {
    h2 h = __builtin_amdgcn_cvt_pkrtz(a, b);
    return __builtin_bit_cast(u32, h);
}
__device__ __forceinline__ float fast_exp2(float x) {
#if __has_builtin(__builtin_amdgcn_exp2f)
    return __builtin_amdgcn_exp2f(x);
#else
    return exp2f(x);
#endif
}

// dot of v[16] with 16 consecutive floats (global, wave-uniform address -> s_load)
__device__ __forceinline__ float dot16g(const float* __restrict__ wrow,
                                        const float* __restrict__ v) {
    const float4 w0 = *(const float4*)(wrow);
    const float4 w1 = *(const float4*)(wrow + 4);
    const float4 w2 = *(const float4*)(wrow + 8);
    const float4 w3 = *(const float4*)(wrow + 12);
    float a = v[0] * w0.x;
    a = fmaf(v[1], w0.y, a); a = fmaf(v[2], w0.z, a); a = fmaf(v[3], w0.w, a);
    a = fmaf(v[4], w1.x, a); a = fmaf(v[5], w1.y, a); a = fmaf(v[6], w1.z, a);
    a = fmaf(v[7], w1.w, a);
    a = fmaf(v[8], w2.x, a); a = fmaf(v[9], w2.y, a); a = fmaf(v[10], w2.z, a);
    a = fmaf(v[11], w2.w, a);
    a = fmaf(v[12], w3.x, a); a = fmaf(v[13], w3.y, a); a = fmaf(v[14], w3.z, a);
    a = fmaf(v[15], w3.w, a);
    return a;
}

// Inline exact-GELU via Abramowitz-Stegun 7.1.26 erf (max abs err 1.5e-7).
__device__ __forceinline__ float gelu_exact(float x) {
    const float z = x * 0.70710678118654752f;
    const float az = fabsf(z);
    const float t = __builtin_amdgcn_rcpf(fmaf(0.3275911f, az, 1.0f));
    float y = fmaf(t, 1.061405429f, -1.453152027f);
    y = fmaf(t, y, 1.421413741f);
    y = fmaf(t, y, -0.284496736f);
    y = fmaf(t, y, 0.254829592f);
    y *= t;
    const float one_m_erf = y * __expf(-az * az);
    const float erf_az = 1.0f - one_m_erf;
    const float erf_z = (z < 0.f) ? -erf_az : erf_az;
    return 0.5f * x * (1.0f + erf_z);
}

__device__ __forceinline__ void store_f16_row(u32* base, int t, const float* v8) {
    uint4 u;
    u.x = packh2(v8[0], v8[1]); u.y = packh2(v8[2], v8[3]);
    u.z = packh2(v8[4], v8[5]); u.w = packh2(v8[6], v8[7]);
    *(uint4*)(base + t * 4) = u;
}

// ---- bias expand, f16 TILED: bexp16[((bh)*484 + qt*22 + kt)*256 + n*16 + g] ----
// One tile = 512B contiguous -> 8 cache lines per tile instead of 16.
__global__ __launch_bounds__(256) void k_bias_expand(
    const float* __restrict__ rpb,   // (3, 2197, 2)
    __fp16* __restrict__ bexp16)
{
    const int tile = blockIdx.x;     // ((blk*2+h)*22 + qt)*22 + kt
    const int kt = tile % NTILE;
    const int rest = tile / NTILE;
    const int qt = rest % NTILE;
    const int bh = rest / NTILE;
    const int blk = bh >> 1, h = bh & 1;
    const int tid = threadIdx.x;     // n*16 + g
    const int n = tid >> 4, g = tid & 15;
    const int i = qt * 16 + n, j = kt * 16 + g;
    float val;
    if (j >= NWTOK) {
        val = -60.f;                 // key padding -> exp2 ~ 0
    } else if (i >= NWTOK) {
        val = 0.f;                   // query padding, never stored
    } else {
        const int iz = i / 49, ir = i - iz * 49, iy = ir / 7, ix = ir - iy * 7;
        const int jz = j / 49, jr = j - jz * 49, jy = jr / 7, jx = jr - jy * 7;
        const int idx = (iz - jz + 6) * 169 + (iy - jy + 6) * 13 + (ix - jx + 6);
        val = rpb[((size_t)blk * 2197 + idx) * 2 + h] * LOG2E;
    }
    bexp16[(size_t)tile * 256 + tid] = (__fp16)val;
}

// ---------------- K0: patch embed + LN + LN1 + QKV(block 0) ----------------
__global__ __launch_bounds__(256, 2) void k0_patch_qkv(
    const float* __restrict__ x,
    const float* __restrict__ pe_w,
    const float* __restrict__ pe_bias,
    const float* __restrict__ pe_g,
    const float* __restrict__ pe_b,
    const float* __restrict__ n1_g,
    const float* __restrict__ n1_b,
    const float* __restrict__ qkv_w,
    float* __restrict__ xe,
    u32* __restrict__ qg,
    u32* __restrict__ kg,
    u32* __restrict__ vg)
{
    const int tid = threadIdx.x;
    const int g = blockIdx.x * 256 + tid;
    if (g >= NTOK) return;
    const int z = g / 2401;
    const int r = g - z * 2401;
    const int y = r / 49;
    const int xx = r - y * 49;
    const float* bp = x + ((2 * z) * 98 + (2 * y)) * 98 + 2 * xx;
    float in[8];
    in[0] = bp[0];    in[1] = bp[1];
    in[2] = bp[98];   in[3] = bp[99];
    in[4] = bp[9604]; in[5] = bp[9605];
    in[6] = bp[9702]; in[7] = bp[9703];
    float v[16];
    float mu = 0.f;
    #pragma unroll
    for (int c = 0; c < 16; ++c) {
        float a = pe_bias[c];
        #pragma unroll
        for (int k = 0; k < 8; ++k) a = fmaf(in[k], pe_w[c * 8 + k], a);
        v[c] = a; mu += a;
    }
    mu *= 0.0625f;
    float var = 0.f;
    #pragma unroll
    for (int c = 0; c < 16; ++c) { float d = v[c] - mu; var = fmaf(d, d, var); }
    var *= 0.0625f;
    float rs = rsqrtf(var + 1e-5f);
    float o[16];
    #pragma unroll
    for (int c = 0; c < 16; ++c) o[c] = (v[c] - mu) * rs * pe_g[c] + pe_b[c];

    const int zw = z / 7, zi = z - zw * 7;
    const int yw = y / 7, yi = y - yw * 7;
    const int xw = xx / 7, xi = xx - xw * 7;
    const int w = (zw * 7 + yw) * 7 + xw;
    const int t = (zi * 7 + yi) * 7 + xi;
    const int widx = w * NWTOK + t;

    float4* dst = (float4*)(xe + (size_t)widx * 16);
    dst[0] = ((float4*)o)[0]; dst[1] = ((float4*)o)[1];
    dst[2] = ((float4*)o)[2]; dst[3] = ((float4*)o)[3];

    mu = 0.f;
    #pragma unroll
    for (int c = 0; c < 16; ++c) mu += o[c];
    mu *= 0.0625f;
    var = 0.f;
    #pragma unroll
    for (int c = 0; c < 16; ++c) { float d = o[c] - mu; var = fmaf(d, d, var); }
    var *= 0.0625f;
    rs = rsqrtf(var + 1e-5f);
    float yv[16];
    #pragma unroll
    for (int c = 0; c < 16; ++c) yv[c] = (o[c] - mu) * rs * n1_g[c] + n1_b[c];

    float tmp[16];
    #pragma unroll
    for (int rr = 0; rr < 16; ++rr) tmp[rr] = dot16g(qkv_w + rr * 16, yv) * QSCALE;
    store_f16_row(qg + (size_t)(w * 2) * QPLANE, t, tmp);
    store_f16_row(qg + (size_t)(w * 2 + 1) * QPLANE, t, tmp + 8);
    #pragma unroll
    for (int rr = 0; rr < 16; ++rr) tmp[rr] = dot16g(qkv_w + (16 + rr) * 16, yv);
    store_f16_row(kg + (size_t)(w * 2) * QPLANE, t, tmp);
    store_f16_row(kg + (size_t)(w * 2 + 1) * QPLANE, t, tmp + 8);
    #pragma unroll
    for (int rr = 0; rr < 16; ++rr) tmp[rr] = dot16g(qkv_w + (32 + rr) * 16, yv);
    store_f16_row(vg + (size_t)(w * 2) * QPLANE, t, tmp);
    store_f16_row(vg + (size_t)(w * 2 + 1) * QPLANE, t, tmp + 8);
}

// ---- K_attn: WG = (window-pair, head); 11 waves; 1 qt-pair/wave x 2 windows ----
// Bias tile (depends only on qt,kt,h) loaded ONCE, shared by both windows.
__global__ __launch_bounds__(704, 5) void k_attn(
    const u32* __restrict__ qg,
    const u32* __restrict__ kg,
    const u32* __restrict__ vg,
    float* __restrict__ og,
    const __fp16* __restrict__ bexp_blk)   // this block's [2][22][22][256] f16 tiles
{
    __shared__ __fp16 Kl[2][NPAD][16];
    __shared__ __fp16 Ql[2][NPAD][16];
    __shared__ __fp16 Vt[2][16][360];

    const int tid = threadIdx.x;
    const int pidx = blockIdx.x;
    const int wp = pidx >> 1;
    const int h = pidx & 1;
    const int w0 = 2 * wp;
    const int w1 = (w0 + 1 < NWTOK) ? w0 + 1 : NWTOK - 1;
    const int wh0 = w0 * 2 + h;
    const int wh1 = w1 * 2 + h;

    // staging: threads 0..351 -> window slot 0, 352..703 -> slot 1
    {
        const int sw = (tid >= NPAD) ? 1 : 0;
        const int st = tid - sw * NPAD;
        const size_t qpl = (size_t)(sw ? wh1 : wh0) * QPLANE;
        const uint4 z4 = make_uint4(0, 0, 0, 0);
        if (st < NWTOK) {
            const uint4 kw = ((const uint4*)(kg + qpl))[st];
            const uint4 qw = ((const uint4*)(qg + qpl))[st];
            const uint4 vw = ((const uint4*)(vg + qpl))[st];
            *(uint4*)&Kl[sw][st][0] = kw; *(uint4*)&Kl[sw][st][8] = z4;
            *(uint4*)&Ql[sw][st][0] = qw; *(uint4*)&Ql[sw][st][8] = z4;
            const h2 v01 = __builtin_bit_cast(h2, vw.x);
            const h2 v23 = __builtin_bit_cast(h2, vw.y);
            const h2 v45 = __builtin_bit_cast(h2, vw.z);
            const h2 v67 = __builtin_bit_cast(h2, vw.w);
            Vt[sw][0][st] = v01.x; Vt[sw][1][st] = v01.y;
            Vt[sw][2][st] = v23.x; Vt[sw][3][st] = v23.y;
            Vt[sw][4][st] = v45.x; Vt[sw][5][st] = v45.y;
            Vt[sw][6][st] = v67.x; Vt[sw][7][st] = v67.y;
        } else {
            *(uint4*)&Kl[sw][st][0] = z4; *(uint4*)&Kl[sw][st][8] = z4;
            *(uint4*)&Ql[sw][st][0] = z4; *(uint4*)&Ql[sw][st][8] = z4;
            #pragma unroll
            for (int d = 0; d < 8; ++d) Vt[sw][d][st] = (__fp16)0.f;
        }
        #pragma unroll
        for (int d = 8; d < 16; ++d) Vt[sw][d][st] = (__fp16)0.f;
    }
    __syncthreads();

    const int wave = tid >> 6;        // 0..10 == qt-pair index
    const int lane = tid & 63;
    const int n = lane & 15;
    const int g4 = (lane >> 4) * 4;

    const int qiA = (2 * wave) * 16 + n;
    const int qiB = qiA + 16;
    const h4 bqA0 = *(const h4*)&Ql[0][qiA][g4];
    const h4 bqB0 = *(const h4*)&Ql[0][qiB][g4];
    const h4 bqA1 = *(const h4*)&Ql[1][qiA][g4];
    const h4 bqB1 = *(const h4*)&Ql[1][qiB][g4];

    const int laneoff = n * 16 + g4;  // f16 elements within a 256-elem tile
    const __fp16* trowA = bexp_blk + ((size_t)(h * 484) + (size_t)(2 * wave) * NTILE) * 256 + laneoff;
    const __fp16* trowB = trowA + (size_t)NTILE * 256;

    f32x4 accA0 = {0.f, 0.f, 0.f, 0.f}, accB0 = {0.f, 0.f, 0.f, 0.f};
    f32x4 accA1 = {0.f, 0.f, 0.f, 0.f}, accB1 = {0.f, 0.f, 0.f, 0.f};
    float lA0 = 0.f, lB0 = 0.f, lA1 = 0.f, lB1 = 0.f;

    #pragma unroll
    for (int kt = 0; kt < NTILE; ++kt) {
        const uint2 cbA16 = *(const uint2*)(trowA + kt * 256);
        const uint2 cbB16 = *(const uint2*)(trowB + kt * 256);
        const h2 alo = __builtin_bit_cast(h2, cbA16.x);
        const h2 ahi = __builtin_bit_cast(h2, cbA16.y);
        const h2 blo = __builtin_bit_cast(h2, cbB16.x);
        const h2 bhi = __builtin_bit_cast(h2, cbB16.y);
        f32x4 cbAf, cbBf;
        cbAf[0] = (float)alo.x; cbAf[1] = (float)alo.y;
        cbAf[2] = (float)ahi.x; cbAf[3] = (float)ahi.y;
        cbBf[0] = (float)blo.x; cbBf[1] = (float)blo.y;
        cbBf[2] = (float)bhi.x; cbBf[3] = (float)bhi.y;

        const h4 ak0 = *(const h4*)&Kl[0][kt * 16 + n][g4];
        const h4 ak1 = *(const h4*)&Kl[1][kt * 16 + n][g4];
        const h4 av0 = *(const h4*)&Vt[0][n][kt * 16 + g4];
        const h4 av1 = *(const h4*)&Vt[1][n][kt * 16 + g4];

        f32x4 sA0 = __builtin_amdgcn_mfma_f32_16x16x16f16(ak0, bqA0, cbAf, 0, 0, 0);
        f32x4 sB0 = __builtin_amdgcn_mfma_f32_16x16x16f16(ak0, bqB0, cbBf, 0, 0, 0);
        f32x4 sA1 = __builtin_amdgcn_mfma_f32_16x16x16f16(ak1, bqA1, cbAf, 0, 0, 0);
        f32x4 sB1 = __builtin_amdgcn_mfma_f32_16x16x16f16(ak1, bqB1, cbBf, 0, 0, 0);

        const float pA00 = fast_exp2(sA0[0]);
        const float pA01 = fast_exp2(sA0[1]);
        const float pA02 = fast_exp2(sA0[2]);
        const float pA03 = fast_exp2(sA0[3]);
        const float pB00 = fast_exp2(sB0[0]);
        const float pB01 = fast_exp2(sB0[1]);
        const float pB02 = fast_exp2(sB0[2]);
        const float pB03 = fast_exp2(sB0[3]);
        const float pA10 = fast_exp2(sA1[0]);
        const float pA11 = fast_exp2(sA1[1]);
        const float pA12 = fast_exp2(sA1[2]);
        const float pA13 = fast_exp2(sA1[3]);
        const float pB10 = fast_exp2(sB1[0]);
        const float pB11 = fast_exp2(sB1[1]);
        const float pB12 = fast_exp2(sB1[2]);
        const float pB13 = fast_exp2(sB1[3]);

        lA0 += (pA00 + pA01) + (pA02 + pA03);
        lB0 += (pB00 + pB01) + (pB02 + pB03);
        lA1 += (pA10 + pA11) + (pA12 + pA13);
        lB1 += (pB10 + pB11) + (pB12 + pB13);

        const h4 bpA0 = __builtin_bit_cast(h4, make_uint2(packh2(pA00, pA01), packh2(pA02, pA03)));
        const h4 bpB0 = __builtin_bit_cast(h4, make_uint2(packh2(pB00, pB01), packh2(pB02, pB03)));
        const h4 bpA1 = __builtin_bit_cast(h4, make_uint2(packh2(pA10, pA11), packh2(pA12, pA13)));
        const h4 bpB1 = __builtin_bit_cast(h4, make_uint2(packh2(pB10, pB11), packh2(pB12, pB13)));

        accA0 = __builtin_amdgcn_mfma_f32_16x16x16f16(av0, bpA0, accA0, 0, 0, 0);
        accB0 = __builtin_amdgcn_mfma_f32_16x16x16f16(av0, bpB0, accB0, 0, 0, 0);
        accA1 = __builtin_amdgcn_mfma_f32_16x16x16f16(av1, bpA1, accA1, 0, 0, 0);
        accB1 = __builtin_amdgcn_mfma_f32_16x16x16f16(av1, bpB1, accB1, 0, 0, 0);
    }

    lA0 += __shfl_xor(lA0, 16); lA0 += __shfl_xor(lA0, 32);
    lB0 += __shfl_xor(lB0, 16); lB0 += __shfl_xor(lB0, 32);
    lA1 += __shfl_xor(lA1, 16); lA1 += __shfl_xor(lA1, 32);
    lB1 += __shfl_xor(lB1, 16); lB1 += __shfl_xor(lB1, 32);

    if (g4 < 8) {
        if (qiA < NWTOK) {
            const f32x4 o0 = accA0 * (1.f / lA0);
            *(f32x4*)(og + (size_t)wh0 * OPLANE + qiA * 8 + g4) = o0;
            const f32x4 o1 = accA1 * (1.f / lA1);
            *(f32x4*)(og + (size_t)wh1 * OPLANE + qiA * 8 + g4) = o1;
        }
        if (qiB < NWTOK) {
            const f32x4 o0 = accB0 * (1.f / lB0);
            *(f32x4*)(og + (size_t)wh0 * OPLANE + qiB * 8 + g4) = o0;
            const f32x4 o1 = accB1 * (1.f / lB1);
            *(f32x4*)(og + (size_t)wh1 * OPLANE + qiB * 8 + g4) = o1;
        }
    }
}

// ------- K_post: proj + residual + LN2 + MLP (+ next LN1+QKV or output) -------
// Weights read directly from global with wave-uniform addresses (s_load / K$).
__global__ __launch_bounds__(256, 4) void k_post(
    float* __restrict__ xe,
    const float* __restrict__ og,
    u32* __restrict__ qg,
    u32* __restrict__ kg,
    u32* __restrict__ vg,
    const float* __restrict__ proj_w,
    const float* __restrict__ proj_b,
    const float* __restrict__ n2_g,
    const float* __restrict__ n2_b,
    const float* __restrict__ fc1_w,
    const float* __restrict__ fc1_b,
    const float* __restrict__ fc2_w,
    const float* __restrict__ fc2_b,
    const float* __restrict__ n1_g_nx,
    const float* __restrict__ n1_b_nx,
    const float* __restrict__ qkv_w_nx,
    float* __restrict__ outp,
    const int last)
{
    const int tid = threadIdx.x;
    const int widx = blockIdx.x * 256 + tid;
    if (widx >= NTOK) return;
    const int w = widx / NWTOK;
    const int t = widx - w * NWTOK;

    float o[16];
    const float* o0 = og + (size_t)(w * 2) * OPLANE + t * 8;
    const float* o1 = og + (size_t)(w * 2 + 1) * OPLANE + t * 8;
    ((float4*)o)[0] = ((const float4*)o0)[0]; ((float4*)o)[1] = ((const float4*)o0)[1];
    ((float4*)o)[2] = ((const float4*)o1)[0]; ((float4*)o)[3] = ((const float4*)o1)[1];

    float xr[16];
    const float4* xs = (const float4*)(xe + (size_t)widx * 16);
    ((float4*)xr)[0] = xs[0]; ((float4*)xr)[1] = xs[1];
    ((float4*)xr)[2] = xs[2]; ((float4*)xr)[3] = xs[3];

    #pragma unroll
    for (int c = 0; c < 16; ++c) xr[c] += proj_b[c] + dot16g(proj_w + c * 16, o);

    float mu = 0.f;
    #pragma unroll
    for (int c = 0; c < 16; ++c) mu += xr[c];
    mu *= 0.0625f;
    float var = 0.f;
    #pragma unroll
    for (int c = 0; c < 16; ++c) { float d = xr[c] - mu; var = fmaf(d, d, var); }
    var *= 0.0625f;
    float rs = rsqrtf(var + 1e-5f);
    float zv[16];
    #pragma unroll
    for (int c = 0; c < 16; ++c) zv[c] = (xr[c] - mu) * rs * n2_g[c] + n2_b[c];

    float accm[16];
    #pragma unroll
    for (int c = 0; c < 16; ++c) accm[c] = fc2_b[c];
    #pragma unroll
    for (int ch = 0; ch < 4; ++ch) {
        float hv[16];
        #pragma unroll
        for (int mm = 0; mm < 16; ++mm) {
            const int mi = ch * 16 + mm;
            hv[mm] = gelu_exact(fc1_b[mi] + dot16g(fc1_w + mi * 16, zv));
        }
        #pragma unroll
        for (int c = 0; c < 16; ++c)
            accm[c] += dot16g(fc2_w + c * 64 + ch * 16, hv);
    }
    #pragma unroll
    for (int c = 0; c < 16; ++c) xr[c] += accm[c];

    if (last) {
        const int wd = w / 49;
        const int wr2 = w - wd * 49;
        const int whh = wr2 / 7;
        const int www = wr2 - whh * 7;
        const int tz = t / 49;
        const int tr2 = t - tz * 49;
        const int ty = tr2 / 7;
        const int tx = tr2 - ty * 7;
        const int g = ((wd * 7 + tz) * 49 + (whh * 7 + ty)) * 49 + (www * 7 + tx);
        #pragma unroll
        for (int c = 0; c < 16; ++c) outp[(size_t)c * NTOK + g] = xr[c];
        return;
    }

    float4* dst = (float4*)(xe + (size_t)widx * 16);
    dst[0] = ((float4*)xr)[0]; dst[1] = ((float4*)xr)[1];
    dst[2] = ((float4*)xr)[2]; dst[3] = ((float4*)xr)[3];

    // LN1 + QKV for next block (f16 packed)
    mu = 0.f;
    #pragma unroll
    for (int c = 0; c < 16; ++c) mu += xr[c];
    mu *= 0.0625f;
    var = 0.f;
    #pragma unroll
    for (int c = 0; c < 16; ++c) { float d = xr[c] - mu; var = fmaf(d, d, var); }
    var *= 0.0625f;
    rs = rsqrtf(var + 1e-5f);
    float yv[16];
    #pragma unroll
    for (int c = 0; c < 16; ++c) yv[c] = (xr[c] - mu) * rs * n1_g_nx[c] + n1_b_nx[c];

    float tmp[16];
    #pragma unroll
    for (int rr = 0; rr < 16; ++rr) tmp[rr] = dot16g(qkv_w_nx + rr * 16, yv) * QSCALE;
    store_f16_row(qg + (size_t)(w * 2) * QPLANE, t, tmp);
    store_f16_row(qg + (size_t)(w * 2 + 1) * QPLANE, t, tmp + 8);
    #pragma unroll
    for (int rr = 0; rr < 16; ++rr) tmp[rr] = dot16g(qkv_w_nx + (16 + rr) * 16, yv);
    store_f16_row(kg + (size_t)(w * 2) * QPLANE, t, tmp);
    store_f16_row(kg + (size_t)(w * 2 + 1) * QPLANE, t, tmp + 8);
    #pragma unroll
    for (int rr = 0; rr < 16; ++rr) tmp[rr] = dot16g(qkv_w_nx + (32 + rr) * 16, yv);
    store_f16_row(vg + (size_t)(w * 2) * QPLANE, t, tmp);
    store_f16_row(vg + (size_t)(w * 2 + 1) * QPLANE, t, tmp + 8);
}

extern "C" void kernel_launch(void* const* d_in, const int* in_sizes, int n_in,
                              void* d_out, int out_size, void* d_ws, size_t ws_size,
                              hipStream_t stream) {
    const float* x       = (const float*)d_in[0];
    const float* pe_w    = (const float*)d_in[1];
    const float* pe_bias = (const float*)d_in[2];
    const float* pe_g    = (const float*)d_in[3];
    const float* pe_b    = (const float*)d_in[4];
    const float* n1_g    = (const float*)d_in[5];
    const float* n1_b    = (const float*)d_in[6];
    const float* qkv_w   = (const float*)d_in[7];
    const float* rpb     = (const float*)d_in[8];
    const float* proj_w  = (const float*)d_in[9];
    const float* proj_b  = (const float*)d_in[10];
    const float* n2_g    = (const float*)d_in[11];
    const float* n2_b    = (const float*)d_in[12];
    const float* fc1_w   = (const float*)d_in[13];
    const float* fc1_b   = (const float*)d_in[14];
    const float* fc2_w   = (const float*)d_in[15];
    const float* fc2_b   = (const float*)d_in[16];

    float* ws = (float*)d_ws;
    const size_t SEG = (size_t)NTOK * 16;     // 1,882,384 floats
    const size_t QSEG = (size_t)686 * QPLANE; // 941,192 u32
    float* xe = ws;
    u32* qg = (u32*)(ws + SEG);
    u32* kg = qg + QSEG;
    u32* vg = kg + QSEG;
    float* og = (float*)(vg + QSEG);                  // 686*2744 f32
    __fp16* bexp16 = (__fp16*)(og + (size_t)686 * OPLANE); // 6*484*256 f16
    float* out = (float*)d_out;

    k_bias_expand<<<6 * NTILE * NTILE, 256, 0, stream>>>(rpb, bexp16);

    k0_patch_qkv<<<(NTOK + 255) / 256, 256, 0, stream>>>(
        x, pe_w, pe_bias, pe_g, pe_b, n1_g, n1_b, qkv_w, xe, qg, kg, vg);

    for (int i = 0; i < 3; ++i) {
        const int last = (i == 2) ? 1 : 0;
        const int nx = last ? i : i + 1;
        k_attn<<<344, 704, 0, stream>>>(
            qg, kg, vg, og, bexp16 + (size_t)i * 2 * 484 * 256);
        k_post<<<(NTOK + 255) / 256, 256, 0, stream>>>(
            xe, og, qg, kg, vg,
            proj_w + (size_t)i * 256, proj_b + (size_t)i * 16,
            n2_g + (size_t)i * 16, n2_b + (size_t)i * 16,
            fc1_w + (size_t)i * 1024, fc1_b + (size_t)i * 64,
            fc2_w + (size_t)i * 1024, fc2_b + (size_t)i * 16,
            n1_g + (size_t)nx * 16, n1_b + (size_t)nx * 16,
            qkv_w + (size_t)nx * 768,
            out, last);
    }
}

// Round 13
// 204.652 us; speedup vs baseline: 1.4383x; 1.0548x over previous
//
#include <hip/hip_runtime.h>
#include <math.h>

#define NWTOK 343
#define NTOK 117649
#define QSCALE 0.510069734f   // (1/sqrt(8)) * log2(e)
#define LOG2E 1.4426950408889634f
#define QPLANE 1372   // u32 per (window,head) plane of f16 rows
#define OPLANE 2744   // f32 per (window,head) plane of o
#define NPAD 352
#define NTILE 22

typedef unsigned int u32;
typedef __fp16 h2 __attribute__((ext_vector_type(2)));
typedef __fp16 h4 __attribute__((ext_vector_type(4)));
typedef float f32x4 __attribute__((ext_vector_type(4)));

__device__ __forceinline__ u32 packh2(float a, float b) {
    h2 h = __builtin_amdgcn_cvt_pkrtz(a, b);
    return __builtin_bit_cast(u32, h);
}
__device__ __forceinline__ float fast_exp2(float x) {
#if __has_builtin(__builtin_amdgcn_exp2f)
    return __builtin_amdgcn_exp2f(x);
#else
    return exp2f(x);
#endif
}

// dot of v[16] with 16 consecutive LDS floats via 4x ds_read_b128
__device__ __forceinline__ float dot16_lds(const float* __restrict__ wrow,
                                           const float* __restrict__ v) {
    const float4 w0 = *(const float4*)(wrow);
    const float4 w1 = *(const float4*)(wrow + 4);
    const float4 w2 = *(const float4*)(wrow + 8);
    const float4 w3 = *(const float4*)(wrow + 12);
    float a = v[0] * w0.x;
    a = fmaf(v[1], w0.y, a); a = fmaf(v[2], w0.z, a); a = fmaf(v[3], w0.w, a);
    a = fmaf(v[4], w1.x, a); a = fmaf(v[5], w1.y, a); a = fmaf(v[6], w1.z, a);
    a = fmaf(v[7], w1.w, a);
    a = fmaf(v[8], w2.x, a); a = fmaf(v[9], w2.y, a); a = fmaf(v[10], w2.z, a);
    a = fmaf(v[11], w2.w, a);
    a = fmaf(v[12], w3.x, a); a = fmaf(v[13], w3.y, a); a = fmaf(v[14], w3.z, a);
    a = fmaf(v[15], w3.w, a);
    return a;
}

// two-token dot: one weight read (4x ds_read_b128) feeds 8 FMAs
__device__ __forceinline__ void dot16_lds2(const float* __restrict__ wrow,
                                           const float* __restrict__ vA,
                                           const float* __restrict__ vB,
                                           float& ra, float& rb) {
    const float4 w0 = *(const float4*)(wrow);
    const float4 w1 = *(const float4*)(wrow + 4);
    const float4 w2 = *(const float4*)(wrow + 8);
    const float4 w3 = *(const float4*)(wrow + 12);
    float a = fmaf(vA[0], w0.x, ra);
    float b = fmaf(vB[0], w0.x, rb);
    a = fmaf(vA[1], w0.y, a);  b = fmaf(vB[1], w0.y, b);
    a = fmaf(vA[2], w0.z, a);  b = fmaf(vB[2], w0.z, b);
    a = fmaf(vA[3], w0.w, a);  b = fmaf(vB[3], w0.w, b);
    a = fmaf(vA[4], w1.x, a);  b = fmaf(vB[4], w1.x, b);
    a = fmaf(vA[5], w1.y, a);  b = fmaf(vB[5], w1.y, b);
    a = fmaf(vA[6], w1.z, a);  b = fmaf(vB[6], w1.z, b);
    a = fmaf(vA[7], w1.w, a);  b = fmaf(vB[7], w1.w, b);
    a = fmaf(vA[8], w2.x, a);  b = fmaf(vB[8], w2.x, b);
    a = fmaf(vA[9], w2.y, a);  b = fmaf(vB[9], w2.y, b);
    a = fmaf(vA[10], w2.z, a); b = fmaf(vB[10], w2.z, b);
    a = fmaf(vA[11], w2.w, a); b = fmaf(vB[11], w2.w, b);
    a = fmaf(vA[12], w3.x, a); b = fmaf(vB[12], w3.x, b);
    a = fmaf(vA[13], w3.y, a); b = fmaf(vB[13], w3.y, b);
    a = fmaf(vA[14], w3.z, a); b = fmaf(vB[14], w3.z, b);
    a = fmaf(vA[15], w3.w, a); b = fmaf(vB[15], w3.w, b);
    ra = a; rb = b;
}

// Inline exact-GELU via Abramowitz-Stegun 7.1.26 erf (max abs err 1.5e-7).
__device__ __forceinline__ float gelu_exact(float x) {
    const float z = x * 0.70710678118654752f;
    const float az = fabsf(z);
    const float t = __builtin_amdgcn_rcpf(fmaf(0.3275911f, az, 1.0f));
    float y = fmaf(t, 1.061405429f, -1.453152027f);
    y = fmaf(t, y, 1.421413741f);
    y = fmaf(t, y, -0.284496736f);
    y = fmaf(t, y, 0.254829592f);
    y *= t;
    const float one_m_erf = y * __expf(-az * az);
    const float erf_az = 1.0f - one_m_erf;
    const float erf_z = (z < 0.f) ? -erf_az : erf_az;
    return 0.5f * x * (1.0f + erf_z);
}

__device__ __forceinline__ void store_f16_row(u32* base, int t, const float* v8) {
    uint4 u;
    u.x = packh2(v8[0], v8[1]); u.y = packh2(v8[2], v8[3]);
    u.z = packh2(v8[4], v8[5]); u.w = packh2(v8[6], v8[7]);
    *(uint4*)(base + t * 4) = u;
}

// ---- bias expand, f16 TILED: bexp16[((bh)*484 + qt*22 + kt)*256 + n*16 + g] ----
__global__ __launch_bounds__(256) void k_bias_expand(
    const float* __restrict__ rpb,   // (3, 2197, 2)
    __fp16* __restrict__ bexp16)
{
    const int tile = blockIdx.x;     // ((blk*2+h)*22 + qt)*22 + kt
    const int kt = tile % NTILE;
    const int rest = tile / NTILE;
    const int qt = rest % NTILE;
    const int bh = rest / NTILE;
    const int blk = bh >> 1, h = bh & 1;
    const int tid = threadIdx.x;     // n*16 + g
    const int n = tid >> 4, g = tid & 15;
    const int i = qt * 16 + n, j = kt * 16 + g;
    float val;
    if (j >= NWTOK) {
        val = -60.f;
    } else if (i >= NWTOK) {
        val = 0.f;
    } else {
        const int iz = i / 49, ir = i - iz * 49, iy = ir / 7, ix = ir - iy * 7;
        const int jz = j / 49, jr = j - jz * 49, jy = jr / 7, jx = jr - jy * 7;
        const int idx = (iz - jz + 6) * 169 + (iy - jy + 6) * 13 + (ix - jx + 6);
        val = rpb[((size_t)blk * 2197 + idx) * 2 + h] * LOG2E;
    }
    bexp16[(size_t)tile * 256 + tid] = (__fp16)val;
}

// ---------------- K0: patch embed + LN + LN1 + QKV(block 0) ----------------
__global__ __launch_bounds__(256, 2) void k0_patch_qkv(
    const float* __restrict__ x,
    const float* __restrict__ pe_w,
    const float* __restrict__ pe_bias,
    const float* __restrict__ pe_g,
    const float* __restrict__ pe_b,
    const float* __restrict__ n1_g,
    const float* __restrict__ n1_b,
    const float* __restrict__ qkv_w,
    float* __restrict__ xe,
    u32* __restrict__ qg,
    u32* __restrict__ kg,
    u32* __restrict__ vg)
{
    __shared__ float w_s[128];
    __shared__ float pb_s[16], g_s[16], b_s[16], n1g_s[16], n1b_s[16];
    __shared__ float qkvw_s[768];
    const int tid = threadIdx.x;
    if (tid < 128) w_s[tid] = pe_w[tid];
    if (tid < 16) {
        pb_s[tid] = pe_bias[tid]; g_s[tid] = pe_g[tid]; b_s[tid] = pe_b[tid];
        n1g_s[tid] = n1_g[tid]; n1b_s[tid] = n1_b[tid];
    }
    for (int i = tid; i < 768; i += 256) qkvw_s[i] = qkv_w[i];
    __syncthreads();
    const int g = blockIdx.x * 256 + tid;
    if (g >= NTOK) return;
    const int z = g / 2401;
    const int r = g - z * 2401;
    const int y = r / 49;
    const int xx = r - y * 49;
    const float* bp = x + ((2 * z) * 98 + (2 * y)) * 98 + 2 * xx;
    float in[8];
    in[0] = bp[0];    in[1] = bp[1];
    in[2] = bp[98];   in[3] = bp[99];
    in[4] = bp[9604]; in[5] = bp[9605];
    in[6] = bp[9702]; in[7] = bp[9703];
    float v[16];
    float mu = 0.f;
    #pragma unroll
    for (int c = 0; c < 16; ++c) {
        float a = pb_s[c];
        #pragma unroll
        for (int k = 0; k < 8; ++k) a = fmaf(in[k], w_s[c * 8 + k], a);
        v[c] = a; mu += a;
    }
    mu *= 0.0625f;
    float var = 0.f;
    #pragma unroll
    for (int c = 0; c < 16; ++c) { float d = v[c] - mu; var = fmaf(d, d, var); }
    var *= 0.0625f;
    float rs = rsqrtf(var + 1e-5f);
    float o[16];
    #pragma unroll
    for (int c = 0; c < 16; ++c) o[c] = (v[c] - mu) * rs * g_s[c] + b_s[c];

    const int zw = z / 7, zi = z - zw * 7;
    const int yw = y / 7, yi = y - yw * 7;
    const int xw = xx / 7, xi = xx - xw * 7;
    const int w = (zw * 7 + yw) * 7 + xw;
    const int t = (zi * 7 + yi) * 7 + xi;
    const int widx = w * NWTOK + t;

    float4* dst = (float4*)(xe + (size_t)widx * 16);
    dst[0] = ((float4*)o)[0]; dst[1] = ((float4*)o)[1];
    dst[2] = ((float4*)o)[2]; dst[3] = ((float4*)o)[3];

    mu = 0.f;
    #pragma unroll
    for (int c = 0; c < 16; ++c) mu += o[c];
    mu *= 0.0625f;
    var = 0.f;
    #pragma unroll
    for (int c = 0; c < 16; ++c) { float d = o[c] - mu; var = fmaf(d, d, var); }
    var *= 0.0625f;
    rs = rsqrtf(var + 1e-5f);
    float yv[16];
    #pragma unroll
    for (int c = 0; c < 16; ++c) yv[c] = (o[c] - mu) * rs * n1g_s[c] + n1b_s[c];

    float tmp[16];
    #pragma unroll
    for (int rr = 0; rr < 16; ++rr) tmp[rr] = dot16_lds(qkvw_s + rr * 16, yv) * QSCALE;
    store_f16_row(qg + (size_t)(w * 2) * QPLANE, t, tmp);
    store_f16_row(qg + (size_t)(w * 2 + 1) * QPLANE, t, tmp + 8);
    #pragma unroll
    for (int rr = 0; rr < 16; ++rr) tmp[rr] = dot16_lds(qkvw_s + (16 + rr) * 16, yv);
    store_f16_row(kg + (size_t)(w * 2) * QPLANE, t, tmp);
    store_f16_row(kg + (size_t)(w * 2 + 1) * QPLANE, t, tmp + 8);
    #pragma unroll
    for (int rr = 0; rr < 16; ++rr) tmp[rr] = dot16_lds(qkvw_s + (32 + rr) * 16, yv);
    store_f16_row(vg + (size_t)(w * 2) * QPLANE, t, tmp);
    store_f16_row(vg + (size_t)(w * 2 + 1) * QPLANE, t, tmp + 8);
}

// ---- K_attn: WG = (window-pair, head); 11 waves; 1 qt-pair/wave x 2 windows ----
__global__ __launch_bounds__(704, 5) void k_attn(
    const u32* __restrict__ qg,
    const u32* __restrict__ kg,
    const u32* __restrict__ vg,
    float* __restrict__ og,
    const __fp16* __restrict__ bexp_blk)   // this block's [2][22][22][256] f16 tiles
{
    __shared__ __fp16 Kl[2][NPAD][16];
    __shared__ __fp16 Ql[2][NPAD][16];
    __shared__ __fp16 Vt[2][16][360];

    const int tid = threadIdx.x;
    const int pidx = blockIdx.x;
    const int wp = pidx >> 1;
    const int h = pidx & 1;
    const int w0 = 2 * wp;
    const int w1 = (w0 + 1 < NWTOK) ? w0 + 1 : NWTOK - 1;
    const int wh0 = w0 * 2 + h;
    const int wh1 = w1 * 2 + h;

    {
        const int sw = (tid >= NPAD) ? 1 : 0;
        const int st = tid - sw * NPAD;
        const size_t qpl = (size_t)(sw ? wh1 : wh0) * QPLANE;
        const uint4 z4 = make_uint4(0, 0, 0, 0);
        if (st < NWTOK) {
            const uint4 kw = ((const uint4*)(kg + qpl))[st];
            const uint4 qw = ((const uint4*)(qg + qpl))[st];
            const uint4 vw = ((const uint4*)(vg + qpl))[st];
            *(uint4*)&Kl[sw][st][0] = kw; *(uint4*)&Kl[sw][st][8] = z4;
            *(uint4*)&Ql[sw][st][0] = qw; *(uint4*)&Ql[sw][st][8] = z4;
            const h2 v01 = __builtin_bit_cast(h2, vw.x);
            const h2 v23 = __builtin_bit_cast(h2, vw.y);
            const h2 v45 = __builtin_bit_cast(h2, vw.z);
            const h2 v67 = __builtin_bit_cast(h2, vw.w);
            Vt[sw][0][st] = v01.x; Vt[sw][1][st] = v01.y;
            Vt[sw][2][st] = v23.x; Vt[sw][3][st] = v23.y;
            Vt[sw][4][st] = v45.x; Vt[sw][5][st] = v45.y;
            Vt[sw][6][st] = v67.x; Vt[sw][7][st] = v67.y;
        } else {
            *(uint4*)&Kl[sw][st][0] = z4; *(uint4*)&Kl[sw][st][8] = z4;
            *(uint4*)&Ql[sw][st][0] = z4; *(uint4*)&Ql[sw][st][8] = z4;
            #pragma unroll
            for (int d = 0; d < 8; ++d) Vt[sw][d][st] = (__fp16)0.f;
        }
        #pragma unroll
        for (int d = 8; d < 16; ++d) Vt[sw][d][st] = (__fp16)0.f;
    }
    __syncthreads();

    const int wave = tid >> 6;        // 0..10 == qt-pair index
    const int lane = tid & 63;
    const int n = lane & 15;
    const int g4 = (lane >> 4) * 4;

    const int qiA = (2 * wave) * 16 + n;
    const int qiB = qiA + 16;
    const h4 bqA0 = *(const h4*)&Ql[0][qiA][g4];
    const h4 bqB0 = *(const h4*)&Ql[0][qiB][g4];
    const h4 bqA1 = *(const h4*)&Ql[1][qiA][g4];
    const h4 bqB1 = *(const h4*)&Ql[1][qiB][g4];

    const int laneoff = n * 16 + g4;
    const __fp16* trowA = bexp_blk + ((size_t)(h * 484) + (size_t)(2 * wave) * NTILE) * 256 + laneoff;
    const __fp16* trowB = trowA + (size_t)NTILE * 256;

    f32x4 accA0 = {0.f, 0.f, 0.f, 0.f}, accB0 = {0.f, 0.f, 0.f, 0.f};
    f32x4 accA1 = {0.f, 0.f, 0.f, 0.f}, accB1 = {0.f, 0.f, 0.f, 0.f};
    float lA0 = 0.f, lB0 = 0.f, lA1 = 0.f, lB1 = 0.f;

    #pragma unroll
    for (int kt = 0; kt < NTILE; ++kt) {
        const uint2 cbA16 = *(const uint2*)(trowA + kt * 256);
        const uint2 cbB16 = *(const uint2*)(trowB + kt * 256);
        const h2 alo = __builtin_bit_cast(h2, cbA16.x);
        const h2 ahi = __builtin_bit_cast(h2, cbA16.y);
        const h2 blo = __builtin_bit_cast(h2, cbB16.x);
        const h2 bhi = __builtin_bit_cast(h2, cbB16.y);
        f32x4 cbAf, cbBf;
        cbAf[0] = (float)alo.x; cbAf[1] = (float)alo.y;
        cbAf[2] = (float)ahi.x; cbAf[3] = (float)ahi.y;
        cbBf[0] = (float)blo.x; cbBf[1] = (float)blo.y;
        cbBf[2] = (float)bhi.x; cbBf[3] = (float)bhi.y;

        const h4 ak0 = *(const h4*)&Kl[0][kt * 16 + n][g4];
        const h4 ak1 = *(const h4*)&Kl[1][kt * 16 + n][g4];
        const h4 av0 = *(const h4*)&Vt[0][n][kt * 16 + g4];
        const h4 av1 = *(const h4*)&Vt[1][n][kt * 16 + g4];

        f32x4 sA0 = __builtin_amdgcn_mfma_f32_16x16x16f16(ak0, bqA0, cbAf, 0, 0, 0);
        f32x4 sB0 = __builtin_amdgcn_mfma_f32_16x16x16f16(ak0, bqB0, cbBf, 0, 0, 0);
        f32x4 sA1 = __builtin_amdgcn_mfma_f32_16x16x16f16(ak1, bqA1, cbAf, 0, 0, 0);
        f32x4 sB1 = __builtin_amdgcn_mfma_f32_16x16x16f16(ak1, bqB1, cbBf, 0, 0, 0);

        const float pA00 = fast_exp2(sA0[0]);
        const float pA01 = fast_exp2(sA0[1]);
        const float pA02 = fast_exp2(sA0[2]);
        const float pA03 = fast_exp2(sA0[3]);
        const float pB00 = fast_exp2(sB0[0]);
        const float pB01 = fast_exp2(sB0[1]);
        const float pB02 = fast_exp2(sB0[2]);
        const float pB03 = fast_exp2(sB0[3]);
        const float pA10 = fast_exp2(sA1[0]);
        const float pA11 = fast_exp2(sA1[1]);
        const float pA12 = fast_exp2(sA1[2]);
        const float pA13 = fast_exp2(sA1[3]);
        const float pB10 = fast_exp2(sB1[0]);
        const float pB11 = fast_exp2(sB1[1]);
        const float pB12 = fast_exp2(sB1[2]);
        const float pB13 = fast_exp2(sB1[3]);

        lA0 += (pA00 + pA01) + (pA02 + pA03);
        lB0 += (pB00 + pB01) + (pB02 + pB03);
        lA1 += (pA10 + pA11) + (pA12 + pA13);
        lB1 += (pB10 + pB11) + (pB12 + pB13);

        const h4 bpA0 = __builtin_bit_cast(h4, make_uint2(packh2(pA00, pA01), packh2(pA02, pA03)));
        const h4 bpB0 = __builtin_bit_cast(h4, make_uint2(packh2(pB00, pB01), packh2(pB02, pB03)));
        const h4 bpA1 = __builtin_bit_cast(h4, make_uint2(packh2(pA10, pA11), packh2(pA12, pA13)));
        const h4 bpB1 = __builtin_bit_cast(h4, make_uint2(packh2(pB10, pB11), packh2(pB12, pB13)));

        accA0 = __builtin_amdgcn_mfma_f32_16x16x16f16(av0, bpA0, accA0, 0, 0, 0);
        accB0 = __builtin_amdgcn_mfma_f32_16x16x16f16(av0, bpB0, accB0, 0, 0, 0);
        accA1 = __builtin_amdgcn_mfma_f32_16x16x16f16(av1, bpA1, accA1, 0, 0, 0);
        accB1 = __builtin_amdgcn_mfma_f32_16x16x16f16(av1, bpB1, accB1, 0, 0, 0);
    }

    lA0 += __shfl_xor(lA0, 16); lA0 += __shfl_xor(lA0, 32);
    lB0 += __shfl_xor(lB0, 16); lB0 += __shfl_xor(lB0, 32);
    lA1 += __shfl_xor(lA1, 16); lA1 += __shfl_xor(lA1, 32);
    lB1 += __shfl_xor(lB1, 16); lB1 += __shfl_xor(lB1, 32);

    if (g4 < 8) {
        if (qiA < NWTOK) {
            const f32x4 o0 = accA0 * (1.f / lA0);
            *(f32x4*)(og + (size_t)wh0 * OPLANE + qiA * 8 + g4) = o0;
            const f32x4 o1 = accA1 * (1.f / lA1);
            *(f32x4*)(og + (size_t)wh1 * OPLANE + qiA * 8 + g4) = o1;
        }
        if (qiB < NWTOK) {
            const f32x4 o0 = accB0 * (1.f / lB0);
            *(f32x4*)(og + (size_t)wh0 * OPLANE + qiB * 8 + g4) = o0;
            const f32x4 o1 = accB1 * (1.f / lB1);
            *(f32x4*)(og + (size_t)wh1 * OPLANE + qiB * 8 + g4) = o1;
        }
    }
}

// ------- K_post: 2 tokens/thread; LDS-staged weights; each weight b128 feeds 8 FMAs -------
__global__ __launch_bounds__(256, 2) void k_post(
    float* __restrict__ xe,
    const float* __restrict__ og,
    u32* __restrict__ qg,
    u32* __restrict__ kg,
    u32* __restrict__ vg,
    const float* __restrict__ proj_w,
    const float* __restrict__ proj_b,
    const float* __restrict__ n2_g,
    const float* __restrict__ n2_b,
    const float* __restrict__ fc1_w,
    const float* __restrict__ fc1_b,
    const float* __restrict__ fc2_w,
    const float* __restrict__ fc2_b,
    const float* __restrict__ n1_g_nx,
    const float* __restrict__ n1_b_nx,
    const float* __restrict__ qkv_w_nx,
    float* __restrict__ outp,
    const int last)
{
    __shared__ float projw_s[256];
    __shared__ float fc1w_s[1024];
    __shared__ float fc2w_s[1024];
    __shared__ float qkvw_s[768];
    __shared__ float projb_s[16], n2g_s[16], n2b_s[16], fc2b_s[16], n1g_s[16], n1b_s[16];
    __shared__ float fc1b_s[64];
    const int tid = threadIdx.x;
    if (tid < 256) projw_s[tid] = proj_w[tid];
    for (int i = tid; i < 1024; i += 256) { fc1w_s[i] = fc1_w[i]; fc2w_s[i] = fc2_w[i]; }
    for (int i = tid; i < 768; i += 256) qkvw_s[i] = qkv_w_nx[i];
    if (tid < 16) {
        projb_s[tid] = proj_b[tid];
        n2g_s[tid] = n2_g[tid]; n2b_s[tid] = n2_b[tid];
        fc2b_s[tid] = fc2_b[tid];
        n1g_s[tid] = n1_g_nx[tid]; n1b_s[tid] = n1_b_nx[tid];
    }
    if (tid < 64) fc1b_s[tid] = fc1_b[tid];
    __syncthreads();

    const int wA_idx = blockIdx.x * 512 + tid;       // always < NTOK (grid sized)
    const int wB_raw = wA_idx + 256;
    const bool hasB = (wB_raw < NTOK);
    const int wB_idx = hasB ? wB_raw : wA_idx;

    const int wA = wA_idx / NWTOK, tA = wA_idx - wA * NWTOK;
    const int wB = wB_idx / NWTOK, tB = wB_idx - wB * NWTOK;

    float xrA[16], xrB[16];
    {
        float oA[16], oB[16];
        const float* a0 = og + (size_t)(wA * 2) * OPLANE + tA * 8;
        const float* a1 = og + (size_t)(wA * 2 + 1) * OPLANE + tA * 8;
        const float* b0 = og + (size_t)(wB * 2) * OPLANE + tB * 8;
        const float* b1 = og + (size_t)(wB * 2 + 1) * OPLANE + tB * 8;
        ((float4*)oA)[0] = ((const float4*)a0)[0]; ((float4*)oA)[1] = ((const float4*)a0)[1];
        ((float4*)oA)[2] = ((const float4*)a1)[0]; ((float4*)oA)[3] = ((const float4*)a1)[1];
        ((float4*)oB)[0] = ((const float4*)b0)[0]; ((float4*)oB)[1] = ((const float4*)b0)[1];
        ((float4*)oB)[2] = ((const float4*)b1)[0]; ((float4*)oB)[3] = ((const float4*)b1)[1];

        const float4* xsA = (const float4*)(xe + (size_t)wA_idx * 16);
        const float4* xsB = (const float4*)(xe + (size_t)wB_idx * 16);
        ((float4*)xrA)[0] = xsA[0]; ((float4*)xrA)[1] = xsA[1];
        ((float4*)xrA)[2] = xsA[2]; ((float4*)xrA)[3] = xsA[3];
        ((float4*)xrB)[0] = xsB[0]; ((float4*)xrB)[1] = xsB[1];
        ((float4*)xrB)[2] = xsB[2]; ((float4*)xrB)[3] = xsB[3];

        #pragma unroll
        for (int c = 0; c < 16; ++c) {
            float a = projb_s[c], b = projb_s[c];
            dot16_lds2(projw_s + c * 16, oA, oB, a, b);
            xrA[c] += a; xrB[c] += b;
        }
    }

    float zvA[16], zvB[16];
    {
        float muA = 0.f, muB = 0.f;
        #pragma unroll
        for (int c = 0; c < 16; ++c) { muA += xrA[c]; muB += xrB[c]; }
        muA *= 0.0625f; muB *= 0.0625f;
        float vaA = 0.f, vaB = 0.f;
        #pragma unroll
        for (int c = 0; c < 16; ++c) {
            float dA = xrA[c] - muA; vaA = fmaf(dA, dA, vaA);
            float dB = xrB[c] - muB; vaB = fmaf(dB, dB, vaB);
        }
        const float rsA = rsqrtf(vaA * 0.0625f + 1e-5f);
        const float rsB = rsqrtf(vaB * 0.0625f + 1e-5f);
        #pragma unroll
        for (int c = 0; c < 16; ++c) {
            zvA[c] = (xrA[c] - muA) * rsA * n2g_s[c] + n2b_s[c];
            zvB[c] = (xrB[c] - muB) * rsB * n2b_s[c] * 0.f + (xrB[c] - muB) * rsB * n2g_s[c] + n2b_s[c];
        }
    }

    #pragma unroll
    for (int c = 0; c < 16; ++c) { xrA[c] += fc2b_s[c]; xrB[c] += fc2b_s[c]; }
    #pragma unroll
    for (int ch = 0; ch < 4; ++ch) {
        float hvA[16], hvB[16];
        #pragma unroll
        for (int mm = 0; mm < 16; ++mm) {
            const int mi = ch * 16 + mm;
            float a = fc1b_s[mi], b = fc1b_s[mi];
            dot16_lds2(fc1w_s + mi * 16, zvA, zvB, a, b);
            hvA[mm] = gelu_exact(a);
            hvB[mm] = gelu_exact(b);
        }
        #pragma unroll
        for (int c = 0; c < 16; ++c) {
            float a = 0.f, b = 0.f;
            dot16_lds2(fc2w_s + c * 64 + ch * 16, hvA, hvB, a, b);
            xrA[c] += a; xrB[c] += b;
        }
    }

    if (last) {
        {
            const int wd = wA / 49, wr2 = wA - wd * 49, whh = wr2 / 7, www = wr2 - whh * 7;
            const int tz = tA / 49, tr2 = tA - tz * 49, ty = tr2 / 7, tx = tr2 - ty * 7;
            const int g = ((wd * 7 + tz) * 49 + (whh * 7 + ty)) * 49 + (www * 7 + tx);
            #pragma unroll
            for (int c = 0; c < 16; ++c) outp[(size_t)c * NTOK + g] = xrA[c];
        }
        if (hasB) {
            const int wd = wB / 49, wr2 = wB - wd * 49, whh = wr2 / 7, www = wr2 - whh * 7;
            const int tz = tB / 49, tr2 = tB - tz * 49, ty = tr2 / 7, tx = tr2 - ty * 7;
            const int g = ((wd * 7 + tz) * 49 + (whh * 7 + ty)) * 49 + (www * 7 + tx);
            #pragma unroll
            for (int c = 0; c < 16; ++c) outp[(size_t)c * NTOK + g] = xrB[c];
        }
        return;
    }

    {
        float4* dstA = (float4*)(xe + (size_t)wA_idx * 16);
        dstA[0] = ((float4*)xrA)[0]; dstA[1] = ((float4*)xrA)[1];
        dstA[2] = ((float4*)xrA)[2]; dstA[3] = ((float4*)xrA)[3];
        if (hasB) {
            float4* dstB = (float4*)(xe + (size_t)wB_idx * 16);
            dstB[0] = ((float4*)xrB)[0]; dstB[1] = ((float4*)xrB)[1];
            dstB[2] = ((float4*)xrB)[2]; dstB[3] = ((float4*)xrB)[3];
        }
    }

    // LN1 + QKV for next block (f16 packed); reuse zv for normalized y
    {
        float muA = 0.f, muB = 0.f;
        #pragma unroll
        for (int c = 0; c < 16; ++c) { muA += xrA[c]; muB += xrB[c]; }
        muA *= 0.0625f; muB *= 0.0625f;
        float vaA = 0.f, vaB = 0.f;
        #pragma unroll
        for (int c = 0; c < 16; ++c) {
            float dA = xrA[c] - muA; vaA = fmaf(dA, dA, vaA);
            float dB = xrB[c] - muB; vaB = fmaf(dB, dB, vaB);
        }
        const float rsA = rsqrtf(vaA * 0.0625f + 1e-5f);
        const float rsB = rsqrtf(vaB * 0.0625f + 1e-5f);
        #pragma unroll
        for (int c = 0; c < 16; ++c) {
            zvA[c] = (xrA[c] - muA) * rsA * n1g_s[c] + n1b_s[c];
            zvB[c] = (xrB[c] - muB) * rsB * n1g_s[c] + n1b_s[c];
        }
    }

    float tmpA[16], tmpB[16];
    #pragma unroll
    for (int rr = 0; rr < 16; ++rr) {
        float a = 0.f, b = 0.f;
        dot16_lds2(qkvw_s + rr * 16, zvA, zvB, a, b);
        tmpA[rr] = a * QSCALE; tmpB[rr] = b * QSCALE;
    }
    store_f16_row(qg + (size_t)(wA * 2) * QPLANE, tA, tmpA);
    store_f16_row(qg + (size_t)(wA * 2 + 1) * QPLANE, tA, tmpA + 8);
    if (hasB) {
        store_f16_row(qg + (size_t)(wB * 2) * QPLANE, tB, tmpB);
        store_f16_row(qg + (size_t)(wB * 2 + 1) * QPLANE, tB, tmpB + 8);
    }
    #pragma unroll
    for (int rr = 0; rr < 16; ++rr) {
        float a = 0.f, b = 0.f;
        dot16_lds2(qkvw_s + (16 + rr) * 16, zvA, zvB, a, b);
        tmpA[rr] = a; tmpB[rr] = b;
    }
    store_f16_row(kg + (size_t)(wA * 2) * QPLANE, tA, tmpA);
    store_f16_row(kg + (size_t)(wA * 2 + 1) * QPLANE, tA, tmpA + 8);
    if (hasB) {
        store_f16_row(kg + (size_t)(wB * 2) * QPLANE, tB, tmpB);
        store_f16_row(kg + (size_t)(wB * 2 + 1) * QPLANE, tB, tmpB + 8);
    }
    #pragma unroll
    for (int rr = 0; rr < 16; ++rr) {
        float a = 0.f, b = 0.f;
        dot16_lds2(qkvw_s + (32 + rr) * 16, zvA, zvB, a, b);
        tmpA[rr] = a; tmpB[rr] = b;
    }
    store_f16_row(vg + (size_t)(wA * 2) * QPLANE, tA, tmpA);
    store_f16_row(vg + (size_t)(wA * 2 + 1) * QPLANE, tA, tmpA + 8);
    if (hasB) {
        store_f16_row(vg + (size_t)(wB * 2) * QPLANE, tB, tmpB);
        store_f16_row(vg + (size_t)(wB * 2 + 1) * QPLANE, tB, tmpB + 8);
    }
}

extern "C" void kernel_launch(void* const* d_in, const int* in_sizes, int n_in,
                              void* d_out, int out_size, void* d_ws, size_t ws_size,
                              hipStream_t stream) {
    const float* x       = (const float*)d_in[0];
    const float* pe_w    = (const float*)d_in[1];
    const float* pe_bias = (const float*)d_in[2];
    const float* pe_g    = (const float*)d_in[3];
    const float* pe_b    = (const float*)d_in[4];
    const float* n1_g    = (const float*)d_in[5];
    const float* n1_b    = (const float*)d_in[6];
    const float* qkv_w   = (const float*)d_in[7];
    const float* rpb     = (const float*)d_in[8];
    const float* proj_w  = (const float*)d_in[9];
    const float* proj_b  = (const float*)d_in[10];
    const float* n2_g    = (const float*)d_in[11];
    const float* n2_b    = (const float*)d_in[12];
    const float* fc1_w   = (const float*)d_in[13];
    const float* fc1_b   = (const float*)d_in[14];
    const float* fc2_w   = (const float*)d_in[15];
    const float* fc2_b   = (const float*)d_in[16];

    float* ws = (float*)d_ws;
    const size_t SEG = (size_t)NTOK * 16;     // 1,882,384 floats
    const size_t QSEG = (size_t)686 * QPLANE; // 941,192 u32
    float* xe = ws;
    u32* qg = (u32*)(ws + SEG);
    u32* kg = qg + QSEG;
    u32* vg = kg + QSEG;
    float* og = (float*)(vg + QSEG);                  // 686*2744 f32
    __fp16* bexp16 = (__fp16*)(og + (size_t)686 * OPLANE); // 6*484*256 f16
    float* out = (float*)d_out;

    k_bias_expand<<<6 * NTILE * NTILE, 256, 0, stream>>>(rpb, bexp16);

    k0_patch_qkv<<<(NTOK + 255) / 256, 256, 0, stream>>>(
        x, pe_w, pe_bias, pe_g, pe_b, n1_g, n1_b, qkv_w, xe, qg, kg, vg);

    for (int i = 0; i < 3; ++i) {
        const int last = (i == 2) ? 1 : 0;
        const int nx = last ? i : i + 1;
        k_attn<<<344, 704, 0, stream>>>(
            qg, kg, vg, og, bexp16 + (size_t)i * 2 * 484 * 256);
        k_post<<<(NTOK + 511) / 512, 256, 0, stream>>>(
            xe, og, qg, kg, vg,
            proj_w + (size_t)i * 256, proj_b + (size_t)i * 16,
            n2_g + (size_t)i * 16, n2_b + (size_t)i * 16,
            fc1_w + (size_t)i * 1024, fc1_b + (size_t)i * 64,
            fc2_w + (size_t)i * 1024, fc2_b + (size_t)i * 16,
            n1_g + (size_t)nx * 16, n1_b + (size_t)nx * 16,
            qkv_w + (size_t)nx * 768,
            out, last);
    }
}

// Round 14
// 162.760 us; speedup vs baseline: 1.8085x; 1.2574x over previous
//
#include <hip/hip_runtime.h>
#include <math.h>

#define NWTOK 343
#define NTOK 117649
#define QSCALE 0.510069734f   // (1/sqrt(8)) * log2(e)
#define LOG2E 1.4426950408889634f
#define QPLANE 1372   // u32 per (window,head) plane of f16 rows
#define OPLANE 2744   // f32 per (window,head) plane of o
#define NPAD 352
#define NTILE 22

typedef unsigned int u32;
typedef __fp16 h2 __attribute__((ext_vector_type(2)));
typedef __fp16 h4 __attribute__((ext_vector_type(4)));
typedef float f32x4 __attribute__((ext_vector_type(4)));

__device__ __forceinline__ u32 packh2(float a, float b) {
    h2 h = __builtin_amdgcn_cvt_pkrtz(a, b);
    return __builtin_bit_cast(u32, h);
}
__device__ __forceinline__ float fdot2u(u32 a, u32 b, float c) {
#if __has_builtin(__builtin_amdgcn_fdot2)
    return __builtin_amdgcn_fdot2(__builtin_bit_cast(h2, a), __builtin_bit_cast(h2, b), c, false);
#else
    h2 ha = __builtin_bit_cast(h2, a), hb = __builtin_bit_cast(h2, b);
    return fmaf((float)ha.y, (float)hb.y, fmaf((float)ha.x, (float)hb.x, c));
#endif
}
__device__ __forceinline__ float fast_exp2(float x) {
#if __has_builtin(__builtin_amdgcn_exp2f)
    return __builtin_amdgcn_exp2f(x);
#else
    return exp2f(x);
#endif
}

// dot of packed-f16 v (8 u32) with a packed-f16 LDS weight row (2x ds_read_b128)
__device__ __forceinline__ float dot16h(const u32* __restrict__ wrow,
                                        const u32* __restrict__ vp, float acc) {
    const uint4 w0 = *(const uint4*)(wrow);
    const uint4 w1 = *(const uint4*)(wrow + 4);
    float a = acc;
    a = fdot2u(vp[0], w0.x, a);
    a = fdot2u(vp[1], w0.y, a);
    a = fdot2u(vp[2], w0.z, a);
    a = fdot2u(vp[3], w0.w, a);
    a = fdot2u(vp[4], w1.x, a);
    a = fdot2u(vp[5], w1.y, a);
    a = fdot2u(vp[6], w1.z, a);
    a = fdot2u(vp[7], w1.w, a);
    return a;
}

// dot of v[16] with 16 consecutive LDS floats via 4x ds_read_b128
__device__ __forceinline__ float dot16_lds(const float* __restrict__ wrow,
                                           const float* __restrict__ v) {
    const float4 w0 = *(const float4*)(wrow);
    const float4 w1 = *(const float4*)(wrow + 4);
    const float4 w2 = *(const float4*)(wrow + 8);
    const float4 w3 = *(const float4*)(wrow + 12);
    float a = v[0] * w0.x;
    a = fmaf(v[1], w0.y, a); a = fmaf(v[2], w0.z, a); a = fmaf(v[3], w0.w, a);
    a = fmaf(v[4], w1.x, a); a = fmaf(v[5], w1.y, a); a = fmaf(v[6], w1.z, a);
    a = fmaf(v[7], w1.w, a);
    a = fmaf(v[8], w2.x, a); a = fmaf(v[9], w2.y, a); a = fmaf(v[10], w2.z, a);
    a = fmaf(v[11], w2.w, a);
    a = fmaf(v[12], w3.x, a); a = fmaf(v[13], w3.y, a); a = fmaf(v[14], w3.z, a);
    a = fmaf(v[15], w3.w, a);
    return a;
}

// Inline exact-GELU via Abramowitz-Stegun 7.1.26 erf (max abs err 1.5e-7).
__device__ __forceinline__ float gelu_exact(float x) {
    const float z = x * 0.70710678118654752f;
    const float az = fabsf(z);
    const float t = __builtin_amdgcn_rcpf(fmaf(0.3275911f, az, 1.0f));
    float y = fmaf(t, 1.061405429f, -1.453152027f);
    y = fmaf(t, y, 1.421413741f);
    y = fmaf(t, y, -0.284496736f);
    y = fmaf(t, y, 0.254829592f);
    y *= t;
    const float one_m_erf = y * __expf(-az * az);
    const float erf_az = 1.0f - one_m_erf;
    const float erf_z = (z < 0.f) ? -erf_az : erf_az;
    return 0.5f * x * (1.0f + erf_z);
}

__device__ __forceinline__ void store_f16_row(u32* base, int t, const float* v8) {
    uint4 u;
    u.x = packh2(v8[0], v8[1]); u.y = packh2(v8[2], v8[3]);
    u.z = packh2(v8[4], v8[5]); u.w = packh2(v8[6], v8[7]);
    *(uint4*)(base + t * 4) = u;
}

// ---- bias expand, f16 TILED: bexp16[((bh)*484 + qt*22 + kt)*256 + n*16 + g] ----
__global__ __launch_bounds__(256) void k_bias_expand(
    const float* __restrict__ rpb,   // (3, 2197, 2)
    __fp16* __restrict__ bexp16)
{
    const int tile = blockIdx.x;     // ((blk*2+h)*22 + qt)*22 + kt
    const int kt = tile % NTILE;
    const int rest = tile / NTILE;
    const int qt = rest % NTILE;
    const int bh = rest / NTILE;
    const int blk = bh >> 1, h = bh & 1;
    const int tid = threadIdx.x;     // n*16 + g
    const int n = tid >> 4, g = tid & 15;
    const int i = qt * 16 + n, j = kt * 16 + g;
    float val;
    if (j >= NWTOK) {
        val = -60.f;
    } else if (i >= NWTOK) {
        val = 0.f;
    } else {
        const int iz = i / 49, ir = i - iz * 49, iy = ir / 7, ix = ir - iy * 7;
        const int jz = j / 49, jr = j - jz * 49, jy = jr / 7, jx = jr - jy * 7;
        const int idx = (iz - jz + 6) * 169 + (iy - jy + 6) * 13 + (ix - jx + 6);
        val = rpb[((size_t)blk * 2197 + idx) * 2 + h] * LOG2E;
    }
    bexp16[(size_t)tile * 256 + tid] = (__fp16)val;
}

// ---------------- K0: patch embed + LN + LN1 + QKV(block 0) ----------------
__global__ __launch_bounds__(256, 2) void k0_patch_qkv(
    const float* __restrict__ x,
    const float* __restrict__ pe_w,
    const float* __restrict__ pe_bias,
    const float* __restrict__ pe_g,
    const float* __restrict__ pe_b,
    const float* __restrict__ n1_g,
    const float* __restrict__ n1_b,
    const float* __restrict__ qkv_w,
    float* __restrict__ xe,
    u32* __restrict__ qg,
    u32* __restrict__ kg,
    u32* __restrict__ vg)
{
    __shared__ float w_s[128];
    __shared__ float pb_s[16], g_s[16], b_s[16], n1g_s[16], n1b_s[16];
    __shared__ float qkvw_s[768];
    const int tid = threadIdx.x;
    if (tid < 128) w_s[tid] = pe_w[tid];
    if (tid < 16) {
        pb_s[tid] = pe_bias[tid]; g_s[tid] = pe_g[tid]; b_s[tid] = pe_b[tid];
        n1g_s[tid] = n1_g[tid]; n1b_s[tid] = n1_b[tid];
    }
    for (int i = tid; i < 768; i += 256) qkvw_s[i] = qkv_w[i];
    __syncthreads();
    const int g = blockIdx.x * 256 + tid;
    if (g >= NTOK) return;
    const int z = g / 2401;
    const int r = g - z * 2401;
    const int y = r / 49;
    const int xx = r - y * 49;
    const float* bp = x + ((2 * z) * 98 + (2 * y)) * 98 + 2 * xx;
    float in[8];
    in[0] = bp[0];    in[1] = bp[1];
    in[2] = bp[98];   in[3] = bp[99];
    in[4] = bp[9604]; in[5] = bp[9605];
    in[6] = bp[9702]; in[7] = bp[9703];
    float v[16];
    float mu = 0.f;
    #pragma unroll
    for (int c = 0; c < 16; ++c) {
        float a = pb_s[c];
        #pragma unroll
        for (int k = 0; k < 8; ++k) a = fmaf(in[k], w_s[c * 8 + k], a);
        v[c] = a; mu += a;
    }
    mu *= 0.0625f;
    float var = 0.f;
    #pragma unroll
    for (int c = 0; c < 16; ++c) { float d = v[c] - mu; var = fmaf(d, d, var); }
    var *= 0.0625f;
    float rs = rsqrtf(var + 1e-5f);
    float o[16];
    #pragma unroll
    for (int c = 0; c < 16; ++c) o[c] = (v[c] - mu) * rs * g_s[c] + b_s[c];

    const int zw = z / 7, zi = z - zw * 7;
    const int yw = y / 7, yi = y - yw * 7;
    const int xw = xx / 7, xi = xx - xw * 7;
    const int w = (zw * 7 + yw) * 7 + xw;
    const int t = (zi * 7 + yi) * 7 + xi;
    const int widx = w * NWTOK + t;

    float4* dst = (float4*)(xe + (size_t)widx * 16);
    dst[0] = ((float4*)o)[0]; dst[1] = ((float4*)o)[1];
    dst[2] = ((float4*)o)[2]; dst[3] = ((float4*)o)[3];

    mu = 0.f;
    #pragma unroll
    for (int c = 0; c < 16; ++c) mu += o[c];
    mu *= 0.0625f;
    var = 0.f;
    #pragma unroll
    for (int c = 0; c < 16; ++c) { float d = o[c] - mu; var = fmaf(d, d, var); }
    var *= 0.0625f;
    rs = rsqrtf(var + 1e-5f);
    float yv[16];
    #pragma unroll
    for (int c = 0; c < 16; ++c) yv[c] = (o[c] - mu) * rs * n1g_s[c] + n1b_s[c];

    float tmp[16];
    #pragma unroll
    for (int rr = 0; rr < 16; ++rr) tmp[rr] = dot16_lds(qkvw_s + rr * 16, yv) * QSCALE;
    store_f16_row(qg + (size_t)(w * 2) * QPLANE, t, tmp);
    store_f16_row(qg + (size_t)(w * 2 + 1) * QPLANE, t, tmp + 8);
    #pragma unroll
    for (int rr = 0; rr < 16; ++rr) tmp[rr] = dot16_lds(qkvw_s + (16 + rr) * 16, yv);
    store_f16_row(kg + (size_t)(w * 2) * QPLANE, t, tmp);
    store_f16_row(kg + (size_t)(w * 2 + 1) * QPLANE, t, tmp + 8);
    #pragma unroll
    for (int rr = 0; rr < 16; ++rr) tmp[rr] = dot16_lds(qkvw_s + (32 + rr) * 16, yv);
    store_f16_row(vg + (size_t)(w * 2) * QPLANE, t, tmp);
    store_f16_row(vg + (size_t)(w * 2 + 1) * QPLANE, t, tmp + 8);
}

// ---- K_attn: WG = (window-pair, head); 11 waves; 1 qt-pair/wave x 2 windows ----
__global__ __launch_bounds__(704, 5) void k_attn(
    const u32* __restrict__ qg,
    const u32* __restrict__ kg,
    const u32* __restrict__ vg,
    float* __restrict__ og,
    const __fp16* __restrict__ bexp_blk)   // this block's [2][22][22][256] f16 tiles
{
    __shared__ __fp16 Kl[2][NPAD][16];
    __shared__ __fp16 Ql[2][NPAD][16];
    __shared__ __fp16 Vt[2][16][360];

    const int tid = threadIdx.x;
    const int pidx = blockIdx.x;
    const int wp = pidx >> 1;
    const int h = pidx & 1;
    const int w0 = 2 * wp;
    const int w1 = (w0 + 1 < NWTOK) ? w0 + 1 : NWTOK - 1;
    const int wh0 = w0 * 2 + h;
    const int wh1 = w1 * 2 + h;

    {
        const int sw = (tid >= NPAD) ? 1 : 0;
        const int st = tid - sw * NPAD;
        const size_t qpl = (size_t)(sw ? wh1 : wh0) * QPLANE;
        const uint4 z4 = make_uint4(0, 0, 0, 0);
        if (st < NWTOK) {
            const uint4 kw = ((const uint4*)(kg + qpl))[st];
            const uint4 qw = ((const uint4*)(qg + qpl))[st];
            const uint4 vw = ((const uint4*)(vg + qpl))[st];
            *(uint4*)&Kl[sw][st][0] = kw; *(uint4*)&Kl[sw][st][8] = z4;
            *(uint4*)&Ql[sw][st][0] = qw; *(uint4*)&Ql[sw][st][8] = z4;
            const h2 v01 = __builtin_bit_cast(h2, vw.x);
            const h2 v23 = __builtin_bit_cast(h2, vw.y);
            const h2 v45 = __builtin_bit_cast(h2, vw.z);
            const h2 v67 = __builtin_bit_cast(h2, vw.w);
            Vt[sw][0][st] = v01.x; Vt[sw][1][st] = v01.y;
            Vt[sw][2][st] = v23.x; Vt[sw][3][st] = v23.y;
            Vt[sw][4][st] = v45.x; Vt[sw][5][st] = v45.y;
            Vt[sw][6][st] = v67.x; Vt[sw][7][st] = v67.y;
        } else {
            *(uint4*)&Kl[sw][st][0] = z4; *(uint4*)&Kl[sw][st][8] = z4;
            *(uint4*)&Ql[sw][st][0] = z4; *(uint4*)&Ql[sw][st][8] = z4;
            #pragma unroll
            for (int d = 0; d < 8; ++d) Vt[sw][d][st] = (__fp16)0.f;
        }
        #pragma unroll
        for (int d = 8; d < 16; ++d) Vt[sw][d][st] = (__fp16)0.f;
    }
    __syncthreads();

    const int wave = tid >> 6;        // 0..10 == qt-pair index
    const int lane = tid & 63;
    const int n = lane & 15;
    const int g4 = (lane >> 4) * 4;

    const int qiA = (2 * wave) * 16 + n;
    const int qiB = qiA + 16;
    const h4 bqA0 = *(const h4*)&Ql[0][qiA][g4];
    const h4 bqB0 = *(const h4*)&Ql[0][qiB][g4];
    const h4 bqA1 = *(const h4*)&Ql[1][qiA][g4];
    const h4 bqB1 = *(const h4*)&Ql[1][qiB][g4];

    const int laneoff = n * 16 + g4;
    const __fp16* trowA = bexp_blk + ((size_t)(h * 484) + (size_t)(2 * wave) * NTILE) * 256 + laneoff;
    const __fp16* trowB = trowA + (size_t)NTILE * 256;

    f32x4 accA0 = {0.f, 0.f, 0.f, 0.f}, accB0 = {0.f, 0.f, 0.f, 0.f};
    f32x4 accA1 = {0.f, 0.f, 0.f, 0.f}, accB1 = {0.f, 0.f, 0.f, 0.f};
    float lA0 = 0.f, lB0 = 0.f, lA1 = 0.f, lB1 = 0.f;

    #pragma unroll
    for (int kt = 0; kt < NTILE; ++kt) {
        const uint2 cbA16 = *(const uint2*)(trowA + kt * 256);
        const uint2 cbB16 = *(const uint2*)(trowB + kt * 256);
        const h2 alo = __builtin_bit_cast(h2, cbA16.x);
        const h2 ahi = __builtin_bit_cast(h2, cbA16.y);
        const h2 blo = __builtin_bit_cast(h2, cbB16.x);
        const h2 bhi = __builtin_bit_cast(h2, cbB16.y);
        f32x4 cbAf, cbBf;
        cbAf[0] = (float)alo.x; cbAf[1] = (float)alo.y;
        cbAf[2] = (float)ahi.x; cbAf[3] = (float)ahi.y;
        cbBf[0] = (float)blo.x; cbBf[1] = (float)blo.y;
        cbBf[2] = (float)bhi.x; cbBf[3] = (float)bhi.y;

        const h4 ak0 = *(const h4*)&Kl[0][kt * 16 + n][g4];
        const h4 ak1 = *(const h4*)&Kl[1][kt * 16 + n][g4];
        const h4 av0 = *(const h4*)&Vt[0][n][kt * 16 + g4];
        const h4 av1 = *(const h4*)&Vt[1][n][kt * 16 + g4];

        f32x4 sA0 = __builtin_amdgcn_mfma_f32_16x16x16f16(ak0, bqA0, cbAf, 0, 0, 0);
        f32x4 sB0 = __builtin_amdgcn_mfma_f32_16x16x16f16(ak0, bqB0, cbBf, 0, 0, 0);
        f32x4 sA1 = __builtin_amdgcn_mfma_f32_16x16x16f16(ak1, bqA1, cbAf, 0, 0, 0);
        f32x4 sB1 = __builtin_amdgcn_mfma_f32_16x16x16f16(ak1, bqB1, cbBf, 0, 0, 0);

        const float pA00 = fast_exp2(sA0[0]);
        const float pA01 = fast_exp2(sA0[1]);
        const float pA02 = fast_exp2(sA0[2]);
        const float pA03 = fast_exp2(sA0[3]);
        const float pB00 = fast_exp2(sB0[0]);
        const float pB01 = fast_exp2(sB0[1]);
        const float pB02 = fast_exp2(sB0[2]);
        const float pB03 = fast_exp2(sB0[3]);
        const float pA10 = fast_exp2(sA1[0]);
        const float pA11 = fast_exp2(sA1[1]);
        const float pA12 = fast_exp2(sA1[2]);
        const float pA13 = fast_exp2(sA1[3]);
        const float pB10 = fast_exp2(sB1[0]);
        const float pB11 = fast_exp2(sB1[1]);
        const float pB12 = fast_exp2(sB1[2]);
        const float pB13 = fast_exp2(sB1[3]);

        lA0 += (pA00 + pA01) + (pA02 + pA03);
        lB0 += (pB00 + pB01) + (pB02 + pB03);
        lA1 += (pA10 + pA11) + (pA12 + pA13);
        lB1 += (pB10 + pB11) + (pB12 + pB13);

        const h4 bpA0 = __builtin_bit_cast(h4, make_uint2(packh2(pA00, pA01), packh2(pA02, pA03)));
        const h4 bpB0 = __builtin_bit_cast(h4, make_uint2(packh2(pB00, pB01), packh2(pB02, pB03)));
        const h4 bpA1 = __builtin_bit_cast(h4, make_uint2(packh2(pA10, pA11), packh2(pA12, pA13)));
        const h4 bpB1 = __builtin_bit_cast(h4, make_uint2(packh2(pB10, pB11), packh2(pB12, pB13)));

        accA0 = __builtin_amdgcn_mfma_f32_16x16x16f16(av0, bpA0, accA0, 0, 0, 0);
        accB0 = __builtin_amdgcn_mfma_f32_16x16x16f16(av0, bpB0, accB0, 0, 0, 0);
        accA1 = __builtin_amdgcn_mfma_f32_16x16x16f16(av1, bpA1, accA1, 0, 0, 0);
        accB1 = __builtin_amdgcn_mfma_f32_16x16x16f16(av1, bpB1, accB1, 0, 0, 0);
    }

    lA0 += __shfl_xor(lA0, 16); lA0 += __shfl_xor(lA0, 32);
    lB0 += __shfl_xor(lB0, 16); lB0 += __shfl_xor(lB0, 32);
    lA1 += __shfl_xor(lA1, 16); lA1 += __shfl_xor(lA1, 32);
    lB1 += __shfl_xor(lB1, 16); lB1 += __shfl_xor(lB1, 32);

    if (g4 < 8) {
        if (qiA < NWTOK) {
            const f32x4 o0 = accA0 * (1.f / lA0);
            *(f32x4*)(og + (size_t)wh0 * OPLANE + qiA * 8 + g4) = o0;
            const f32x4 o1 = accA1 * (1.f / lA1);
            *(f32x4*)(og + (size_t)wh1 * OPLANE + qiA * 8 + g4) = o1;
        }
        if (qiB < NWTOK) {
            const f32x4 o0 = accB0 * (1.f / lB0);
            *(f32x4*)(og + (size_t)wh0 * OPLANE + qiB * 8 + g4) = o0;
            const f32x4 o1 = accB1 * (1.f / lB1);
            *(f32x4*)(og + (size_t)wh1 * OPLANE + qiB * 8 + g4) = o1;
        }
    }
}

// ------- K_post: 1 token/thread; f16-packed LDS weights; dot = 2 b128 + 8 fdot2 -------
__global__ __launch_bounds__(256, 4) void k_post(
    float* __restrict__ xe,
    const float* __restrict__ og,
    u32* __restrict__ qg,
    u32* __restrict__ kg,
    u32* __restrict__ vg,
    const float* __restrict__ proj_w,
    const float* __restrict__ proj_b,
    const float* __restrict__ n2_g,
    const float* __restrict__ n2_b,
    const float* __restrict__ fc1_w,
    const float* __restrict__ fc1_b,
    const float* __restrict__ fc2_w,
    const float* __restrict__ fc2_b,
    const float* __restrict__ n1_g_nx,
    const float* __restrict__ n1_b_nx,
    const float* __restrict__ qkv_w_nx,
    float* __restrict__ outp,
    const int last)
{
    __shared__ u32 projh[128];     // (16,16) f16
    __shared__ u32 fc1h[512];      // (64,16) f16
    __shared__ u32 fc2h[512];      // (16,64) f16
    __shared__ u32 qkvh[384];      // (48,16) f16
    __shared__ float projb_s[16], n2g_s[16], n2b_s[16], fc2b_s[16], n1g_s[16], n1b_s[16];
    __shared__ float fc1b_s[64];
    const int tid = threadIdx.x;
    if (tid < 128) {
        const float2 p = ((const float2*)proj_w)[tid];
        projh[tid] = packh2(p.x, p.y);
    }
    for (int i = tid; i < 512; i += 256) {
        const float2 a = ((const float2*)fc1_w)[i];
        fc1h[i] = packh2(a.x, a.y);
        const float2 b = ((const float2*)fc2_w)[i];
        fc2h[i] = packh2(b.x, b.y);
    }
    for (int i = tid; i < 384; i += 256) {
        const float2 a = ((const float2*)qkv_w_nx)[i];
        qkvh[i] = packh2(a.x, a.y);
    }
    if (tid < 16) {
        projb_s[tid] = proj_b[tid];
        n2g_s[tid] = n2_g[tid]; n2b_s[tid] = n2_b[tid];
        fc2b_s[tid] = fc2_b[tid];
        n1g_s[tid] = n1_g_nx[tid]; n1b_s[tid] = n1_b_nx[tid];
    }
    if (tid < 64) fc1b_s[tid] = fc1_b[tid];
    __syncthreads();

    const int widx = blockIdx.x * 256 + tid;
    if (widx >= NTOK) return;
    const int w = widx / NWTOK;
    const int t = widx - w * NWTOK;

    float o[16];
    const float* o0 = og + (size_t)(w * 2) * OPLANE + t * 8;
    const float* o1 = og + (size_t)(w * 2 + 1) * OPLANE + t * 8;
    ((float4*)o)[0] = ((const float4*)o0)[0]; ((float4*)o)[1] = ((const float4*)o0)[1];
    ((float4*)o)[2] = ((const float4*)o1)[0]; ((float4*)o)[3] = ((const float4*)o1)[1];

    float xr[16];
    const float4* xs = (const float4*)(xe + (size_t)widx * 16);
    ((float4*)xr)[0] = xs[0]; ((float4*)xr)[1] = xs[1];
    ((float4*)xr)[2] = xs[2]; ((float4*)xr)[3] = xs[3];

    // ---- proj + residual (o packed once, weights f16) ----
    {
        u32 op[8];
        #pragma unroll
        for (int i = 0; i < 8; ++i) op[i] = packh2(o[2 * i], o[2 * i + 1]);
        float pb[16];
        #pragma unroll
        for (int q = 0; q < 4; ++q) ((float4*)pb)[q] = *(const float4*)(projb_s + q * 4);
        #pragma unroll
        for (int c = 0; c < 16; ++c) xr[c] += dot16h(projh + c * 8, op, pb[c]);
    }

    // ---- LN2 ----
    float mu = 0.f;
    #pragma unroll
    for (int c = 0; c < 16; ++c) mu += xr[c];
    mu *= 0.0625f;
    float var = 0.f;
    #pragma unroll
    for (int c = 0; c < 16; ++c) { float d = xr[c] - mu; var = fmaf(d, d, var); }
    var *= 0.0625f;
    float rs = rsqrtf(var + 1e-5f);
    u32 zp[8];
    {
        float g2[16], b2[16];
        #pragma unroll
        for (int q = 0; q < 4; ++q) {
            ((float4*)g2)[q] = *(const float4*)(n2g_s + q * 4);
            ((float4*)b2)[q] = *(const float4*)(n2b_s + q * 4);
        }
        #pragma unroll
        for (int i = 0; i < 8; ++i) {
            const float za = (xr[2 * i] - mu) * rs * g2[2 * i] + b2[2 * i];
            const float zb = (xr[2 * i + 1] - mu) * rs * g2[2 * i + 1] + b2[2 * i + 1];
            zp[i] = packh2(za, zb);
        }
    }

    // ---- MLP (chunked 16), accumulate into xr ----
    {
        float f2b[16];
        #pragma unroll
        for (int q = 0; q < 4; ++q) ((float4*)f2b)[q] = *(const float4*)(fc2b_s + q * 4);
        #pragma unroll
        for (int c = 0; c < 16; ++c) xr[c] += f2b[c];
    }
    #pragma unroll
    for (int ch = 0; ch < 4; ++ch) {
        float f1b[16];
        #pragma unroll
        for (int q = 0; q < 4; ++q) ((float4*)f1b)[q] = *(const float4*)(fc1b_s + ch * 16 + q * 4);
        float hv[16];
        #pragma unroll
        for (int mm = 0; mm < 16; ++mm)
            hv[mm] = gelu_exact(dot16h(fc1h + (ch * 16 + mm) * 8, zp, f1b[mm]));
        u32 hp[8];
        #pragma unroll
        for (int i = 0; i < 8; ++i) hp[i] = packh2(hv[2 * i], hv[2 * i + 1]);
        #pragma unroll
        for (int c = 0; c < 16; ++c)
            xr[c] = dot16h(fc2h + c * 32 + ch * 8, hp, xr[c]);
    }

    if (last) {
        const int wd = w / 49, wr2 = w - wd * 49, whh = wr2 / 7, www = wr2 - whh * 7;
        const int tz = t / 49, tr2 = t - tz * 49, ty = tr2 / 7, tx = tr2 - ty * 7;
        const int g = ((wd * 7 + tz) * 49 + (whh * 7 + ty)) * 49 + (www * 7 + tx);
        #pragma unroll
        for (int c = 0; c < 16; ++c) outp[(size_t)c * NTOK + g] = xr[c];
        return;
    }

    float4* dst = (float4*)(xe + (size_t)widx * 16);
    dst[0] = ((float4*)xr)[0]; dst[1] = ((float4*)xr)[1];
    dst[2] = ((float4*)xr)[2]; dst[3] = ((float4*)xr)[3];

    // ---- LN1 + QKV for next block ----
    mu = 0.f;
    #pragma unroll
    for (int c = 0; c < 16; ++c) mu += xr[c];
    mu *= 0.0625f;
    var = 0.f;
    #pragma unroll
    for (int c = 0; c < 16; ++c) { float d = xr[c] - mu; var = fmaf(d, d, var); }
    var *= 0.0625f;
    rs = rsqrtf(var + 1e-5f);
    u32 yp[8];
    {
        float g1[16], b1[16];
        #pragma unroll
        for (int q = 0; q < 4; ++q) {
            ((float4*)g1)[q] = *(const float4*)(n1g_s + q * 4);
            ((float4*)b1)[q] = *(const float4*)(n1b_s + q * 4);
        }
        #pragma unroll
        for (int i = 0; i < 8; ++i) {
            const float ya = (xr[2 * i] - mu) * rs * g1[2 * i] + b1[2 * i];
            const float yb = (xr[2 * i + 1] - mu) * rs * g1[2 * i + 1] + b1[2 * i + 1];
            yp[i] = packh2(ya, yb);
        }
    }

    float tmp[16];
    #pragma unroll
    for (int rr = 0; rr < 16; ++rr) tmp[rr] = dot16h(qkvh + rr * 8, yp, 0.f) * QSCALE;
    store_f16_row(qg + (size_t)(w * 2) * QPLANE, t, tmp);
    store_f16_row(qg + (size_t)(w * 2 + 1) * QPLANE, t, tmp + 8);
    #pragma unroll
    for (int rr = 0; rr < 16; ++rr) tmp[rr] = dot16h(qkvh + (16 + rr) * 8, yp, 0.f);
    store_f16_row(kg + (size_t)(w * 2) * QPLANE, t, tmp);
    store_f16_row(kg + (size_t)(w * 2 + 1) * QPLANE, t, tmp + 8);
    #pragma unroll
    for (int rr = 0; rr < 16; ++rr) tmp[rr] = dot16h(qkvh + (32 + rr) * 8, yp, 0.f);
    store_f16_row(vg + (size_t)(w * 2) * QPLANE, t, tmp);
    store_f16_row(vg + (size_t)(w * 2 + 1) * QPLANE, t, tmp + 8);
}

extern "C" void kernel_launch(void* const* d_in, const int* in_sizes, int n_in,
                              void* d_out, int out_size, void* d_ws, size_t ws_size,
                              hipStream_t stream) {
    const float* x       = (const float*)d_in[0];
    const float* pe_w    = (const float*)d_in[1];
    const float* pe_bias = (const float*)d_in[2];
    const float* pe_g    = (const float*)d_in[3];
    const float* pe_b    = (const float*)d_in[4];
    const float* n1_g    = (const float*)d_in[5];
    const float* n1_b    = (const float*)d_in[6];
    const float* qkv_w   = (const float*)d_in[7];
    const float* rpb     = (const float*)d_in[8];
    const float* proj_w  = (const float*)d_in[9];
    const float* proj_b  = (const float*)d_in[10];
    const float* n2_g    = (const float*)d_in[11];
    const float* n2_b    = (const float*)d_in[12];
    const float* fc1_w   = (const float*)d_in[13];
    const float* fc1_b   = (const float*)d_in[14];
    const float* fc2_w   = (const float*)d_in[15];
    const float* fc2_b   = (const float*)d_in[16];

    float* ws = (float*)d_ws;
    const size_t SEG = (size_t)NTOK * 16;     // 1,882,384 floats
    const size_t QSEG = (size_t)686 * QPLANE; // 941,192 u32
    float* xe = ws;
    u32* qg = (u32*)(ws + SEG);
    u32* kg = qg + QSEG;
    u32* vg = kg + QSEG;
    float* og = (float*)(vg + QSEG);                  // 686*2744 f32
    __fp16* bexp16 = (__fp16*)(og + (size_t)686 * OPLANE); // 6*484*256 f16
    float* out = (float*)d_out;

    k_bias_expand<<<6 * NTILE * NTILE, 256, 0, stream>>>(rpb, bexp16);

    k0_patch_qkv<<<(NTOK + 255) / 256, 256, 0, stream>>>(
        x, pe_w, pe_bias, pe_g, pe_b, n1_g, n1_b, qkv_w, xe, qg, kg, vg);

    for (int i = 0; i < 3; ++i) {
        const int last = (i == 2) ? 1 : 0;
        const int nx = last ? i : i + 1;
        k_attn<<<344, 704, 0, stream>>>(
            qg, kg, vg, og, bexp16 + (size_t)i * 2 * 484 * 256);
        k_post<<<(NTOK + 255) / 256, 256, 0, stream>>>(
            xe, og, qg, kg, vg,
            proj_w + (size_t)i * 256, proj_b + (size_t)i * 16,
            n2_g + (size_t)i * 16, n2_b + (size_t)i * 16,
            fc1_w + (size_t)i * 1024, fc1_b + (size_t)i * 64,
            fc2_w + (size_t)i * 1024, fc2_b + (size_t)i * 16,
            n1_g + (size_t)nx * 16, n1_b + (size_t)nx * 16,
            qkv_w + (size_t)nx * 768,
            out, last);
    }
}

// Round 15
// 141.735 us; speedup vs baseline: 2.0768x; 1.1483x over previous
//
#include <hip/hip_runtime.h>
#include <math.h>

#define NWTOK 343
#define NTOK 117649
#define QSCALE 0.510069734f   // (1/sqrt(8)) * log2(e)
#define LOG2E 1.4426950408889634f
#define QPLANE 1372   // u32 per (window,head) plane of f16 rows
#define OPLANE 2744   // f32 per (window,head) plane of o
#define NPAD 352
#define NTILE 22

typedef unsigned int u32;
typedef __fp16 h2 __attribute__((ext_vector_type(2)));
typedef __fp16 h4 __attribute__((ext_vector_type(4)));
typedef float f32x4 __attribute__((ext_vector_type(4)));

__device__ __forceinline__ u32 packh2(float a, float b) {
    h2 h = __builtin_amdgcn_cvt_pkrtz(a, b);
    return __builtin_bit_cast(u32, h);
}
__device__ __forceinline__ h4 packh4(float a, float b, float c, float d) {
    return __builtin_bit_cast(h4, make_uint2(packh2(a, b), packh2(c, d)));
}
__device__ __forceinline__ float fast_exp2(float x) {
#if __has_builtin(__builtin_amdgcn_exp2f)
    return __builtin_amdgcn_exp2f(x);
#else
    return exp2f(x);
#endif
}

// dot of v[16] with 16 consecutive LDS floats via 4x ds_read_b128
__device__ __forceinline__ float dot16_lds(const float* __restrict__ wrow,
                                           const float* __restrict__ v) {
    const float4 w0 = *(const float4*)(wrow);
    const float4 w1 = *(const float4*)(wrow + 4);
    const float4 w2 = *(const float4*)(wrow + 8);
    const float4 w3 = *(const float4*)(wrow + 12);
    float a = v[0] * w0.x;
    a = fmaf(v[1], w0.y, a); a = fmaf(v[2], w0.z, a); a = fmaf(v[3], w0.w, a);
    a = fmaf(v[4], w1.x, a); a = fmaf(v[5], w1.y, a); a = fmaf(v[6], w1.z, a);
    a = fmaf(v[7], w1.w, a);
    a = fmaf(v[8], w2.x, a); a = fmaf(v[9], w2.y, a); a = fmaf(v[10], w2.z, a);
    a = fmaf(v[11], w2.w, a);
    a = fmaf(v[12], w3.x, a); a = fmaf(v[13], w3.y, a); a = fmaf(v[14], w3.z, a);
    a = fmaf(v[15], w3.w, a);
    return a;
}

// Inline exact-GELU via Abramowitz-Stegun 7.1.26 erf (max abs err 1.5e-7).
__device__ __forceinline__ float gelu_exact(float x) {
    const float z = x * 0.70710678118654752f;
    const float az = fabsf(z);
    const float t = __builtin_amdgcn_rcpf(fmaf(0.3275911f, az, 1.0f));
    float y = fmaf(t, 1.061405429f, -1.453152027f);
    y = fmaf(t, y, 1.421413741f);
    y = fmaf(t, y, -0.284496736f);
    y = fmaf(t, y, 0.254829592f);
    y *= t;
    const float one_m_erf = y * __expf(-az * az);
    const float erf_az = 1.0f - one_m_erf;
    const float erf_z = (z < 0.f) ? -erf_az : erf_az;
    return 0.5f * x * (1.0f + erf_z);
}

__device__ __forceinline__ void store_f16_row(u32* base, int t, const float* v8) {
    uint4 u;
    u.x = packh2(v8[0], v8[1]); u.y = packh2(v8[2], v8[3]);
    u.z = packh2(v8[4], v8[5]); u.w = packh2(v8[6], v8[7]);
    *(uint4*)(base + t * 4) = u;
}

// ---- bias expand, f16 TILED: bexp16[((bh)*484 + qt*22 + kt)*256 + n*16 + g] ----
__global__ __launch_bounds__(256) void k_bias_expand(
    const float* __restrict__ rpb,   // (3, 2197, 2)
    __fp16* __restrict__ bexp16)
{
    const int tile = blockIdx.x;     // ((blk*2+h)*22 + qt)*22 + kt
    const int kt = tile % NTILE;
    const int rest = tile / NTILE;
    const int qt = rest % NTILE;
    const int bh = rest / NTILE;
    const int blk = bh >> 1, h = bh & 1;
    const int tid = threadIdx.x;     // n*16 + g
    const int n = tid >> 4, g = tid & 15;
    const int i = qt * 16 + n, j = kt * 16 + g;
    float val;
    if (j >= NWTOK) {
        val = -60.f;
    } else if (i >= NWTOK) {
        val = 0.f;
    } else {
        const int iz = i / 49, ir = i - iz * 49, iy = ir / 7, ix = ir - iy * 7;
        const int jz = j / 49, jr = j - jz * 49, jy = jr / 7, jx = jr - jy * 7;
        const int idx = (iz - jz + 6) * 169 + (iy - jy + 6) * 13 + (ix - jx + 6);
        val = rpb[((size_t)blk * 2197 + idx) * 2 + h] * LOG2E;
    }
    bexp16[(size_t)tile * 256 + tid] = (__fp16)val;
}

// ---------------- K0: patch embed + LN + LN1 + QKV(block 0) ----------------
__global__ __launch_bounds__(256, 2) void k0_patch_qkv(
    const float* __restrict__ x,
    const float* __restrict__ pe_w,
    const float* __restrict__ pe_bias,
    const float* __restrict__ pe_g,
    const float* __restrict__ pe_b,
    const float* __restrict__ n1_g,
    const float* __restrict__ n1_b,
    const float* __restrict__ qkv_w,
    float* __restrict__ xe,
    u32* __restrict__ qg,
    u32* __restrict__ kg,
    u32* __restrict__ vg)
{
    __shared__ float w_s[128];
    __shared__ float pb_s[16], g_s[16], b_s[16], n1g_s[16], n1b_s[16];
    __shared__ float qkvw_s[768];
    const int tid = threadIdx.x;
    if (tid < 128) w_s[tid] = pe_w[tid];
    if (tid < 16) {
        pb_s[tid] = pe_bias[tid]; g_s[tid] = pe_g[tid]; b_s[tid] = pe_b[tid];
        n1g_s[tid] = n1_g[tid]; n1b_s[tid] = n1_b[tid];
    }
    for (int i = tid; i < 768; i += 256) qkvw_s[i] = qkv_w[i];
    __syncthreads();
    const int g = blockIdx.x * 256 + tid;
    if (g >= NTOK) return;
    const int z = g / 2401;
    const int r = g - z * 2401;
    const int y = r / 49;
    const int xx = r - y * 49;
    const float* bp = x + ((2 * z) * 98 + (2 * y)) * 98 + 2 * xx;
    float in[8];
    in[0] = bp[0];    in[1] = bp[1];
    in[2] = bp[98];   in[3] = bp[99];
    in[4] = bp[9604]; in[5] = bp[9605];
    in[6] = bp[9702]; in[7] = bp[9703];
    float v[16];
    float mu = 0.f;
    #pragma unroll
    for (int c = 0; c < 16; ++c) {
        float a = pb_s[c];
        #pragma unroll
        for (int k = 0; k < 8; ++k) a = fmaf(in[k], w_s[c * 8 + k], a);
        v[c] = a; mu += a;
    }
    mu *= 0.0625f;
    float var = 0.f;
    #pragma unroll
    for (int c = 0; c < 16; ++c) { float d = v[c] - mu; var = fmaf(d, d, var); }
    var *= 0.0625f;
    float rs = rsqrtf(var + 1e-5f);
    float o[16];
    #pragma unroll
    for (int c = 0; c < 16; ++c) o[c] = (v[c] - mu) * rs * g_s[c] + b_s[c];

    const int zw = z / 7, zi = z - zw * 7;
    const int yw = y / 7, yi = y - yw * 7;
    const int xw = xx / 7, xi = xx - xw * 7;
    const int w = (zw * 7 + yw) * 7 + xw;
    const int t = (zi * 7 + yi) * 7 + xi;
    const int widx = w * NWTOK + t;

    float4* dst = (float4*)(xe + (size_t)widx * 16);
    dst[0] = ((float4*)o)[0]; dst[1] = ((float4*)o)[1];
    dst[2] = ((float4*)o)[2]; dst[3] = ((float4*)o)[3];

    mu = 0.f;
    #pragma unroll
    for (int c = 0; c < 16; ++c) mu += o[c];
    mu *= 0.0625f;
    var = 0.f;
    #pragma unroll
    for (int c = 0; c < 16; ++c) { float d = o[c] - mu; var = fmaf(d, d, var); }
    var *= 0.0625f;
    rs = rsqrtf(var + 1e-5f);
    float yv[16];
    #pragma unroll
    for (int c = 0; c < 16; ++c) yv[c] = (o[c] - mu) * rs * n1g_s[c] + n1b_s[c];

    float tmp[16];
    #pragma unroll
    for (int rr = 0; rr < 16; ++rr) tmp[rr] = dot16_lds(qkvw_s + rr * 16, yv) * QSCALE;
    store_f16_row(qg + (size_t)(w * 2) * QPLANE, t, tmp);
    store_f16_row(qg + (size_t)(w * 2 + 1) * QPLANE, t, tmp + 8);
    #pragma unroll
    for (int rr = 0; rr < 16; ++rr) tmp[rr] = dot16_lds(qkvw_s + (16 + rr) * 16, yv);
    store_f16_row(kg + (size_t)(w * 2) * QPLANE, t, tmp);
    store_f16_row(kg + (size_t)(w * 2 + 1) * QPLANE, t, tmp + 8);
    #pragma unroll
    for (int rr = 0; rr < 16; ++rr) tmp[rr] = dot16_lds(qkvw_s + (32 + rr) * 16, yv);
    store_f16_row(vg + (size_t)(w * 2) * QPLANE, t, tmp);
    store_f16_row(vg + (size_t)(w * 2 + 1) * QPLANE, t, tmp + 8);
}

// ---- K_attn: WG = (window-pair, head); 11 waves; 1 qt-pair/wave x 2 windows ----
__global__ __launch_bounds__(704, 5) void k_attn(
    const u32* __restrict__ qg,
    const u32* __restrict__ kg,
    const u32* __restrict__ vg,
    float* __restrict__ og,
    const __fp16* __restrict__ bexp_blk)   // this block's [2][22][22][256] f16 tiles
{
    __shared__ __fp16 Kl[2][NPAD][16];
    __shared__ __fp16 Ql[2][NPAD][16];
    __shared__ __fp16 Vt[2][16][360];

    const int tid = threadIdx.x;
    const int pidx = blockIdx.x;
    const int wp = pidx >> 1;
    const int h = pidx & 1;
    const int w0 = 2 * wp;
    const int w1 = (w0 + 1 < NWTOK) ? w0 + 1 : NWTOK - 1;
    const int wh0 = w0 * 2 + h;
    const int wh1 = w1 * 2 + h;

    {
        const int sw = (tid >= NPAD) ? 1 : 0;
        const int st = tid - sw * NPAD;
        const size_t qpl = (size_t)(sw ? wh1 : wh0) * QPLANE;
        const uint4 z4 = make_uint4(0, 0, 0, 0);
        if (st < NWTOK) {
            const uint4 kw = ((const uint4*)(kg + qpl))[st];
            const uint4 qw = ((const uint4*)(qg + qpl))[st];
            const uint4 vw = ((const uint4*)(vg + qpl))[st];
            *(uint4*)&Kl[sw][st][0] = kw; *(uint4*)&Kl[sw][st][8] = z4;
            *(uint4*)&Ql[sw][st][0] = qw; *(uint4*)&Ql[sw][st][8] = z4;
            const h2 v01 = __builtin_bit_cast(h2, vw.x);
            const h2 v23 = __builtin_bit_cast(h2, vw.y);
            const h2 v45 = __builtin_bit_cast(h2, vw.z);
            const h2 v67 = __builtin_bit_cast(h2, vw.w);
            Vt[sw][0][st] = v01.x; Vt[sw][1][st] = v01.y;
            Vt[sw][2][st] = v23.x; Vt[sw][3][st] = v23.y;
            Vt[sw][4][st] = v45.x; Vt[sw][5][st] = v45.y;
            Vt[sw][6][st] = v67.x; Vt[sw][7][st] = v67.y;
        } else {
            *(uint4*)&Kl[sw][st][0] = z4; *(uint4*)&Kl[sw][st][8] = z4;
            *(uint4*)&Ql[sw][st][0] = z4; *(uint4*)&Ql[sw][st][8] = z4;
            #pragma unroll
            for (int d = 0; d < 8; ++d) Vt[sw][d][st] = (__fp16)0.f;
        }
        #pragma unroll
        for (int d = 8; d < 16; ++d) Vt[sw][d][st] = (__fp16)0.f;
    }
    __syncthreads();

    const int wave = tid >> 6;        // 0..10 == qt-pair index
    const int lane = tid & 63;
    const int n = lane & 15;
    const int g4 = (lane >> 4) * 4;

    const int qiA = (2 * wave) * 16 + n;
    const int qiB = qiA + 16;
    const h4 bqA0 = *(const h4*)&Ql[0][qiA][g4];
    const h4 bqB0 = *(const h4*)&Ql[0][qiB][g4];
    const h4 bqA1 = *(const h4*)&Ql[1][qiA][g4];
    const h4 bqB1 = *(const h4*)&Ql[1][qiB][g4];

    const int laneoff = n * 16 + g4;
    const __fp16* trowA = bexp_blk + ((size_t)(h * 484) + (size_t)(2 * wave) * NTILE) * 256 + laneoff;
    const __fp16* trowB = trowA + (size_t)NTILE * 256;

    f32x4 accA0 = {0.f, 0.f, 0.f, 0.f}, accB0 = {0.f, 0.f, 0.f, 0.f};
    f32x4 accA1 = {0.f, 0.f, 0.f, 0.f}, accB1 = {0.f, 0.f, 0.f, 0.f};
    float lA0 = 0.f, lB0 = 0.f, lA1 = 0.f, lB1 = 0.f;

    #pragma unroll
    for (int kt = 0; kt < NTILE; ++kt) {
        const uint2 cbA16 = *(const uint2*)(trowA + kt * 256);
        const uint2 cbB16 = *(const uint2*)(trowB + kt * 256);
        const h2 alo = __builtin_bit_cast(h2, cbA16.x);
        const h2 ahi = __builtin_bit_cast(h2, cbA16.y);
        const h2 blo = __builtin_bit_cast(h2, cbB16.x);
        const h2 bhi = __builtin_bit_cast(h2, cbB16.y);
        f32x4 cbAf, cbBf;
        cbAf[0] = (float)alo.x; cbAf[1] = (float)alo.y;
        cbAf[2] = (float)ahi.x; cbAf[3] = (float)ahi.y;
        cbBf[0] = (float)blo.x; cbBf[1] = (float)blo.y;
        cbBf[2] = (float)bhi.x; cbBf[3] = (float)bhi.y;

        const h4 ak0 = *(const h4*)&Kl[0][kt * 16 + n][g4];
        const h4 ak1 = *(const h4*)&Kl[1][kt * 16 + n][g4];
        const h4 av0 = *(const h4*)&Vt[0][n][kt * 16 + g4];
        const h4 av1 = *(const h4*)&Vt[1][n][kt * 16 + g4];

        f32x4 sA0 = __builtin_amdgcn_mfma_f32_16x16x16f16(ak0, bqA0, cbAf, 0, 0, 0);
        f32x4 sB0 = __builtin_amdgcn_mfma_f32_16x16x16f16(ak0, bqB0, cbBf, 0, 0, 0);
        f32x4 sA1 = __builtin_amdgcn_mfma_f32_16x16x16f16(ak1, bqA1, cbAf, 0, 0, 0);
        f32x4 sB1 = __builtin_amdgcn_mfma_f32_16x16x16f16(ak1, bqB1, cbBf, 0, 0, 0);

        const float pA00 = fast_exp2(sA0[0]);
        const float pA01 = fast_exp2(sA0[1]);
        const float pA02 = fast_exp2(sA0[2]);
        const float pA03 = fast_exp2(sA0[3]);
        const float pB00 = fast_exp2(sB0[0]);
        const float pB01 = fast_exp2(sB0[1]);
        const float pB02 = fast_exp2(sB0[2]);
        const float pB03 = fast_exp2(sB0[3]);
        const float pA10 = fast_exp2(sA1[0]);
        const float pA11 = fast_exp2(sA1[1]);
        const float pA12 = fast_exp2(sA1[2]);
        const float pA13 = fast_exp2(sA1[3]);
        const float pB10 = fast_exp2(sB1[0]);
        const float pB11 = fast_exp2(sB1[1]);
        const float pB12 = fast_exp2(sB1[2]);
        const float pB13 = fast_exp2(sB1[3]);

        lA0 += (pA00 + pA01) + (pA02 + pA03);
        lB0 += (pB00 + pB01) + (pB02 + pB03);
        lA1 += (pA10 + pA11) + (pA12 + pA13);
        lB1 += (pB10 + pB11) + (pB12 + pB13);

        const h4 bpA0 = packh4(pA00, pA01, pA02, pA03);
        const h4 bpB0 = packh4(pB00, pB01, pB02, pB03);
        const h4 bpA1 = packh4(pA10, pA11, pA12, pA13);
        const h4 bpB1 = packh4(pB10, pB11, pB12, pB13);

        accA0 = __builtin_amdgcn_mfma_f32_16x16x16f16(av0, bpA0, accA0, 0, 0, 0);
        accB0 = __builtin_amdgcn_mfma_f32_16x16x16f16(av0, bpB0, accB0, 0, 0, 0);
        accA1 = __builtin_amdgcn_mfma_f32_16x16x16f16(av1, bpA1, accA1, 0, 0, 0);
        accB1 = __builtin_amdgcn_mfma_f32_16x16x16f16(av1, bpB1, accB1, 0, 0, 0);
    }

    lA0 += __shfl_xor(lA0, 16); lA0 += __shfl_xor(lA0, 32);
    lB0 += __shfl_xor(lB0, 16); lB0 += __shfl_xor(lB0, 32);
    lA1 += __shfl_xor(lA1, 16); lA1 += __shfl_xor(lA1, 32);
    lB1 += __shfl_xor(lB1, 16); lB1 += __shfl_xor(lB1, 32);

    if (g4 < 8) {
        if (qiA < NWTOK) {
            const f32x4 o0 = accA0 * (1.f / lA0);
            *(f32x4*)(og + (size_t)wh0 * OPLANE + qiA * 8 + g4) = o0;
            const f32x4 o1 = accA1 * (1.f / lA1);
            *(f32x4*)(og + (size_t)wh1 * OPLANE + qiA * 8 + g4) = o1;
        }
        if (qiB < NWTOK) {
            const f32x4 o0 = accB0 * (1.f / lB0);
            *(f32x4*)(og + (size_t)wh0 * OPLANE + qiB * 8 + g4) = o0;
            const f32x4 o1 = accB1 * (1.f / lB1);
            *(f32x4*)(og + (size_t)wh1 * OPLANE + qiB * 8 + g4) = o1;
        }
    }
}

// ------- K_post (MFMA): wave = one (window, qt) tile of 16 tokens -------
// All GEMMs computed swapped (W · X^T): D layout (m89) = {col=lane&15=token,
// row=(lane>>4)*4+reg=channel} == the B-fragment layout of the NEXT GEMM,
// so activations flow D -> cvt_pk -> B with zero cross-lane moves. LN stats
// via 2x shfl_xor (16,32). Weights: one broadcast ds_read_b64 per MFMA.
__global__ __launch_bounds__(256, 4) void k_post(
    float* __restrict__ xe,
    const float* __restrict__ og,
    u32* __restrict__ qg,
    u32* __restrict__ kg,
    u32* __restrict__ vg,
    const float* __restrict__ proj_w,
    const float* __restrict__ proj_b,
    const float* __restrict__ n2_g,
    const float* __restrict__ n2_b,
    const float* __restrict__ fc1_w,
    const float* __restrict__ fc1_b,
    const float* __restrict__ fc2_w,
    const float* __restrict__ fc2_b,
    const float* __restrict__ n1_g_nx,
    const float* __restrict__ n1_b_nx,
    const float* __restrict__ qkv_w_nx,
    float* __restrict__ outp,
    const int last)
{
    __shared__ u32 projh[128];     // (16,16) f16: row*8 + k/2
    __shared__ u32 fc1h[512];      // (64,16) f16
    __shared__ u32 fc2h[512];      // (16,64) f16: row*32 + k/2
    __shared__ u32 qkvh[384];      // (48,16) f16
    __shared__ float projb_s[16], n2g_s[16], n2b_s[16], fc2b_s[16], n1g_s[16], n1b_s[16];
    __shared__ float fc1b_s[64];
    const int tid = threadIdx.x;
    if (tid < 128) {
        const float2 p = ((const float2*)proj_w)[tid];
        projh[tid] = packh2(p.x, p.y);
    }
    for (int i = tid; i < 512; i += 256) {
        const float2 a = ((const float2*)fc1_w)[i];
        fc1h[i] = packh2(a.x, a.y);
        const float2 b = ((const float2*)fc2_w)[i];
        fc2h[i] = packh2(b.x, b.y);
    }
    for (int i = tid; i < 384; i += 256) {
        const float2 a = ((const float2*)qkv_w_nx)[i];
        qkvh[i] = packh2(a.x, a.y);
    }
    if (tid < 16) {
        projb_s[tid] = proj_b[tid];
        n2g_s[tid] = n2_g[tid]; n2b_s[tid] = n2_b[tid];
        fc2b_s[tid] = fc2_b[tid];
        n1g_s[tid] = n1_g_nx[tid]; n1b_s[tid] = n1_b_nx[tid];
    }
    if (tid < 64) fc1b_s[tid] = fc1_b[tid];
    __syncthreads();

    const int wave_id = blockIdx.x * 4 + (tid >> 6);
    if (wave_id >= NWTOK * NTILE) return;   // 7546 tiles
    const int w = wave_id / NTILE;
    const int qt = wave_id - w * NTILE;

    const int lane = tid & 63;
    const int tcol = lane & 15;             // token column (also A row index)
    const int g4 = (lane >> 4) * 4;         // channel group base
    const int tok = qt * 16 + tcol;
    const bool valid = (tok < NWTOK);
    const int tokc = valid ? tok : (NWTOK - 1);

    const f32x4 zero = {0.f, 0.f, 0.f, 0.f};

    // ---- B-frag: o^T (ch g4..g4+3 of this token) ----
    const int pl = g4 >> 3;                 // head plane
    const int po = g4 & 7;                  // within-plane ch offset (0 or 4)
    const float4 o4 = *(const float4*)(og + (size_t)(w * 2 + pl) * OPLANE + tokc * 8 + po);
    const h4 oB = packh4(o4.x, o4.y, o4.z, o4.w);

    // ---- proj + residual + bias ----
    const uint2 apw = *(const uint2*)(projh + tcol * 8 + (g4 >> 1));
    const f32x4 d1 = __builtin_amdgcn_mfma_f32_16x16x16f16(
        __builtin_bit_cast(h4, apw), oB, zero, 0, 0, 0);
    const float4 xe4 = *(const float4*)(xe + (size_t)(w * NWTOK + tokc) * 16 + g4);
    const float4 pb4 = *(const float4*)(projb_s + g4);
    float xr0 = d1[0] + xe4.x + pb4.x;
    float xr1 = d1[1] + xe4.y + pb4.y;
    float xr2 = d1[2] + xe4.z + pb4.z;
    float xr3 = d1[3] + xe4.w + pb4.w;

    // ---- LN2 (cross-lane over channel groups) ----
    float s = (xr0 + xr1) + (xr2 + xr3);
    s += __shfl_xor(s, 16); s += __shfl_xor(s, 32);
    float mu = s * 0.0625f;
    float v0 = xr0 - mu, v1 = xr1 - mu, v2 = xr2 - mu, v3 = xr3 - mu;
    float vv = fmaf(v0, v0, fmaf(v1, v1, fmaf(v2, v2, v3 * v3)));
    vv += __shfl_xor(vv, 16); vv += __shfl_xor(vv, 32);
    float rs = rsqrtf(vv * 0.0625f + 1e-5f);
    const float4 g2 = *(const float4*)(n2g_s + g4);
    const float4 b2 = *(const float4*)(n2b_s + g4);
    const h4 zB = packh4(v0 * rs * g2.x + b2.x, v1 * rs * g2.y + b2.y,
                         v2 * rs * g2.z + b2.z, v3 * rs * g2.w + b2.w);

    // ---- fc1 (4 MFMAs) + bias + GELU -> 4 B-frags ----
    h4 hB[4];
    #pragma unroll
    for (int i = 0; i < 4; ++i) {
        const uint2 aw = *(const uint2*)(fc1h + (i * 16 + tcol) * 8 + (g4 >> 1));
        f32x4 hd = __builtin_amdgcn_mfma_f32_16x16x16f16(
            __builtin_bit_cast(h4, aw), zB, zero, 0, 0, 0);
        const float4 fb = *(const float4*)(fc1b_s + i * 16 + g4);
        hB[i] = packh4(gelu_exact(hd[0] + fb.x), gelu_exact(hd[1] + fb.y),
                       gelu_exact(hd[2] + fb.z), gelu_exact(hd[3] + fb.w));
    }

    // ---- fc2 (K=64: 4 chained MFMAs) + bias + residual ----
    f32x4 acc = zero;
    #pragma unroll
    for (int j = 0; j < 4; ++j) {
        const uint2 aw = *(const uint2*)(fc2h + tcol * 32 + ((j * 16 + g4) >> 1));
        acc = __builtin_amdgcn_mfma_f32_16x16x16f16(
            __builtin_bit_cast(h4, aw), hB[j], acc, 0, 0, 0);
    }
    const float4 f2b = *(const float4*)(fc2b_s + g4);
    xr0 += acc[0] + f2b.x;
    xr1 += acc[1] + f2b.y;
    xr2 += acc[2] + f2b.z;
    xr3 += acc[3] + f2b.w;

    if (last) {
        if (valid) {
            const int wd = w / 49, wr2 = w - wd * 49, whh = wr2 / 7, www = wr2 - whh * 7;
            const int tz = tok / 49, tr2 = tok - tz * 49, ty = tr2 / 7, tx = tr2 - ty * 7;
            const int g = ((wd * 7 + tz) * 49 + (whh * 7 + ty)) * 49 + (www * 7 + tx);
            outp[(size_t)(g4 + 0) * NTOK + g] = xr0;
            outp[(size_t)(g4 + 1) * NTOK + g] = xr1;
            outp[(size_t)(g4 + 2) * NTOK + g] = xr2;
            outp[(size_t)(g4 + 3) * NTOK + g] = xr3;
        }
        return;
    }

    if (valid) {
        float4 st = make_float4(xr0, xr1, xr2, xr3);
        *(float4*)(xe + (size_t)(w * NWTOK + tok) * 16 + g4) = st;
    }

    // ---- LN1 ----
    s = (xr0 + xr1) + (xr2 + xr3);
    s += __shfl_xor(s, 16); s += __shfl_xor(s, 32);
    mu = s * 0.0625f;
    v0 = xr0 - mu; v1 = xr1 - mu; v2 = xr2 - mu; v3 = xr3 - mu;
    vv = fmaf(v0, v0, fmaf(v1, v1, fmaf(v2, v2, v3 * v3)));
    vv += __shfl_xor(vv, 16); vv += __shfl_xor(vv, 32);
    rs = rsqrtf(vv * 0.0625f + 1e-5f);
    const float4 g1 = *(const float4*)(n1g_s + g4);
    const float4 b1 = *(const float4*)(n1b_s + g4);
    const h4 yB = packh4(v0 * rs * g1.x + b1.x, v1 * rs * g1.y + b1.y,
                         v2 * rs * g1.z + b1.z, v3 * rs * g1.w + b1.w);

    // ---- QKV for next block (3 MFMAs), store f16 rows ----
    const int head = g4 >> 3;
    const int uoff = (g4 & 7) >> 1;         // u32 offset within the token's 4-u32 row
    const size_t qpl = (size_t)(w * 2 + head) * QPLANE + tok * 4 + uoff;
    #pragma unroll
    for (int m = 0; m < 3; ++m) {
        const uint2 aw = *(const uint2*)(qkvh + (m * 16 + tcol) * 8 + (g4 >> 1));
        f32x4 d = __builtin_amdgcn_mfma_f32_16x16x16f16(
            __builtin_bit_cast(h4, aw), yB, zero, 0, 0, 0);
        float sc = (m == 0) ? QSCALE : 1.f;
        const u32 lo = packh2(d[0] * sc, d[1] * sc);
        const u32 hi = packh2(d[2] * sc, d[3] * sc);
        if (valid) {
            u32* dst = (m == 0 ? qg : (m == 1 ? kg : vg)) + qpl;
            dst[0] = lo;
            dst[1] = hi;
        }
    }
}

extern "C" void kernel_launch(void* const* d_in, const int* in_sizes, int n_in,
                              void* d_out, int out_size, void* d_ws, size_t ws_size,
                              hipStream_t stream) {
    const float* x       = (const float*)d_in[0];
    const float* pe_w    = (const float*)d_in[1];
    const float* pe_bias = (const float*)d_in[2];
    const float* pe_g    = (const float*)d_in[3];
    const float* pe_b    = (const float*)d_in[4];
    const float* n1_g    = (const float*)d_in[5];
    const float* n1_b    = (const float*)d_in[6];
    const float* qkv_w   = (const float*)d_in[7];
    const float* rpb     = (const float*)d_in[8];
    const float* proj_w  = (const float*)d_in[9];
    const float* proj_b  = (const float*)d_in[10];
    const float* n2_g    = (const float*)d_in[11];
    const float* n2_b    = (const float*)d_in[12];
    const float* fc1_w   = (const float*)d_in[13];
    const float* fc1_b   = (const float*)d_in[14];
    const float* fc2_w   = (const float*)d_in[15];
    const float* fc2_b   = (const float*)d_in[16];

    float* ws = (float*)d_ws;
    const size_t SEG = (size_t)NTOK * 16;     // 1,882,384 floats
    const size_t QSEG = (size_t)686 * QPLANE; // 941,192 u32
    float* xe = ws;
    u32* qg = (u32*)(ws + SEG);
    u32* kg = qg + QSEG;
    u32* vg = kg + QSEG;
    float* og = (float*)(vg + QSEG);                  // 686*2744 f32
    __fp16* bexp16 = (__fp16*)(og + (size_t)686 * OPLANE); // 6*484*256 f16
    float* out = (float*)d_out;

    k_bias_expand<<<6 * NTILE * NTILE, 256, 0, stream>>>(rpb, bexp16);

    k0_patch_qkv<<<(NTOK + 255) / 256, 256, 0, stream>>>(
        x, pe_w, pe_bias, pe_g, pe_b, n1_g, n1_b, qkv_w, xe, qg, kg, vg);

    const int post_grid = (NWTOK * NTILE + 3) / 4;    // 7546 tiles, 4 waves/WG
    for (int i = 0; i < 3; ++i) {
        const int last = (i == 2) ? 1 : 0;
        const int nx = last ? i : i + 1;
        k_attn<<<344, 704, 0, stream>>>(
            qg, kg, vg, og, bexp16 + (size_t)i * 2 * 484 * 256);
        k_post<<<post_grid, 256, 0, stream>>>(
            xe, og, qg, kg, vg,
            proj_w + (size_t)i * 256, proj_b + (size_t)i * 16,
            n2_g + (size_t)i * 16, n2_b + (size_t)i * 16,
            fc1_w + (size_t)i * 1024, fc1_b + (size_t)i * 64,
            fc2_w + (size_t)i * 1024, fc2_b + (size_t)i * 16,
            n1_g + (size_t)nx * 16, n1_b + (size_t)nx * 16,
            qkv_w + (size_t)nx * 768,
            out, last);
    }
}

// Round 16
// 130.680 us; speedup vs baseline: 2.2524x; 1.0846x over previous
//
#include <hip/hip_runtime.h>
#include <math.h>

#define NWTOK 343
#define NTOK 117649
#define QSCALE 0.510069734f   // (1/sqrt(8)) * log2(e)
#define LOG2E 1.4426950408889634f
#define QPLANE 1372   // u32 per (window,head) plane of f16 rows
#define OPLANE 2744   // f32 per (window,head) plane of o
#define NPAD 352
#define NTILE 22
#define NBIAS_BLK 2904        // 6*22*22 bias tiles
#define NK0_TILE 7546         // 343*22 token tiles

typedef unsigned int u32;
typedef __fp16 h2 __attribute__((ext_vector_type(2)));
typedef __fp16 h4 __attribute__((ext_vector_type(4)));
typedef float f32x4 __attribute__((ext_vector_type(4)));

__device__ __forceinline__ u32 packh2(float a, float b) {
    h2 h = __builtin_amdgcn_cvt_pkrtz(a, b);
    return __builtin_bit_cast(u32, h);
}
__device__ __forceinline__ h4 packh4(float a, float b, float c, float d) {
    return __builtin_bit_cast(h4, make_uint2(packh2(a, b), packh2(c, d)));
}
__device__ __forceinline__ float fast_exp2(float x) {
#if __has_builtin(__builtin_amdgcn_exp2f)
    return __builtin_amdgcn_exp2f(x);
#else
    return exp2f(x);
#endif
}

// Inline exact-GELU via Abramowitz-Stegun 7.1.26 erf (max abs err 1.5e-7).
__device__ __forceinline__ float gelu_exact(float x) {
    const float z = x * 0.70710678118654752f;
    const float az = fabsf(z);
    const float t = __builtin_amdgcn_rcpf(fmaf(0.3275911f, az, 1.0f));
    float y = fmaf(t, 1.061405429f, -1.453152027f);
    y = fmaf(t, y, 1.421413741f);
    y = fmaf(t, y, -0.284496736f);
    y = fmaf(t, y, 0.254829592f);
    y *= t;
    const float one_m_erf = y * __expf(-az * az);
    const float erf_az = 1.0f - one_m_erf;
    const float erf_z = (z < 0.f) ? -erf_az : erf_az;
    return 0.5f * x * (1.0f + erf_z);
}

// ---- K0 fused: blocks [0,2904) expand bias tiles; blocks >= 2904 do
// patch-embed + LN + LN1 + QKV(block 0) in the MFMA tile structure
// (wave = one (window, qt) tile; verified D layout from k_post). ----
__global__ __launch_bounds__(256, 4) void k0_fused(
    const float* __restrict__ x,
    const float* __restrict__ pe_w,
    const float* __restrict__ pe_bias,
    const float* __restrict__ pe_g,
    const float* __restrict__ pe_b,
    const float* __restrict__ n1_g,
    const float* __restrict__ n1_b,
    const float* __restrict__ qkv_w,
    const float* __restrict__ rpb,     // (3, 2197, 2)
    float* __restrict__ xe,
    u32* __restrict__ qg,
    u32* __restrict__ kg,
    u32* __restrict__ vg,
    __fp16* __restrict__ bexp16)
{
    const int tid = threadIdx.x;

    if (blockIdx.x < NBIAS_BLK) {
        // ---- bias expand, f16 tiled: [((bh)*484 + qt*22 + kt)*256 + n*16 + g] ----
        const int tile = blockIdx.x;
        const int kt = tile % NTILE;
        const int rest = tile / NTILE;
        const int qt = rest % NTILE;
        const int bh = rest / NTILE;
        const int blk = bh >> 1, h = bh & 1;
        const int n = tid >> 4, g = tid & 15;
        const int i = qt * 16 + n, j = kt * 16 + g;
        float val;
        if (j >= NWTOK) {
            val = -60.f;
        } else if (i >= NWTOK) {
            val = 0.f;
        } else {
            const int iz = i / 49, ir = i - iz * 49, iy = ir / 7, ix = ir - iy * 7;
            const int jz = j / 49, jr = j - jz * 49, jy = jr / 7, jx = jr - jy * 7;
            const int idx = (iz - jz + 6) * 169 + (iy - jy + 6) * 13 + (ix - jx + 6);
            val = rpb[((size_t)blk * 2197 + idx) * 2 + h] * LOG2E;
        }
        bexp16[(size_t)tile * 256 + tid] = (__fp16)val;
        return;
    }

    // ---------------- patch embed + LN + LN1 + QKV tile path ----------------
    __shared__ float pw_s[128];
    __shared__ u32 qkvh[384];
    __shared__ float pb_s[16], g_s[16], b_s[16], n1g_s[16], n1b_s[16];

    if (tid < 128) pw_s[tid] = pe_w[tid];
    for (int i = tid; i < 384; i += 256) {
        const float2 a = ((const float2*)qkv_w)[i];
        qkvh[i] = packh2(a.x, a.y);
    }
    if (tid < 16) {
        pb_s[tid] = pe_bias[tid]; g_s[tid] = pe_g[tid]; b_s[tid] = pe_b[tid];
        n1g_s[tid] = n1_g[tid]; n1b_s[tid] = n1_b[tid];
    }
    __syncthreads();

    const int wave_id = (blockIdx.x - NBIAS_BLK) * 4 + (tid >> 6);
    if (wave_id >= NK0_TILE) return;
    const int w = wave_id / NTILE;
    const int qt = wave_id - w * NTILE;

    const int lane = tid & 63;
    const int tcol = lane & 15;
    const int g4 = (lane >> 4) * 4;
    const int tok = qt * 16 + tcol;
    const bool valid = (tok < NWTOK);
    const int tokc = valid ? tok : (NWTOK - 1);

    // global voxel coords for this token
    const int wd = w / 49, wr = w - wd * 49, wh = wr / 7, ww = wr - wh * 7;
    const int tz = tokc / 49, tr = tokc - tz * 49, ty = tr / 7, tx = tr - ty * 7;
    const int z = wd * 7 + tz, y = wh * 7 + ty, xx = ww * 7 + tx;
    const float* bp = x + ((size_t)(2 * z) * 98 + (2 * y)) * 98 + 2 * xx;
    float in[8];
    in[0] = bp[0];    in[1] = bp[1];
    in[2] = bp[98];   in[3] = bp[99];
    in[4] = bp[9604]; in[5] = bp[9605];
    in[6] = bp[9702]; in[7] = bp[9703];

    // conv for channels g4..g4+3
    float c4[4];
    #pragma unroll
    for (int i = 0; i < 4; ++i) {
        const int ch = g4 + i;
        const float4 w0 = *(const float4*)(pw_s + ch * 8);
        const float4 w1 = *(const float4*)(pw_s + ch * 8 + 4);
        float a = pb_s[ch];
        a = fmaf(in[0], w0.x, a); a = fmaf(in[1], w0.y, a);
        a = fmaf(in[2], w0.z, a); a = fmaf(in[3], w0.w, a);
        a = fmaf(in[4], w1.x, a); a = fmaf(in[5], w1.y, a);
        a = fmaf(in[6], w1.z, a); a = fmaf(in[7], w1.w, a);
        c4[i] = a;
    }

    // patch-embed LN (cross-lane over channel groups)
    float s = (c4[0] + c4[1]) + (c4[2] + c4[3]);
    s += __shfl_xor(s, 16); s += __shfl_xor(s, 32);
    float mu = s * 0.0625f;
    float v0 = c4[0] - mu, v1 = c4[1] - mu, v2 = c4[2] - mu, v3 = c4[3] - mu;
    float vv = fmaf(v0, v0, fmaf(v1, v1, fmaf(v2, v2, v3 * v3)));
    vv += __shfl_xor(vv, 16); vv += __shfl_xor(vv, 32);
    float rs = rsqrtf(vv * 0.0625f + 1e-5f);
    const float4 gg = *(const float4*)(g_s + g4);
    const float4 bb = *(const float4*)(b_s + g4);
    const float o0 = v0 * rs * gg.x + bb.x;
    const float o1 = v1 * rs * gg.y + bb.y;
    const float o2 = v2 * rs * gg.z + bb.z;
    const float o3 = v3 * rs * gg.w + bb.w;

    if (valid)
        *(float4*)(xe + (size_t)(w * NWTOK + tok) * 16 + g4) = make_float4(o0, o1, o2, o3);

    // LN1
    s = (o0 + o1) + (o2 + o3);
    s += __shfl_xor(s, 16); s += __shfl_xor(s, 32);
    mu = s * 0.0625f;
    v0 = o0 - mu; v1 = o1 - mu; v2 = o2 - mu; v3 = o3 - mu;
    vv = fmaf(v0, v0, fmaf(v1, v1, fmaf(v2, v2, v3 * v3)));
    vv += __shfl_xor(vv, 16); vv += __shfl_xor(vv, 32);
    rs = rsqrtf(vv * 0.0625f + 1e-5f);
    const float4 g1 = *(const float4*)(n1g_s + g4);
    const float4 b1 = *(const float4*)(n1b_s + g4);
    const h4 yB = packh4(v0 * rs * g1.x + b1.x, v1 * rs * g1.y + b1.y,
                         v2 * rs * g1.z + b1.z, v3 * rs * g1.w + b1.w);

    // QKV (3 MFMAs), store f16 rows
    const f32x4 zero = {0.f, 0.f, 0.f, 0.f};
    const int head = g4 >> 3;
    const int uoff = (g4 & 7) >> 1;
    const size_t qpl = (size_t)(w * 2 + head) * QPLANE + tok * 4 + uoff;
    #pragma unroll
    for (int m = 0; m < 3; ++m) {
        const uint2 aw = *(const uint2*)(qkvh + (m * 16 + tcol) * 8 + (g4 >> 1));
        f32x4 d = __builtin_amdgcn_mfma_f32_16x16x16f16(
            __builtin_bit_cast(h4, aw), yB, zero, 0, 0, 0);
        const float sc = (m == 0) ? QSCALE : 1.f;
        const u32 lo = packh2(d[0] * sc, d[1] * sc);
        const u32 hi = packh2(d[2] * sc, d[3] * sc);
        if (valid) {
            u32* dst = (m == 0 ? qg : (m == 1 ? kg : vg)) + qpl;
            dst[0] = lo;
            dst[1] = hi;
        }
    }
}

// ---- K_attn: WG = (window-pair, head); 11 waves; 1 qt-pair/wave x 2 windows ----
__global__ __launch_bounds__(704, 5) void k_attn(
    const u32* __restrict__ qg,
    const u32* __restrict__ kg,
    const u32* __restrict__ vg,
    float* __restrict__ og,
    const __fp16* __restrict__ bexp_blk)   // this block's [2][22][22][256] f16 tiles
{
    __shared__ __fp16 Kl[2][NPAD][16];
    __shared__ __fp16 Ql[2][NPAD][16];
    __shared__ __fp16 Vt[2][16][360];

    const int tid = threadIdx.x;
    const int pidx = blockIdx.x;
    const int wp = pidx >> 1;
    const int h = pidx & 1;
    const int w0 = 2 * wp;
    const int w1 = (w0 + 1 < NWTOK) ? w0 + 1 : NWTOK - 1;
    const int wh0 = w0 * 2 + h;
    const int wh1 = w1 * 2 + h;

    {
        const int sw = (tid >= NPAD) ? 1 : 0;
        const int st = tid - sw * NPAD;
        const size_t qpl = (size_t)(sw ? wh1 : wh0) * QPLANE;
        const uint4 z4 = make_uint4(0, 0, 0, 0);
        if (st < NWTOK) {
            const uint4 kw = ((const uint4*)(kg + qpl))[st];
            const uint4 qw = ((const uint4*)(qg + qpl))[st];
            const uint4 vw = ((const uint4*)(vg + qpl))[st];
            *(uint4*)&Kl[sw][st][0] = kw; *(uint4*)&Kl[sw][st][8] = z4;
            *(uint4*)&Ql[sw][st][0] = qw; *(uint4*)&Ql[sw][st][8] = z4;
            const h2 v01 = __builtin_bit_cast(h2, vw.x);
            const h2 v23 = __builtin_bit_cast(h2, vw.y);
            const h2 v45 = __builtin_bit_cast(h2, vw.z);
            const h2 v67 = __builtin_bit_cast(h2, vw.w);
            Vt[sw][0][st] = v01.x; Vt[sw][1][st] = v01.y;
            Vt[sw][2][st] = v23.x; Vt[sw][3][st] = v23.y;
            Vt[sw][4][st] = v45.x; Vt[sw][5][st] = v45.y;
            Vt[sw][6][st] = v67.x; Vt[sw][7][st] = v67.y;
        } else {
            *(uint4*)&Kl[sw][st][0] = z4; *(uint4*)&Kl[sw][st][8] = z4;
            *(uint4*)&Ql[sw][st][0] = z4; *(uint4*)&Ql[sw][st][8] = z4;
            #pragma unroll
            for (int d = 0; d < 8; ++d) Vt[sw][d][st] = (__fp16)0.f;
        }
        #pragma unroll
        for (int d = 8; d < 16; ++d) Vt[sw][d][st] = (__fp16)0.f;
    }
    __syncthreads();

    const int wave = tid >> 6;        // 0..10 == qt-pair index
    const int lane = tid & 63;
    const int n = lane & 15;
    const int g4 = (lane >> 4) * 4;

    const int qiA = (2 * wave) * 16 + n;
    const int qiB = qiA + 16;
    const h4 bqA0 = *(const h4*)&Ql[0][qiA][g4];
    const h4 bqB0 = *(const h4*)&Ql[0][qiB][g4];
    const h4 bqA1 = *(const h4*)&Ql[1][qiA][g4];
    const h4 bqB1 = *(const h4*)&Ql[1][qiB][g4];

    const int laneoff = n * 16 + g4;
    const __fp16* trowA = bexp_blk + ((size_t)(h * 484) + (size_t)(2 * wave) * NTILE) * 256 + laneoff;
    const __fp16* trowB = trowA + (size_t)NTILE * 256;

    f32x4 accA0 = {0.f, 0.f, 0.f, 0.f}, accB0 = {0.f, 0.f, 0.f, 0.f};
    f32x4 accA1 = {0.f, 0.f, 0.f, 0.f}, accB1 = {0.f, 0.f, 0.f, 0.f};
    float lA0 = 0.f, lB0 = 0.f, lA1 = 0.f, lB1 = 0.f;

    #pragma unroll
    for (int kt = 0; kt < NTILE; ++kt) {
        const uint2 cbA16 = *(const uint2*)(trowA + kt * 256);
        const uint2 cbB16 = *(const uint2*)(trowB + kt * 256);
        const h2 alo = __builtin_bit_cast(h2, cbA16.x);
        const h2 ahi = __builtin_bit_cast(h2, cbA16.y);
        const h2 blo = __builtin_bit_cast(h2, cbB16.x);
        const h2 bhi = __builtin_bit_cast(h2, cbB16.y);
        f32x4 cbAf, cbBf;
        cbAf[0] = (float)alo.x; cbAf[1] = (float)alo.y;
        cbAf[2] = (float)ahi.x; cbAf[3] = (float)ahi.y;
        cbBf[0] = (float)blo.x; cbBf[1] = (float)blo.y;
        cbBf[2] = (float)bhi.x; cbBf[3] = (float)bhi.y;

        const h4 ak0 = *(const h4*)&Kl[0][kt * 16 + n][g4];
        const h4 ak1 = *(const h4*)&Kl[1][kt * 16 + n][g4];
        const h4 av0 = *(const h4*)&Vt[0][n][kt * 16 + g4];
        const h4 av1 = *(const h4*)&Vt[1][n][kt * 16 + g4];

        f32x4 sA0 = __builtin_amdgcn_mfma_f32_16x16x16f16(ak0, bqA0, cbAf, 0, 0, 0);
        f32x4 sB0 = __builtin_amdgcn_mfma_f32_16x16x16f16(ak0, bqB0, cbBf, 0, 0, 0);
        f32x4 sA1 = __builtin_amdgcn_mfma_f32_16x16x16f16(ak1, bqA1, cbAf, 0, 0, 0);
        f32x4 sB1 = __builtin_amdgcn_mfma_f32_16x16x16f16(ak1, bqB1, cbBf, 0, 0, 0);

        const float pA00 = fast_exp2(sA0[0]);
        const float pA01 = fast_exp2(sA0[1]);
        const float pA02 = fast_exp2(sA0[2]);
        const float pA03 = fast_exp2(sA0[3]);
        const float pB00 = fast_exp2(sB0[0]);
        const float pB01 = fast_exp2(sB0[1]);
        const float pB02 = fast_exp2(sB0[2]);
        const float pB03 = fast_exp2(sB0[3]);
        const float pA10 = fast_exp2(sA1[0]);
        const float pA11 = fast_exp2(sA1[1]);
        const float pA12 = fast_exp2(sA1[2]);
        const float pA13 = fast_exp2(sA1[3]);
        const float pB10 = fast_exp2(sB1[0]);
        const float pB11 = fast_exp2(sB1[1]);
        const float pB12 = fast_exp2(sB1[2]);
        const float pB13 = fast_exp2(sB1[3]);

        lA0 += (pA00 + pA01) + (pA02 + pA03);
        lB0 += (pB00 + pB01) + (pB02 + pB03);
        lA1 += (pA10 + pA11) + (pA12 + pA13);
        lB1 += (pB10 + pB11) + (pB12 + pB13);

        const h4 bpA0 = packh4(pA00, pA01, pA02, pA03);
        const h4 bpB0 = packh4(pB00, pB01, pB02, pB03);
        const h4 bpA1 = packh4(pA10, pA11, pA12, pA13);
        const h4 bpB1 = packh4(pB10, pB11, pB12, pB13);

        accA0 = __builtin_amdgcn_mfma_f32_16x16x16f16(av0, bpA0, accA0, 0, 0, 0);
        accB0 = __builtin_amdgcn_mfma_f32_16x16x16f16(av0, bpB0, accB0, 0, 0, 0);
        accA1 = __builtin_amdgcn_mfma_f32_16x16x16f16(av1, bpA1, accA1, 0, 0, 0);
        accB1 = __builtin_amdgcn_mfma_f32_16x16x16f16(av1, bpB1, accB1, 0, 0, 0);
    }

    lA0 += __shfl_xor(lA0, 16); lA0 += __shfl_xor(lA0, 32);
    lB0 += __shfl_xor(lB0, 16); lB0 += __shfl_xor(lB0, 32);
    lA1 += __shfl_xor(lA1, 16); lA1 += __shfl_xor(lA1, 32);
    lB1 += __shfl_xor(lB1, 16); lB1 += __shfl_xor(lB1, 32);

    if (g4 < 8) {
        if (qiA < NWTOK) {
            const f32x4 o0 = accA0 * (1.f / lA0);
            *(f32x4*)(og + (size_t)wh0 * OPLANE + qiA * 8 + g4) = o0;
            const f32x4 o1 = accA1 * (1.f / lA1);
            *(f32x4*)(og + (size_t)wh1 * OPLANE + qiA * 8 + g4) = o1;
        }
        if (qiB < NWTOK) {
            const f32x4 o0 = accB0 * (1.f / lB0);
            *(f32x4*)(og + (size_t)wh0 * OPLANE + qiB * 8 + g4) = o0;
            const f32x4 o1 = accB1 * (1.f / lB1);
            *(f32x4*)(og + (size_t)wh1 * OPLANE + qiB * 8 + g4) = o1;
        }
    }
}

// ------- K_post (MFMA): wave = one (window, qt) tile of 16 tokens -------
__global__ __launch_bounds__(256, 4) void k_post(
    float* __restrict__ xe,
    const float* __restrict__ og,
    u32* __restrict__ qg,
    u32* __restrict__ kg,
    u32* __restrict__ vg,
    const float* __restrict__ proj_w,
    const float* __restrict__ proj_b,
    const float* __restrict__ n2_g,
    const float* __restrict__ n2_b,
    const float* __restrict__ fc1_w,
    const float* __restrict__ fc1_b,
    const float* __restrict__ fc2_w,
    const float* __restrict__ fc2_b,
    const float* __restrict__ n1_g_nx,
    const float* __restrict__ n1_b_nx,
    const float* __restrict__ qkv_w_nx,
    float* __restrict__ outp,
    const int last)
{
    __shared__ u32 projh[128];     // (16,16) f16: row*8 + k/2
    __shared__ u32 fc1h[512];      // (64,16) f16
    __shared__ u32 fc2h[512];      // (16,64) f16: row*32 + k/2
    __shared__ u32 qkvh[384];      // (48,16) f16
    __shared__ float projb_s[16], n2g_s[16], n2b_s[16], fc2b_s[16], n1g_s[16], n1b_s[16];
    __shared__ float fc1b_s[64];
    const int tid = threadIdx.x;
    if (tid < 128) {
        const float2 p = ((const float2*)proj_w)[tid];
        projh[tid] = packh2(p.x, p.y);
    }
    for (int i = tid; i < 512; i += 256) {
        const float2 a = ((const float2*)fc1_w)[i];
        fc1h[i] = packh2(a.x, a.y);
        const float2 b = ((const float2*)fc2_w)[i];
        fc2h[i] = packh2(b.x, b.y);
    }
    for (int i = tid; i < 384; i += 256) {
        const float2 a = ((const float2*)qkv_w_nx)[i];
        qkvh[i] = packh2(a.x, a.y);
    }
    if (tid < 16) {
        projb_s[tid] = proj_b[tid];
        n2g_s[tid] = n2_g[tid]; n2b_s[tid] = n2_b[tid];
        fc2b_s[tid] = fc2_b[tid];
        n1g_s[tid] = n1_g_nx[tid]; n1b_s[tid] = n1_b_nx[tid];
    }
    if (tid < 64) fc1b_s[tid] = fc1_b[tid];
    __syncthreads();

    const int wave_id = blockIdx.x * 4 + (tid >> 6);
    if (wave_id >= NWTOK * NTILE) return;   // 7546 tiles
    const int w = wave_id / NTILE;
    const int qt = wave_id - w * NTILE;

    const int lane = tid & 63;
    const int tcol = lane & 15;             // token column (also A row index)
    const int g4 = (lane >> 4) * 4;         // channel group base
    const int tok = qt * 16 + tcol;
    const bool valid = (tok < NWTOK);
    const int tokc = valid ? tok : (NWTOK - 1);

    const f32x4 zero = {0.f, 0.f, 0.f, 0.f};

    // ---- B-frag: o^T (ch g4..g4+3 of this token) ----
    const int pl = g4 >> 3;                 // head plane
    const int po = g4 & 7;                  // within-plane ch offset (0 or 4)
    const float4 o4 = *(const float4*)(og + (size_t)(w * 2 + pl) * OPLANE + tokc * 8 + po);
    const h4 oB = packh4(o4.x, o4.y, o4.z, o4.w);

    // ---- proj + residual + bias ----
    const uint2 apw = *(const uint2*)(projh + tcol * 8 + (g4 >> 1));
    const f32x4 d1 = __builtin_amdgcn_mfma_f32_16x16x16f16(
        __builtin_bit_cast(h4, apw), oB, zero, 0, 0, 0);
    const float4 xe4 = *(const float4*)(xe + (size_t)(w * NWTOK + tokc) * 16 + g4);
    const float4 pb4 = *(const float4*)(projb_s + g4);
    float xr0 = d1[0] + xe4.x + pb4.x;
    float xr1 = d1[1] + xe4.y + pb4.y;
    float xr2 = d1[2] + xe4.z + pb4.z;
    float xr3 = d1[3] + xe4.w + pb4.w;

    // ---- LN2 (cross-lane over channel groups) ----
    float s = (xr0 + xr1) + (xr2 + xr3);
    s += __shfl_xor(s, 16); s += __shfl_xor(s, 32);
    float mu = s * 0.0625f;
    float v0 = xr0 - mu, v1 = xr1 - mu, v2 = xr2 - mu, v3 = xr3 - mu;
    float vv = fmaf(v0, v0, fmaf(v1, v1, fmaf(v2, v2, v3 * v3)));
    vv += __shfl_xor(vv, 16); vv += __shfl_xor(vv, 32);
    float rs = rsqrtf(vv * 0.0625f + 1e-5f);
    const float4 g2 = *(const float4*)(n2g_s + g4);
    const float4 b2 = *(const float4*)(n2b_s + g4);
    const h4 zB = packh4(v0 * rs * g2.x + b2.x, v1 * rs * g2.y + b2.y,
                         v2 * rs * g2.z + b2.z, v3 * rs * g2.w + b2.w);

    // ---- fc1 (4 MFMAs) + bias + GELU -> 4 B-frags ----
    h4 hB[4];
    #pragma unroll
    for (int i = 0; i < 4; ++i) {
        const uint2 aw = *(const uint2*)(fc1h + (i * 16 + tcol) * 8 + (g4 >> 1));
        f32x4 hd = __builtin_amdgcn_mfma_f32_16x16x16f16(
            __builtin_bit_cast(h4, aw), zB, zero, 0, 0, 0);
        const float4 fb = *(const float4*)(fc1b_s + i * 16 + g4);
        hB[i] = packh4(gelu_exact(hd[0] + fb.x), gelu_exact(hd[1] + fb.y),
                       gelu_exact(hd[2] + fb.z), gelu_exact(hd[3] + fb.w));
    }

    // ---- fc2 (K=64: 4 chained MFMAs) + bias + residual ----
    f32x4 acc = zero;
    #pragma unroll
    for (int j = 0; j < 4; ++j) {
        const uint2 aw = *(const uint2*)(fc2h + tcol * 32 + ((j * 16 + g4) >> 1));
        acc = __builtin_amdgcn_mfma_f32_16x16x16f16(
            __builtin_bit_cast(h4, aw), hB[j], acc, 0, 0, 0);
    }
    const float4 f2b = *(const float4*)(fc2b_s + g4);
    xr0 += acc[0] + f2b.x;
    xr1 += acc[1] + f2b.y;
    xr2 += acc[2] + f2b.z;
    xr3 += acc[3] + f2b.w;

    if (last) {
        if (valid) {
            const int wd = w / 49, wr2 = w - wd * 49, whh = wr2 / 7, www = wr2 - whh * 7;
            const int tz = tok / 49, tr2 = tok - tz * 49, ty = tr2 / 7, tx = tr2 - ty * 7;
            const int g = ((wd * 7 + tz) * 49 + (whh * 7 + ty)) * 49 + (www * 7 + tx);
            outp[(size_t)(g4 + 0) * NTOK + g] = xr0;
            outp[(size_t)(g4 + 1) * NTOK + g] = xr1;
            outp[(size_t)(g4 + 2) * NTOK + g] = xr2;
            outp[(size_t)(g4 + 3) * NTOK + g] = xr3;
        }
        return;
    }

    if (valid) {
        float4 st = make_float4(xr0, xr1, xr2, xr3);
        *(float4*)(xe + (size_t)(w * NWTOK + tok) * 16 + g4) = st;
    }

    // ---- LN1 ----
    s = (xr0 + xr1) + (xr2 + xr3);
    s += __shfl_xor(s, 16); s += __shfl_xor(s, 32);
    mu = s * 0.0625f;
    v0 = xr0 - mu; v1 = xr1 - mu; v2 = xr2 - mu; v3 = xr3 - mu;
    vv = fmaf(v0, v0, fmaf(v1, v1, fmaf(v2, v2, v3 * v3)));
    vv += __shfl_xor(vv, 16); vv += __shfl_xor(vv, 32);
    rs = rsqrtf(vv * 0.0625f + 1e-5f);
    const float4 g1 = *(const float4*)(n1g_s + g4);
    const float4 b1 = *(const float4*)(n1b_s + g4);
    const h4 yB = packh4(v0 * rs * g1.x + b1.x, v1 * rs * g1.y + b1.y,
                         v2 * rs * g1.z + b1.z, v3 * rs * g1.w + b1.w);

    // ---- QKV for next block (3 MFMAs), store f16 rows ----
    const int head = g4 >> 3;
    const int uoff = (g4 & 7) >> 1;         // u32 offset within the token's 4-u32 row
    const size_t qpl = (size_t)(w * 2 + head) * QPLANE + tok * 4 + uoff;
    #pragma unroll
    for (int m = 0; m < 3; ++m) {
        const uint2 aw = *(const uint2*)(qkvh + (m * 16 + tcol) * 8 + (g4 >> 1));
        f32x4 d = __builtin_amdgcn_mfma_f32_16x16x16f16(
            __builtin_bit_cast(h4, aw), yB, zero, 0, 0, 0);
        float sc = (m == 0) ? QSCALE : 1.f;
        const u32 lo = packh2(d[0] * sc, d[1] * sc);
        const u32 hi = packh2(d[2] * sc, d[3] * sc);
        if (valid) {
            u32* dst = (m == 0 ? qg : (m == 1 ? kg : vg)) + qpl;
            dst[0] = lo;
            dst[1] = hi;
        }
    }
}

extern "C" void kernel_launch(void* const* d_in, const int* in_sizes, int n_in,
                              void* d_out, int out_size, void* d_ws, size_t ws_size,
                              hipStream_t stream) {
    const float* x       = (const float*)d_in[0];
    const float* pe_w    = (const float*)d_in[1];
    const float* pe_bias = (const float*)d_in[2];
    const float* pe_g    = (const float*)d_in[3];
    const float* pe_b    = (const float*)d_in[4];
    const float* n1_g    = (const float*)d_in[5];
    const float* n1_b    = (const float*)d_in[6];
    const float* qkv_w   = (const float*)d_in[7];
    const float* rpb     = (const float*)d_in[8];
    const float* proj_w  = (const float*)d_in[9];
    const float* proj_b  = (const float*)d_in[10];
    const float* n2_g    = (const float*)d_in[11];
    const float* n2_b    = (const float*)d_in[12];
    const float* fc1_w   = (const float*)d_in[13];
    const float* fc1_b   = (const float*)d_in[14];
    const float* fc2_w   = (const float*)d_in[15];
    const float* fc2_b   = (const float*)d_in[16];

    float* ws = (float*)d_ws;
    const size_t SEG = (size_t)NTOK * 16;     // 1,882,384 floats
    const size_t QSEG = (size_t)686 * QPLANE; // 941,192 u32
    float* xe = ws;
    u32* qg = (u32*)(ws + SEG);
    u32* kg = qg + QSEG;
    u32* vg = kg + QSEG;
    float* og = (float*)(vg + QSEG);                  // 686*2744 f32
    __fp16* bexp16 = (__fp16*)(og + (size_t)686 * OPLANE); // 6*484*256 f16
    float* out = (float*)d_out;

    const int k0_grid = NBIAS_BLK + (NK0_TILE + 3) / 4;   // bias tiles + k0 tiles
    k0_fused<<<k0_grid, 256, 0, stream>>>(
        x, pe_w, pe_bias, pe_g, pe_b, n1_g, n1_b, qkv_w, rpb,
        xe, qg, kg, vg, bexp16);

    const int post_grid = (NWTOK * NTILE + 3) / 4;    // 7546 tiles, 4 waves/WG
    for (int i = 0; i < 3; ++i) {
        const int last = (i == 2) ? 1 : 0;
        const int nx = last ? i : i + 1;
        k_attn<<<344, 704, 0, stream>>>(
            qg, kg, vg, og, bexp16 + (size_t)i * 2 * 484 * 256);
        k_post<<<post_grid, 256, 0, stream>>>(
            xe, og, qg, kg, vg,
            proj_w + (size_t)i * 256, proj_b + (size_t)i * 16,
            n2_g + (size_t)i * 16, n2_b + (size_t)i * 16,
            fc1_w + (size_t)i * 1024, fc1_b + (size_t)i * 64,
            fc2_w + (size_t)i * 1024, fc2_b + (size_t)i * 16,
            n1_g + (size_t)nx * 16, n1_b + (size_t)nx * 16,
            qkv_w + (size_t)nx * 768,
            out, last);
    }
}